// Round 5
// baseline (1065.965 us; speedup 1.0000x reference)
//
#include <hip/hip_runtime.h>
#include <hip/hip_bf16.h>

typedef __hip_bfloat16 bf16;
typedef __attribute__((ext_vector_type(8))) short s16x8;
typedef __attribute__((ext_vector_type(4))) short s16x4;
typedef __attribute__((ext_vector_type(4))) float f32x4;

#define TT 64
#define NN_ 1024
#define EE 512

__device__ __forceinline__ float toF(float v) { return v; }
__device__ __forceinline__ float toF(bf16 v) { return __bfloat162float(v); }
__device__ __forceinline__ bf16 f2b(float v) { return __float2bfloat16(v); }

#if __has_builtin(__builtin_amdgcn_exp2f)
#define EXP2F(x) __builtin_amdgcn_exp2f(x)
#else
#define EXP2F(x) exp2f(x)
#endif
#if __has_builtin(__builtin_amdgcn_logf)
#define LOG2F(x) __builtin_amdgcn_logf(x)
#else
#define LOG2F(x) log2f(x)
#endif

enum { EPI_F32 = 0, EPI_SIG_F32 = 1, EPI_SIG_B16 = 2 };
enum { E_LN1 = 0, E_BF16 = 1, E_LN2 = 2, E_SILU = 3, E_OUT = 4, E_TRI = 5, E_BF16T = 6 };

// ---------------- small fp32 tiled GEMM (S0-S2 only; 1024-row problems) -------------
template <bool TRANSB, int EPI>
__global__ __launch_bounds__(256) void gemm_k(
    const float* __restrict__ A, const float* __restrict__ B,
    float* __restrict__ outF, const float* __restrict__ bias,
    const float* __restrict__ sbeta, float alpha,
    int M, int Nn, int K, int lda, int ldb)
{
    __shared__ float As[16][68];
    __shared__ float Bs[16][68];
    const int tid = threadIdx.x;
    const int tx = tid & 15, ty = tid >> 4;
    const int m0 = blockIdx.x * 64, n0 = blockIdx.y * 64;
    float acc[4][4] = {};

    for (int k0 = 0; k0 < K; k0 += 16) {
        {
            int row = tid >> 2, kk0 = (tid & 3) * 4, grow = m0 + row;
#pragma unroll
            for (int j = 0; j < 4; j++) {
                int kk = kk0 + j, gk = k0 + kk;
                As[kk][row] = (grow < M) ? A[(size_t)grow * lda + gk] : 0.f;
            }
        }
        if (!TRANSB) {
            int kk = tid >> 4, c0 = (tid & 15) * 4;
#pragma unroll
            for (int j = 0; j < 4; j++) {
                int col = c0 + j, gn = n0 + col;
                Bs[kk][col] = (gn < Nn) ? B[(size_t)(k0 + kk) * ldb + gn] : 0.f;
            }
        } else {
            int col = tid >> 2, kk0 = (tid & 3) * 4, gn = n0 + col;
#pragma unroll
            for (int j = 0; j < 4; j++) {
                int kk = kk0 + j;
                Bs[kk][col] = (gn < Nn) ? B[(size_t)gn * ldb + (k0 + kk)] : 0.f;
            }
        }
        __syncthreads();
#pragma unroll
        for (int kk = 0; kk < 16; kk++) {
            float a[4], b[4];
#pragma unroll
            for (int i = 0; i < 4; i++) a[i] = As[kk][ty * 4 + i];
#pragma unroll
            for (int j = 0; j < 4; j++) b[j] = Bs[kk][tx * 4 + j];
#pragma unroll
            for (int i = 0; i < 4; i++)
#pragma unroll
                for (int j = 0; j < 4; j++)
                    acc[i][j] = fmaf(a[i], b[j], acc[i][j]);
        }
        __syncthreads();
    }

    float gb = (EPI != EPI_F32 && sbeta) ? sbeta[0] : 0.f;
#pragma unroll
    for (int i = 0; i < 4; i++) {
        int row = m0 + ty * 4 + i;
        if (row >= M) continue;
#pragma unroll
        for (int j = 0; j < 4; j++) {
            int col = n0 + tx * 4 + j;
            if (col >= Nn) continue;
            float v = acc[i][j];
            if (EPI == EPI_F32) {
                if (bias) v += bias[col];
                outF[(size_t)row * Nn + col] = v;
            } else if (EPI == EPI_SIG_F32) {
                v = v * alpha + gb;
                outF[(size_t)row * Nn + col] = 1.f / (1.f + __expf(-v));
            } else {
                v = v * alpha + gb;
                ((bf16*)outF)[(size_t)row * Nn + col] = f2b(1.f / (1.f + __expf(-v)));
            }
        }
    }
}

// ---------------- MFMA bf16 GEMM, 64x64 wave tile (LN / TRI epilogues) ---------------
// C[M,Nn] = A[M,K](bf16) @ BT[Nn,K]^T(bf16), fp32 accum, fused epilogues.
// 256 threads = 4 waves. BK=32. BN=256: waves side-by-side; BM=256/BN=64: stacked.
// CAT: A row r = [A1[(r&rowmask),0:256] | A2[r,0:256]], K=512.
template <int BM, int BN, bool CAT, int EPI>
__global__ __launch_bounds__(256) void mfma_k(
    const bf16* __restrict__ A1, const bf16* __restrict__ A2, unsigned rowmask,
    const bf16* __restrict__ BT, const float* __restrict__ bias,
    float* __restrict__ outF,
    bf16* __restrict__ outB, bf16* __restrict__ outB2,
    const float* __restrict__ g1, const float* __restrict__ b1,
    const float* __restrict__ g2, const float* __restrict__ b2,
    const bf16* __restrict__ resid,
    int M, int K)
{
    constexpr bool LN = (EPI == E_LN1 || EPI == E_LN2);
    constexpr int STAGE_B = (BM * 32 + BN * 32) * 2;
    constexpr int SB = LN ? (64 * 260 * 4) : STAGE_B;
    __shared__ __align__(16) char smem[SB];
    short* As = (short*)smem;
    short* Bs = As + BM * 32;
    float* Cs = (float*)smem;   // LN epilogue reuses staging LDS

    const int tid = threadIdx.x;
    const int wid = tid >> 6, lane = tid & 63;
    const int wr = (BN == 256) ? 0 : wid;
    const int wc = (BN == 256) ? wid : 0;
    const int m0 = blockIdx.x * BM, n0 = blockIdx.y * BN;
    const int srow = tid >> 2;
    const int skoff = (tid & 3) * 8;

    f32x4 acc[4][4] = {};
    s16x8 pa[BM / 64], pbv[BN / 64];

    auto LOADT = [&](int k0) {
#pragma unroll
        for (int c = 0; c < BM / 64; c++) {
            int r = c * 64 + srow;
            int gr = m0 + r;
            const bf16* p;
            if (CAT) {
                int gk = k0 + skoff;
                p = (gk < 256) ? (A1 + (size_t)(gr & rowmask) * 256 + gk)
                               : (A2 + (size_t)gr * 256 + (gk - 256));
            } else {
                p = A1 + (size_t)gr * K + k0 + skoff;
            }
            pa[c] = *(const s16x8*)p;
        }
#pragma unroll
        for (int c = 0; c < BN / 64; c++) {
            int r = c * 64 + srow;
            pbv[c] = *(const s16x8*)(BT + (size_t)(n0 + r) * K + k0 + skoff);
        }
    };

    LOADT(0);
#pragma unroll 1
    for (int k0 = 0; k0 < K; k0 += 32) {
#pragma unroll
        for (int c = 0; c < BM / 64; c++)
            *(s16x8*)&As[(c * 64 + srow) * 32 + skoff] = pa[c];
#pragma unroll
        for (int c = 0; c < BN / 64; c++)
            *(s16x8*)&Bs[(c * 64 + srow) * 32 + skoff] = pbv[c];
        __syncthreads();
        if (k0 + 32 < K) LOADT(k0 + 32);   // next tile in flight during MFMA
        s16x8 af[4], bf[4];
#pragma unroll
        for (int mi = 0; mi < 4; mi++)
            af[mi] = *(s16x8*)&As[(wr * 64 + mi * 16 + (lane & 15)) * 32 + (lane >> 4) * 8];
#pragma unroll
        for (int ni = 0; ni < 4; ni++)
            bf[ni] = *(s16x8*)&Bs[(wc * 64 + ni * 16 + (lane & 15)) * 32 + (lane >> 4) * 8];
#pragma unroll
        for (int mi = 0; mi < 4; mi++)
#pragma unroll
            for (int ni = 0; ni < 4; ni++)
                acc[mi][ni] = __builtin_amdgcn_mfma_f32_16x16x32_bf16(
                    af[mi], bf[ni], acc[mi][ni], 0, 0, 0);
        __syncthreads();
    }

    if (EPI == E_TRI) {
        // dbc[M,48]: cols 0-15 d1, 16-31 Bm, 32-47 Cm
#pragma unroll
        for (int mi = 0; mi < 4; mi++)
#pragma unroll
            for (int ni = 0; ni < 4; ni++)
#pragma unroll
                for (int r = 0; r < 4; r++) {
                    int row = m0 + wid * 64 + mi * 16 + (lane >> 4) * 4 + r;
                    int col = ni * 16 + (lane & 15);
                    if (col < 48) {
                        float v = acc[mi][ni][r] + bias[col];
                        outF[(size_t)row * 48 + col] = v;
                    }
                }
    } else {
        // E_LN1 / E_LN2: relu -> Cs, then row LN(s). BM=64, BN=256, grid.y=1.
#pragma unroll
        for (int mi = 0; mi < 4; mi++)
#pragma unroll
            for (int ni = 0; ni < 4; ni++)
#pragma unroll
                for (int r = 0; r < 4; r++) {
                    int rl = mi * 16 + (lane >> 4) * 4 + r;
                    int cl = wc * 64 + ni * 16 + (lane & 15);
                    Cs[rl * 260 + cl] = fmaxf(acc[mi][ni][r] + bias[cl], 0.f);
                }
        __syncthreads();
        float g1v[4], b1v[4], g2v[4], b2v[4];
#pragma unroll
        for (int i = 0; i < 4; i++) {
            g1v[i] = g1[lane * 4 + i];
            b1v[i] = b1[lane * 4 + i];
            if (EPI == E_LN2) { g2v[i] = g2[lane * 4 + i]; b2v[i] = b2[lane * 4 + i]; }
        }
        for (int rr = 0; rr < 16; rr++) {
            int rl = wid * 16 + rr;
            int grow = m0 + rl;
            float x[4];
#pragma unroll
            for (int i = 0; i < 4; i++) x[i] = Cs[rl * 260 + lane * 4 + i];
            float s = x[0] + x[1] + x[2] + x[3];
#pragma unroll
            for (int o = 1; o < 64; o <<= 1) s += __shfl_xor(s, o, 64);
            float mu = s * (1.f / 256.f);
            float d[4], ss = 0.f;
#pragma unroll
            for (int i = 0; i < 4; i++) { d[i] = x[i] - mu; ss = fmaf(d[i], d[i], ss); }
#pragma unroll
            for (int o = 1; o < 64; o <<= 1) ss += __shfl_xor(ss, o, 64);
            float inv = rsqrtf(fmaxf(ss * (1.f / 256.f), 0.f) + 1e-5f);
            float y[4];
#pragma unroll
            for (int i = 0; i < 4; i++) y[i] = d[i] * inv * g1v[i] + b1v[i];
            if (EPI == E_LN1) {
                __align__(8) bf16 pk[4];
#pragma unroll
                for (int i = 0; i < 4; i++) pk[i] = f2b(y[i]);
                *(s16x4*)&outB[(size_t)grow * 256 + lane * 4] = *(s16x4*)pk;
            } else {
                int trow = (grow & 1023) * 64 + (grow >> 10);   // [N,T] order
                __align__(8) bf16 pk[4];
#pragma unroll
                for (int i = 0; i < 4; i++) pk[i] = f2b(y[i]);
                *(s16x4*)&outB[(size_t)trow * 256 + lane * 4] = *(s16x4*)pk;
                float s2 = y[0] + y[1] + y[2] + y[3];
#pragma unroll
                for (int o = 1; o < 64; o <<= 1) s2 += __shfl_xor(s2, o, 64);
                float mu2 = s2 * (1.f / 256.f);
                float d2[4], ss2 = 0.f;
#pragma unroll
                for (int i = 0; i < 4; i++) { d2[i] = y[i] - mu2; ss2 = fmaf(d2[i], d2[i], ss2); }
#pragma unroll
                for (int o = 1; o < 64; o <<= 1) ss2 += __shfl_xor(ss2, o, 64);
                float inv2 = rsqrtf(fmaxf(ss2 * (1.f / 256.f), 0.f) + 1e-5f);
                __align__(8) bf16 pk2[4];
#pragma unroll
                for (int i = 0; i < 4; i++) pk2[i] = f2b(d2[i] * inv2 * g2v[i] + b2v[i]);
                *(s16x4*)&outB2[(size_t)trow * 256 + lane * 4] = *(s16x4*)pk2;
            }
        }
    }
}

// ---------------- MFMA bf16 GEMM, 64x128 wave tile (aggmm structure) -----------------
// BM=128 x BN=256, 4 waves (wr=wid&1 rows, wc=wid>>1 cols), 1-deep register prefetch.
// 32 MFMA (~160cy) vs 12 ds_read_b128 (~144cy) per wave per K-step -> MFMA-bound,
// vs the 64x64 wave tile's 16 MFMA / 8 ds_read (LDS-read-bound). Used for the three
// large non-LN GEMMs: S6 (BF16T), S11 (SILU), S14 (OUT).
template <int EPI>
__global__ __launch_bounds__(256, 2) void mfma2_k(
    const bf16* __restrict__ A, const bf16* __restrict__ BT,
    const float* __restrict__ bias,
    float* __restrict__ outF, bf16* __restrict__ outB, bf16* __restrict__ outB2,
    const bf16* __restrict__ resid,
    int K)
{
    constexpr int STAGE_B = (128 * 40 + 256 * 40) * 2;          // 30720
    constexpr int TRB = (EPI == E_BF16T) ? (64 * 268 * 2) : 0;  // 34304
    constexpr int SB = STAGE_B > TRB ? STAGE_B : TRB;
    __shared__ __align__(16) char smem[SB];
    short* As = (short*)smem;
    short* Bs = As + 128 * 40;

    const int tid = threadIdx.x;
    const int wid = tid >> 6, lane = tid & 63;
    const int wr = wid & 1;          // wave rows: wr*64
    const int wc = wid >> 1;         // wave cols: wc*128
    const int m0 = blockIdx.x * 128, n0 = blockIdx.y * 256;
    const int srow = tid >> 2;       // 0..63
    const int skoff = (tid & 3) * 8; // 0,8,16,24

    f32x4 acc[4][8] = {};
    s16x8 pa[2], pb[4];

    auto LOADT = [&](int k0) {
#pragma unroll
        for (int c = 0; c < 2; c++)
            pa[c] = *(const s16x8*)(A + (size_t)(m0 + c * 64 + srow) * K + k0 + skoff);
#pragma unroll
        for (int c = 0; c < 4; c++)
            pb[c] = *(const s16x8*)(BT + (size_t)(n0 + c * 64 + srow) * K + k0 + skoff);
    };

    LOADT(0);
#pragma unroll 1
    for (int k0 = 0; k0 < K; k0 += 32) {
#pragma unroll
        for (int c = 0; c < 2; c++)
            *(s16x8*)&As[(c * 64 + srow) * 40 + skoff] = pa[c];
#pragma unroll
        for (int c = 0; c < 4; c++)
            *(s16x8*)&Bs[(c * 64 + srow) * 40 + skoff] = pb[c];
        __syncthreads();
        if (k0 + 32 < K) LOADT(k0 + 32);   // next tile in flight during MFMA
        s16x8 af[4];
#pragma unroll
        for (int mi = 0; mi < 4; mi++)
            af[mi] = *(s16x8*)&As[(wr * 64 + mi * 16 + (lane & 15)) * 40 + (lane >> 4) * 8];
#pragma unroll
        for (int ni = 0; ni < 8; ni++) {
            s16x8 bfv = *(s16x8*)&Bs[(wc * 128 + ni * 16 + (lane & 15)) * 40 + (lane >> 4) * 8];
#pragma unroll
            for (int mi = 0; mi < 4; mi++)
                acc[mi][ni] = __builtin_amdgcn_mfma_f32_16x16x32_bf16(
                    af[mi], bfv, acc[mi][ni], 0, 0, 0);
        }
        __syncthreads();
    }

    if (EPI == E_SILU) {
#pragma unroll
        for (int mi = 0; mi < 4; mi++)
#pragma unroll
            for (int ni = 0; ni < 8; ni++)
#pragma unroll
                for (int r = 0; r < 4; r++) {
                    int row = m0 + wr * 64 + mi * 16 + (lane >> 4) * 4 + r;
                    int col = n0 + wc * 128 + ni * 16 + (lane & 15);
                    float v = acc[mi][ni][r] + bias[col];
                    float s = v / (1.f + __expf(-v));
                    if (col < EE) outB[(size_t)row * EE + col] = f2b(s);
                    else          outB2[(size_t)row * EE + (col - EE)] = f2b(s);
                }
    } else if (EPI == E_OUT) {
#pragma unroll
        for (int mi = 0; mi < 4; mi++)
#pragma unroll
            for (int ni = 0; ni < 8; ni++)
#pragma unroll
                for (int r = 0; r < 4; r++) {
                    int row = m0 + wr * 64 + mi * 16 + (lane >> 4) * 4 + r;
                    int col = n0 + wc * 128 + ni * 16 + (lane & 15);
                    float v = acc[mi][ni][r] + bias[col] + toF(resid[(size_t)row * 256 + col]);
                    int t = row & 63, n = row >> 6;
                    outF[((size_t)t * NN_ + n) * 256 + col] = v;
                }
    } else {
        // E_BF16T: rows r = t*1024+j -> store transposed [t][col][j].
        // Two 64-row halves through a 64x268 LDS tile (fits with 2 blocks/CU).
        short* Ts = (short*)smem;
#pragma unroll 1
        for (int h = 0; h < 2; h++) {
            if (h) __syncthreads();      // protect previous half's reads
            if (wr == h) {
#pragma unroll
                for (int mi = 0; mi < 4; mi++)
#pragma unroll
                    for (int ni = 0; ni < 8; ni++)
#pragma unroll
                        for (int r = 0; r < 4; r++) {
                            int rl = mi * 16 + (lane >> 4) * 4 + r;
                            int cl = wc * 128 + ni * 16 + (lane & 15);
                            union { bf16 b; short s; } u;
                            u.b = f2b(acc[mi][ni][r] + bias[n0 + cl]);
                            Ts[rl * 268 + cl] = u.s;
                        }
            }
            __syncthreads();
            const int col = tid;
            const int rowbase = m0 + h * 64;
            size_t dbase = (((size_t)(rowbase >> 10)) * 256 + (n0 + col)) * 1024 + (rowbase & 1023);
#pragma unroll
            for (int j0 = 0; j0 < 64; j0 += 8) {
                s16x8 v;
#pragma unroll
                for (int i = 0; i < 8; i++) v[i] = Ts[(j0 + i) * 268 + col];
                *(s16x8*)&outB[dbase + j0] = v;
            }
        }
    }
}

// ---------------- adj bit-pack: adj in {0,1} -> 1 bit/elem (268MB -> 8.4MB) --------
__global__ __launch_bounds__(256) void packadj_k(
    const float4* __restrict__ adj4, unsigned int* __restrict__ bits32)
{
    const size_t nwords = (size_t)TT * NN_ * NN_ / 32;   // 2,097,152
    const size_t stride = (size_t)gridDim.x * 256;
    for (size_t w = (size_t)blockIdx.x * 256 + threadIdx.x; w < nwords; w += stride) {
        const float4* __restrict__ p = adj4 + w * 8;
        float4 v[8];
#pragma unroll
        for (int i = 0; i < 8; i++) v[i] = p[i];
        unsigned int m = 0;
#pragma unroll
        for (int i = 0; i < 8; i++) {
            m |= (v[i].x != 0.f ? 1u : 0u) << (4 * i);
            m |= (v[i].y != 0.f ? 2u : 0u) << (4 * i);
            m |= (v[i].z != 0.f ? 4u : 0u) << (4 * i);
            m |= (v[i].w != 0.f ? 8u : 0u) << (4 * i);
        }
        bits32[w] = m;
    }
}

// ---------------- dense MFMA aggregation via bitmask -------------------------------
template <bool GATED>
__global__ __launch_bounds__(256, 2) void aggmm_k(
    const unsigned char* __restrict__ adjbits, const bf16* __restrict__ gatesb,
    const bf16* __restrict__ BTsrc, bf16* __restrict__ out)
{
    __shared__ __align__(16) short As[128 * 40];
    __shared__ __align__(16) short Bs[256 * 40];
    const int tid = threadIdx.x;
    const int wid = tid >> 6, lane = tid & 63;
    const int wr = wid & 1;          // wave rows: wr*64
    const int wc = wid >> 1;         // wave cols: wc*128
    const int bx = blockIdx.x;
    const int t = bx >> 3, n0 = (bx & 7) * 128;
    const int srow = tid >> 2;       // 0..63
    const int skoff = (tid & 3) * 8; // 0,8,16,24

    const unsigned char* __restrict__ abB =
        adjbits + ((size_t)t * 1024 + n0) * 128 + (tid & 3);
    const bf16* __restrict__ gB = GATED ? (gatesb + (size_t)n0 * 1024 + skoff) : nullptr;
    const bf16* __restrict__ bt = GATED ? BTsrc : (BTsrc + (size_t)t * 256 * 1024);
    const size_t orow0 = (size_t)t * 1024 + n0;

    f32x4 acc[4][8] = {};

    unsigned char pm[2];
    s16x8 pg[2];
    s16x8 pb[4];

    auto LOADA = [&](int k0) {
#pragma unroll
        for (int c = 0; c < 2; c++) {
            int r = c * 64 + srow;
            pm[c] = abB[(size_t)r * 128 + (k0 >> 3)];
            if (GATED) pg[c] = *(const s16x8*)(gB + (size_t)r * 1024 + k0);
        }
#pragma unroll
        for (int c = 0; c < 4; c++)
            pb[c] = *(const s16x8*)(bt + (size_t)(c * 64 + srow) * 1024 + k0 + skoff);
    };
    auto STORE = [&]() {
#pragma unroll
        for (int c = 0; c < 2; c++) {
            unsigned m = pm[c];
            s16x8 tmp;
            if (GATED) {
#pragma unroll
                for (int i = 0; i < 8; i++) tmp[i] = ((m >> i) & 1) ? pg[c][i] : (short)0;
            } else {
#pragma unroll
                for (int i = 0; i < 8; i++) tmp[i] = ((m >> i) & 1) ? (short)0x3F80 : (short)0;
            }
            *(s16x8*)&As[(c * 64 + srow) * 40 + skoff] = tmp;
        }
#pragma unroll
        for (int c = 0; c < 4; c++)
            *(s16x8*)&Bs[(c * 64 + srow) * 40 + skoff] = pb[c];
    };

    LOADA(0);
#pragma unroll 1
    for (int k0 = 0; k0 < 1024; k0 += 32) {
        STORE();
        __syncthreads();
        if (k0 + 32 < 1024) LOADA(k0 + 32);   // next tile in flight during MFMA
        s16x8 af[4];
#pragma unroll
        for (int mi = 0; mi < 4; mi++)
            af[mi] = *(s16x8*)&As[(wr * 64 + mi * 16 + (lane & 15)) * 40 + (lane >> 4) * 8];
#pragma unroll
        for (int ni = 0; ni < 8; ni++) {
            s16x8 bfv = *(s16x8*)&Bs[(wc * 128 + ni * 16 + (lane & 15)) * 40 + (lane >> 4) * 8];
#pragma unroll
            for (int mi = 0; mi < 4; mi++)
                acc[mi][ni] = __builtin_amdgcn_mfma_f32_16x16x32_bf16(
                    af[mi], bfv, acc[mi][ni], 0, 0, 0);
        }
        __syncthreads();
    }

#pragma unroll
    for (int mi = 0; mi < 4; mi++)
#pragma unroll
        for (int ni = 0; ni < 8; ni++)
#pragma unroll
            for (int r = 0; r < 4; r++) {
                int rowl = wr * 64 + mi * 16 + (lane >> 4) * 4 + r;
                int col = wc * 128 + ni * 16 + (lane & 15);
                out[(orow0 + rowl) * 256 + col] = f2b(acc[mi][ni][r]);
            }
}

// ---------------- Mamba selective scan (block = n-col x e-half) ---------------------
__global__ __launch_bounds__(256) void scan_k(
    const bf16* __restrict__ u, const bf16* __restrict__ sg,
    const float* __restrict__ dbc,
    const float* __restrict__ Wdt, const float* __restrict__ bdt,
    const float* __restrict__ Alog, const float* __restrict__ D,
    bf16* __restrict__ yg)
{
    const int n = blockIdx.x, e = blockIdx.y * 256 + threadIdx.x;
    float al[16], wdt[16], h[16];
#pragma unroll
    for (int s = 0; s < 16; s++) {
        al[s] = -__expf(Alog[e * 16 + s]) * 1.44269504f;   // * log2(e)
        h[s] = 0.f;
    }
#pragma unroll
    for (int k = 0; k < 16; k++) wdt[k] = Wdt[(size_t)k * EE + e];
    const float bdte = bdt[e], De = D[e];
    const float* __restrict__ rowp = dbc + (size_t)n * TT * 48;
    const size_t base = (size_t)n * TT * EE + e;
#pragma unroll 2
    for (int t = 0; t < TT; t++) {
        const float* __restrict__ r = rowp + t * 48;
        float a0 = bdte, a1 = 0.f, a2 = 0.f, a3 = 0.f;
#pragma unroll
        for (int k = 0; k < 4; k++) {
            a0 = fmaf(r[k],      wdt[k],      a0);
            a1 = fmaf(r[k + 4],  wdt[k + 4],  a1);
            a2 = fmaf(r[k + 8],  wdt[k + 8],  a2);
            a3 = fmaf(r[k + 12], wdt[k + 12], a3);
        }
        float acc = (a0 + a1) + (a2 + a3);
        float delta = (acc > 20.f)
            ? acc
            : 0.69314718056f * LOG2F(1.f + EXP2F(acc * 1.44269504f));
        size_t idx = base + (size_t)t * EE;
        float uv = toF(u[idx]);
        float du = delta * uv;
        float y0 = 0.f, y1 = 0.f, y2 = 0.f, y3 = 0.f;
#pragma unroll
        for (int s = 0; s < 16; s += 4) {
            float ad0 = EXP2F(delta * al[s]);
            float ad1 = EXP2F(delta * al[s + 1]);
            float ad2 = EXP2F(delta * al[s + 2]);
            float ad3 = EXP2F(delta * al[s + 3]);
            h[s]     = fmaf(ad0, h[s],     du * r[16 + s]);
            h[s + 1] = fmaf(ad1, h[s + 1], du * r[17 + s]);
            h[s + 2] = fmaf(ad2, h[s + 2], du * r[18 + s]);
            h[s + 3] = fmaf(ad3, h[s + 3], du * r[19 + s]);
            y0 = fmaf(r[32 + s], h[s],     y0);
            y1 = fmaf(r[33 + s], h[s + 1], y1);
            y2 = fmaf(r[34 + s], h[s + 2], y2);
            y3 = fmaf(r[35 + s], h[s + 3], y3);
        }
        float y = (y0 + y1) + (y2 + y3);
        yg[idx] = f2b((y + uv * De) * toF(sg[idx]));
    }
}

// ---------------- prep kernels ------------------------------------------------------
__global__ void cast_k(const float* __restrict__ in, bf16* __restrict__ out, int n) {
    int i = blockIdx.x * 256 + threadIdx.x;
    if (i < n) out[i] = f2b(in[i]);
}
__global__ void transT_k(const float* __restrict__ W, bf16* __restrict__ out, int K, int Nn) {
    int gid = blockIdx.x * 256 + threadIdx.x;
    if (gid >= K * Nn) return;
    int n = gid / K, k = gid - n * K;
    out[gid] = f2b(W[(size_t)k * Nn + n]);
}
__global__ void transmsgs_k(const float* __restrict__ msgs, bf16* __restrict__ msgsT) {
    int gid = blockIdx.x * 256 + threadIdx.x;
    int c = gid >> 10, j = gid & 1023;
    msgsT[gid] = f2b(msgs[(size_t)j * 256 + c]);
}
__global__ void wdbct_k(const float* __restrict__ Wd, const float* __restrict__ WB,
                        const float* __restrict__ WC, bf16* __restrict__ out,
                        const float* __restrict__ bd, const float* __restrict__ bB,
                        const float* __restrict__ bC, float* __restrict__ biascat) {
    int gid = blockIdx.x * 256 + threadIdx.x;
    if (gid < 48) biascat[gid] = (gid < 16) ? bd[gid] : (gid < 32) ? bB[gid - 16] : bC[gid - 32];
    if (gid >= 64 * 512) return;
    int n = gid >> 9, k = gid & 511;
    float v = 0.f;
    if (n < 16)      v = Wd[(size_t)k * 16 + n];
    else if (n < 32) v = WB[(size_t)k * 16 + (n - 16)];
    else if (n < 48) v = WC[(size_t)k * 16 + (n - 32)];
    out[gid] = f2b(v);
}

extern "C" void kernel_launch(void* const* d_in, const int* in_sizes, int n_in,
                              void* d_out, int out_size, void* d_ws, size_t ws_size,
                              hipStream_t stream)
{
    const float* adj   = (const float*)d_in[0];
    const float* pos   = (const float*)d_in[1];
    const float* g1Wm  = (const float*)d_in[2];
    const float* g1bm  = (const float*)d_in[3];
    const float* g1Wq  = (const float*)d_in[4];
    const float* g1Wk  = (const float*)d_in[5];
    const float* g1gb  = (const float*)d_in[6];
    const float* g1Wu  = (const float*)d_in[7];
    const float* g1bu  = (const float*)d_in[8];
    const float* g1lg  = (const float*)d_in[9];
    const float* g1lb  = (const float*)d_in[10];
    const float* g2Wm  = (const float*)d_in[11];
    const float* g2bm  = (const float*)d_in[12];
    const float* g2Wu  = (const float*)d_in[13];
    const float* g2bu  = (const float*)d_in[14];
    const float* g2lg  = (const float*)d_in[15];
    const float* g2lb  = (const float*)d_in[16];
    const float* mlg   = (const float*)d_in[17];
    const float* mlb   = (const float*)d_in[18];
    const float* mWin  = (const float*)d_in[19];
    const float* mbin  = (const float*)d_in[20];
    const float* mWd   = (const float*)d_in[21];
    const float* mbd   = (const float*)d_in[22];
    const float* mWdt  = (const float*)d_in[23];
    const float* mbdt  = (const float*)d_in[24];
    const float* mWB   = (const float*)d_in[25];
    const float* mbB   = (const float*)d_in[26];
    const float* mWC   = (const float*)d_in[27];
    const float* mbC   = (const float*)d_in[28];
    const float* mAlog = (const float*)d_in[29];
    const float* mD    = (const float*)d_in[30];
    const float* mWout = (const float*)d_in[31];
    const float* mbout = (const float*)d_in[32];
    float* out = (float*)d_out;
    char* ws = (char*)d_ws;

    const size_t BIGE = (size_t)TT * NN_ * 256;
    size_t o = 0;
    auto alloc = [&](size_t bytes) { size_t r = o; o += (bytes + 255) & ~(size_t)255; return r; };

    float* msgs  = (float*)(ws + alloc((size_t)NN_ * 256 * 4));
    float* q     = (float*)(ws + alloc((size_t)NN_ * 256 * 4));
    float* kk    = (float*)(ws + alloc((size_t)NN_ * 256 * 4));
    bf16*  gatesb = (bf16*)(ws + alloc((size_t)NN_ * NN_ * 2));
    unsigned long long* adjbits =
        (unsigned long long*)(ws + alloc((size_t)TT * NN_ * NN_ / 8));
    bf16*  Ra    = (bf16*)(ws + alloc(BIGE * 2));                 // agg / xn
    size_t off_x1 = alloc(BIGE * 2);
    bf16*  x1    = (bf16*)(ws + off_x1);
    bf16*  agg2  = (bf16*)(ws + alloc(BIGE * 2));                 // contiguous after x1
    bf16*  x2    = (bf16*)(ws + alloc(BIGE * 2));                 // res, [N,T,H]
    bf16*  yg    = (bf16*)(ws + alloc(BIGE * 2));
    bf16*  sg    = (bf16*)(ws + alloc((size_t)NN_ * TT * EE * 2));
    float* dbc   = (float*)(ws + alloc((size_t)TT * NN_ * 48 * 4));  // [M,48] d1|Bm|Cm
    bf16*  u     = (bf16*)(ws + off_x1);                          // aliases x1+agg2
    // transposed bf16 weights / staging
    bf16* posb   = (bf16*)(ws + alloc((size_t)NN_ * 256 * 2));
    bf16* g1WuT  = (bf16*)(ws + alloc((size_t)256 * 512 * 2));
    bf16* g2WmT  = (bf16*)(ws + alloc((size_t)256 * 256 * 2));
    bf16* g2WuT  = (bf16*)(ws + alloc((size_t)256 * 512 * 2));
    bf16* mWinT  = (bf16*)(ws + alloc((size_t)1024 * 256 * 2));
    bf16* mWoutT = (bf16*)(ws + alloc((size_t)256 * 512 * 2));
    bf16* WdBCT  = (bf16*)(ws + alloc((size_t)64 * 512 * 2));
    float* biascat = (float*)(ws + alloc(64 * 4));
    bf16* msgsT  = (bf16*)(ws + alloc((size_t)256 * 1024 * 2));
    bf16* msgs2T = (bf16*)(ws + alloc(BIGE * 2));

    const unsigned ALLR = 0xFFFFFFFFu;
    const int M = TT * NN_;

    // prep
    packadj_k<<<2048, 256, 0, stream>>>((const float4*)adj, (unsigned int*)adjbits);
    cast_k<<<NN_, 256, 0, stream>>>(pos, posb, NN_ * 256);
    transT_k<<<(512 * 256 + 255) / 256, 256, 0, stream>>>(g1Wu, g1WuT, 512, 256);
    transT_k<<<(256 * 256 + 255) / 256, 256, 0, stream>>>(g2Wm, g2WmT, 256, 256);
    transT_k<<<(512 * 256 + 255) / 256, 256, 0, stream>>>(g2Wu, g2WuT, 512, 256);
    transT_k<<<(256 * 1024 + 255) / 256, 256, 0, stream>>>(mWin, mWinT, 256, 1024);
    transT_k<<<(512 * 256 + 255) / 256, 256, 0, stream>>>(mWout, mWoutT, 512, 256);
    wdbct_k<<<(64 * 512 + 255) / 256, 256, 0, stream>>>(mWd, mWB, mWC, WdBCT, mbd, mbB, mbC, biascat);

    // S0: msgs = pos @ g1_Wm + bm (f32)
    gemm_k<false, EPI_F32><<<dim3(16, 4), 256, 0, stream>>>(
        pos, g1Wm, msgs, g1bm, nullptr, 1.f, NN_, 256, 256, 256, 256);
    transmsgs_k<<<1024, 256, 0, stream>>>(msgs, msgsT);
    // S1: q, k
    gemm_k<false, EPI_F32><<<dim3(16, 4), 256, 0, stream>>>(
        msgs, g1Wq, q, nullptr, nullptr, 1.f, NN_, 256, 256, 256, 256);
    gemm_k<false, EPI_F32><<<dim3(16, 4), 256, 0, stream>>>(
        msgs, g1Wk, kk, nullptr, nullptr, 1.f, NN_, 256, 256, 256, 256);
    // S2: gates = sigmoid(q @ k^T / 16 + gb) -> bf16
    gemm_k<true, EPI_SIG_B16><<<dim3(16, 16), 256, 0, stream>>>(
        q, kk, (float*)gatesb, nullptr, g1gb, 1.f / 16.f, NN_, NN_, 256, 256, 256);
    // S3: agg -> Ra
    aggmm_k<true><<<512, 256, 0, stream>>>(
        (const unsigned char*)adjbits, gatesb, msgsT, Ra);
    // S4(+S5): x1 = LN(relu(cat(posb,Ra) @ Wu1 + bu1))
    mfma_k<64, 256, true, E_LN1><<<dim3(1024, 1), 256, 0, stream>>>(
        posb, Ra, 1023u, g1WuT, g1bu, nullptr, x1, nullptr,
        g1lg, g1lb, nullptr, nullptr, nullptr, M, 512);
    // S6: msgs2 = x1 @ Wm2 + bm2 -> msgs2T ([t][c][j])  (64x128 wave tile)
    mfma2_k<E_BF16T><<<dim3(512, 1), 256, 0, stream>>>(
        x1, g2WmT, g2bm, nullptr, msgs2T, nullptr, nullptr, 256);
    // S7: agg2 = adj @ msgs2
    aggmm_k<false><<<512, 256, 0, stream>>>(
        (const unsigned char*)adjbits, nullptr, msgs2T, agg2);
    // S8(+S9+S10): x2 = LN(relu(cat(x1,agg2)@Wu2+bu2)) [N,T,H], xn = LN2 -> Ra [N,T,H]
    mfma_k<64, 256, true, E_LN2><<<dim3(1024, 1), 256, 0, stream>>>(
        x1, agg2, ALLR, g2WuT, g2bu, nullptr, x2, Ra,
        g2lg, g2lb, mlg, mlb, nullptr, M, 512);
    // S11: u/sg = silu halves of xn @ Win + bin  (64x128 wave tile)
    mfma2_k<E_SILU><<<dim3(512, 4), 256, 0, stream>>>(
        Ra, mWinT, mbin, nullptr, u, sg, nullptr, 256);
    // S12 fused: dbc = u @ [Wd|WB|WC] + biases  ([M,48] interleaved)
    mfma_k<256, 64, false, E_TRI><<<dim3(256, 1), 256, 0, stream>>>(
        u, u, ALLR, WdBCT, biascat, dbc, nullptr, nullptr,
        nullptr, nullptr, nullptr, nullptr, nullptr, M, 512);
    // S13: selective scan -> yg  (block per (n, e-half))
    scan_k<<<dim3(NN_, 2), 256, 0, stream>>>(u, sg, dbc, mWdt, mbdt, mAlog, mD, yg);
    // S14: out = yg @ Wout + bout + res -> [T,N,H] f32  (64x128 wave tile)
    mfma2_k<E_OUT><<<dim3(512, 1), 256, 0, stream>>>(
        yg, mWoutT, mbout, out, nullptr, nullptr, x2, 512);

    (void)in_sizes; (void)n_in; (void)out_size; (void)ws_size;
}

// Round 6
// 1029.517 us; speedup vs baseline: 1.0354x; 1.0354x over previous
//
#include <hip/hip_runtime.h>
#include <hip/hip_bf16.h>

typedef __hip_bfloat16 bf16;
typedef __attribute__((ext_vector_type(8))) short s16x8;
typedef __attribute__((ext_vector_type(4))) short s16x4;
typedef __attribute__((ext_vector_type(4))) float f32x4;

#define TT 64
#define NN_ 1024
#define EE 512

__device__ __forceinline__ float toF(float v) { return v; }
__device__ __forceinline__ float toF(bf16 v) { return __bfloat162float(v); }
__device__ __forceinline__ bf16 f2b(float v) { return __float2bfloat16(v); }

#if __has_builtin(__builtin_amdgcn_exp2f)
#define EXP2F(x) __builtin_amdgcn_exp2f(x)
#else
#define EXP2F(x) exp2f(x)
#endif
#if __has_builtin(__builtin_amdgcn_logf)
#define LOG2F(x) __builtin_amdgcn_logf(x)
#else
#define LOG2F(x) log2f(x)
#endif

enum { EPI_F32 = 0, EPI_SIG_F32 = 1, EPI_SIG_B16 = 2 };
enum { E_LN1 = 0, E_BF16 = 1, E_LN2 = 2, E_SILU = 3, E_OUT = 4, E_TRI = 5, E_BF16T = 6 };

// ---------------- small fp32 tiled GEMM (S0/S2; 1024-row problems) ------------------
template <bool TRANSB, int EPI>
__global__ __launch_bounds__(256) void gemm_k(
    const float* __restrict__ A, const float* __restrict__ B,
    float* __restrict__ outF, const float* __restrict__ bias,
    const float* __restrict__ sbeta, float alpha,
    int M, int Nn, int K, int lda, int ldb)
{
    __shared__ float As[16][68];
    __shared__ float Bs[16][68];
    const int tid = threadIdx.x;
    const int tx = tid & 15, ty = tid >> 4;
    const int m0 = blockIdx.x * 64, n0 = blockIdx.y * 64;
    float acc[4][4] = {};

    for (int k0 = 0; k0 < K; k0 += 16) {
        {
            int row = tid >> 2, kk0 = (tid & 3) * 4, grow = m0 + row;
#pragma unroll
            for (int j = 0; j < 4; j++) {
                int kk = kk0 + j, gk = k0 + kk;
                As[kk][row] = (grow < M) ? A[(size_t)grow * lda + gk] : 0.f;
            }
        }
        if (!TRANSB) {
            int kk = tid >> 4, c0 = (tid & 15) * 4;
#pragma unroll
            for (int j = 0; j < 4; j++) {
                int col = c0 + j, gn = n0 + col;
                Bs[kk][col] = (gn < Nn) ? B[(size_t)(k0 + kk) * ldb + gn] : 0.f;
            }
        } else {
            int col = tid >> 2, kk0 = (tid & 3) * 4, gn = n0 + col;
#pragma unroll
            for (int j = 0; j < 4; j++) {
                int kk = kk0 + j;
                Bs[kk][col] = (gn < Nn) ? B[(size_t)gn * ldb + (k0 + kk)] : 0.f;
            }
        }
        __syncthreads();
#pragma unroll
        for (int kk = 0; kk < 16; kk++) {
            float a[4], b[4];
#pragma unroll
            for (int i = 0; i < 4; i++) a[i] = As[kk][ty * 4 + i];
#pragma unroll
            for (int j = 0; j < 4; j++) b[j] = Bs[kk][tx * 4 + j];
#pragma unroll
            for (int i = 0; i < 4; i++)
#pragma unroll
                for (int j = 0; j < 4; j++)
                    acc[i][j] = fmaf(a[i], b[j], acc[i][j]);
        }
        __syncthreads();
    }

    float gb = (EPI != EPI_F32 && sbeta) ? sbeta[0] : 0.f;
#pragma unroll
    for (int i = 0; i < 4; i++) {
        int row = m0 + ty * 4 + i;
        if (row >= M) continue;
#pragma unroll
        for (int j = 0; j < 4; j++) {
            int col = n0 + tx * 4 + j;
            if (col >= Nn) continue;
            float v = acc[i][j];
            if (EPI == EPI_F32) {
                if (bias) v += bias[col];
                outF[(size_t)row * Nn + col] = v;
            } else if (EPI == EPI_SIG_F32) {
                v = v * alpha + gb;
                outF[(size_t)row * Nn + col] = 1.f / (1.f + __expf(-v));
            } else {
                v = v * alpha + gb;
                ((bf16*)outF)[(size_t)row * Nn + col] = f2b(1.f / (1.f + __expf(-v)));
            }
        }
    }
}

// ---------------- S1 fused: q AND k in one launch (grid 16x8) -----------------------
// blockIdx.y < 4 -> q = msgs@Wq ; else k = msgs@Wk. Same math as two gemm_k calls.
__global__ __launch_bounds__(256) void gemmqk_k(
    const float* __restrict__ A, const float* __restrict__ Bq,
    const float* __restrict__ Bk, float* __restrict__ outq, float* __restrict__ outk)
{
    __shared__ float As[16][68];
    __shared__ float Bs[16][68];
    const float* __restrict__ B = (blockIdx.y < 4) ? Bq : Bk;
    float* __restrict__ outF = (blockIdx.y < 4) ? outq : outk;
    const int tid = threadIdx.x;
    const int tx = tid & 15, ty = tid >> 4;
    const int m0 = blockIdx.x * 64, n0 = (blockIdx.y & 3) * 64;
    float acc[4][4] = {};

    for (int k0 = 0; k0 < 256; k0 += 16) {
        {
            int row = tid >> 2, kk0 = (tid & 3) * 4, grow = m0 + row;
#pragma unroll
            for (int j = 0; j < 4; j++) {
                int kk = kk0 + j;
                As[kk][row] = A[(size_t)grow * 256 + k0 + kk];
            }
        }
        {
            int kk = tid >> 4, c0 = (tid & 15) * 4;
#pragma unroll
            for (int j = 0; j < 4; j++) {
                int col = c0 + j;
                Bs[kk][col] = B[(size_t)(k0 + kk) * 256 + n0 + col];
            }
        }
        __syncthreads();
#pragma unroll
        for (int kk = 0; kk < 16; kk++) {
            float a[4], b[4];
#pragma unroll
            for (int i = 0; i < 4; i++) a[i] = As[kk][ty * 4 + i];
#pragma unroll
            for (int j = 0; j < 4; j++) b[j] = Bs[kk][tx * 4 + j];
#pragma unroll
            for (int i = 0; i < 4; i++)
#pragma unroll
                for (int j = 0; j < 4; j++)
                    acc[i][j] = fmaf(a[i], b[j], acc[i][j]);
        }
        __syncthreads();
    }
#pragma unroll
    for (int i = 0; i < 4; i++) {
        int row = m0 + ty * 4 + i;
#pragma unroll
        for (int j = 0; j < 4; j++) {
            int col = n0 + tx * 4 + j;
            outF[(size_t)row * 256 + col] = acc[i][j];
        }
    }
}

// ---------------- MFMA bf16 GEMM, 64x64 wave tile (LN / TRI epilogues) ---------------
template <int BM, int BN, bool CAT, int EPI>
__global__ __launch_bounds__(256) void mfma_k(
    const bf16* __restrict__ A1, const bf16* __restrict__ A2, unsigned rowmask,
    const bf16* __restrict__ BT, const float* __restrict__ bias,
    float* __restrict__ outF,
    bf16* __restrict__ outB, bf16* __restrict__ outB2,
    const float* __restrict__ g1, const float* __restrict__ b1,
    const float* __restrict__ g2, const float* __restrict__ b2,
    const bf16* __restrict__ resid,
    int M, int K)
{
    constexpr bool LN = (EPI == E_LN1 || EPI == E_LN2);
    constexpr int STAGE_B = (BM * 32 + BN * 32) * 2;
    constexpr int SB = LN ? (64 * 260 * 4) : STAGE_B;
    __shared__ __align__(16) char smem[SB];
    short* As = (short*)smem;
    short* Bs = As + BM * 32;
    float* Cs = (float*)smem;   // LN epilogue reuses staging LDS

    const int tid = threadIdx.x;
    const int wid = tid >> 6, lane = tid & 63;
    const int wr = (BN == 256) ? 0 : wid;
    const int wc = (BN == 256) ? wid : 0;
    const int m0 = blockIdx.x * BM, n0 = blockIdx.y * BN;
    const int srow = tid >> 2;
    const int skoff = (tid & 3) * 8;

    f32x4 acc[4][4] = {};
    s16x8 pa[BM / 64], pbv[BN / 64];

    auto LOADT = [&](int k0) {
#pragma unroll
        for (int c = 0; c < BM / 64; c++) {
            int r = c * 64 + srow;
            int gr = m0 + r;
            const bf16* p;
            if (CAT) {
                int gk = k0 + skoff;
                p = (gk < 256) ? (A1 + (size_t)(gr & rowmask) * 256 + gk)
                               : (A2 + (size_t)gr * 256 + (gk - 256));
            } else {
                p = A1 + (size_t)gr * K + k0 + skoff;
            }
            pa[c] = *(const s16x8*)p;
        }
#pragma unroll
        for (int c = 0; c < BN / 64; c++) {
            int r = c * 64 + srow;
            pbv[c] = *(const s16x8*)(BT + (size_t)(n0 + r) * K + k0 + skoff);
        }
    };

    LOADT(0);
#pragma unroll 1
    for (int k0 = 0; k0 < K; k0 += 32) {
#pragma unroll
        for (int c = 0; c < BM / 64; c++)
            *(s16x8*)&As[(c * 64 + srow) * 32 + skoff] = pa[c];
#pragma unroll
        for (int c = 0; c < BN / 64; c++)
            *(s16x8*)&Bs[(c * 64 + srow) * 32 + skoff] = pbv[c];
        __syncthreads();
        if (k0 + 32 < K) LOADT(k0 + 32);   // next tile in flight during MFMA
        s16x8 af[4], bf[4];
#pragma unroll
        for (int mi = 0; mi < 4; mi++)
            af[mi] = *(s16x8*)&As[(wr * 64 + mi * 16 + (lane & 15)) * 32 + (lane >> 4) * 8];
#pragma unroll
        for (int ni = 0; ni < 4; ni++)
            bf[ni] = *(s16x8*)&Bs[(wc * 64 + ni * 16 + (lane & 15)) * 32 + (lane >> 4) * 8];
#pragma unroll
        for (int mi = 0; mi < 4; mi++)
#pragma unroll
            for (int ni = 0; ni < 4; ni++)
                acc[mi][ni] = __builtin_amdgcn_mfma_f32_16x16x32_bf16(
                    af[mi], bf[ni], acc[mi][ni], 0, 0, 0);
        __syncthreads();
    }

    if (EPI == E_TRI) {
        // dbc[M,48]: cols 0-15 d1, 16-31 Bm, 32-47 Cm
#pragma unroll
        for (int mi = 0; mi < 4; mi++)
#pragma unroll
            for (int ni = 0; ni < 4; ni++)
#pragma unroll
                for (int r = 0; r < 4; r++) {
                    int row = m0 + wid * 64 + mi * 16 + (lane >> 4) * 4 + r;
                    int col = ni * 16 + (lane & 15);
                    if (col < 48) {
                        float v = acc[mi][ni][r] + bias[col];
                        outF[(size_t)row * 48 + col] = v;
                    }
                }
    } else {
        // E_LN1 / E_LN2: relu -> Cs, then row LN(s). BM=64, BN=256, grid.y=1.
#pragma unroll
        for (int mi = 0; mi < 4; mi++)
#pragma unroll
            for (int ni = 0; ni < 4; ni++)
#pragma unroll
                for (int r = 0; r < 4; r++) {
                    int rl = mi * 16 + (lane >> 4) * 4 + r;
                    int cl = wc * 64 + ni * 16 + (lane & 15);
                    Cs[rl * 260 + cl] = fmaxf(acc[mi][ni][r] + bias[cl], 0.f);
                }
        __syncthreads();
        float g1v[4], b1v[4], g2v[4], b2v[4];
#pragma unroll
        for (int i = 0; i < 4; i++) {
            g1v[i] = g1[lane * 4 + i];
            b1v[i] = b1[lane * 4 + i];
            if (EPI == E_LN2) { g2v[i] = g2[lane * 4 + i]; b2v[i] = b2[lane * 4 + i]; }
        }
        for (int rr = 0; rr < 16; rr++) {
            int rl = wid * 16 + rr;
            int grow = m0 + rl;
            float x[4];
#pragma unroll
            for (int i = 0; i < 4; i++) x[i] = Cs[rl * 260 + lane * 4 + i];
            float s = x[0] + x[1] + x[2] + x[3];
#pragma unroll
            for (int o = 1; o < 64; o <<= 1) s += __shfl_xor(s, o, 64);
            float mu = s * (1.f / 256.f);
            float d[4], ss = 0.f;
#pragma unroll
            for (int i = 0; i < 4; i++) { d[i] = x[i] - mu; ss = fmaf(d[i], d[i], ss); }
#pragma unroll
            for (int o = 1; o < 64; o <<= 1) ss += __shfl_xor(ss, o, 64);
            float inv = rsqrtf(fmaxf(ss * (1.f / 256.f), 0.f) + 1e-5f);
            float y[4];
#pragma unroll
            for (int i = 0; i < 4; i++) y[i] = d[i] * inv * g1v[i] + b1v[i];
            if (EPI == E_LN1) {
                __align__(8) bf16 pk[4];
#pragma unroll
                for (int i = 0; i < 4; i++) pk[i] = f2b(y[i]);
                *(s16x4*)&outB[(size_t)grow * 256 + lane * 4] = *(s16x4*)pk;
            } else {
                int trow = (grow & 1023) * 64 + (grow >> 10);   // [N,T] order
                __align__(8) bf16 pk[4];
#pragma unroll
                for (int i = 0; i < 4; i++) pk[i] = f2b(y[i]);
                *(s16x4*)&outB[(size_t)trow * 256 + lane * 4] = *(s16x4*)pk;
                float s2 = y[0] + y[1] + y[2] + y[3];
#pragma unroll
                for (int o = 1; o < 64; o <<= 1) s2 += __shfl_xor(s2, o, 64);
                float mu2 = s2 * (1.f / 256.f);
                float d2[4], ss2 = 0.f;
#pragma unroll
                for (int i = 0; i < 4; i++) { d2[i] = y[i] - mu2; ss2 = fmaf(d2[i], d2[i], ss2); }
#pragma unroll
                for (int o = 1; o < 64; o <<= 1) ss2 += __shfl_xor(ss2, o, 64);
                float inv2 = rsqrtf(fmaxf(ss2 * (1.f / 256.f), 0.f) + 1e-5f);
                __align__(8) bf16 pk2[4];
#pragma unroll
                for (int i = 0; i < 4; i++) pk2[i] = f2b(d2[i] * inv2 * g2v[i] + b2v[i]);
                *(s16x4*)&outB2[(size_t)trow * 256 + lane * 4] = *(s16x4*)pk2;
            }
        }
    }
}

// ---------------- MFMA bf16 GEMM, 64x128 wave tile (S6/S11/S14) ----------------------
template <int EPI>
__global__ __launch_bounds__(256, 2) void mfma2_k(
    const bf16* __restrict__ A, const bf16* __restrict__ BT,
    const float* __restrict__ bias,
    float* __restrict__ outF, bf16* __restrict__ outB, bf16* __restrict__ outB2,
    const bf16* __restrict__ resid,
    int K)
{
    constexpr int STAGE_B = (128 * 40 + 256 * 40) * 2;          // 30720
    constexpr int TRB = (EPI == E_BF16T) ? (64 * 268 * 2) : 0;  // 34304
    constexpr int SB = STAGE_B > TRB ? STAGE_B : TRB;
    __shared__ __align__(16) char smem[SB];
    short* As = (short*)smem;
    short* Bs = As + 128 * 40;

    const int tid = threadIdx.x;
    const int wid = tid >> 6, lane = tid & 63;
    const int wr = wid & 1;          // wave rows: wr*64
    const int wc = wid >> 1;         // wave cols: wc*128
    const int m0 = blockIdx.x * 128, n0 = blockIdx.y * 256;
    const int srow = tid >> 2;       // 0..63
    const int skoff = (tid & 3) * 8; // 0,8,16,24

    f32x4 acc[4][8] = {};
    s16x8 pa[2], pb[4];

    auto LOADT = [&](int k0) {
#pragma unroll
        for (int c = 0; c < 2; c++)
            pa[c] = *(const s16x8*)(A + (size_t)(m0 + c * 64 + srow) * K + k0 + skoff);
#pragma unroll
        for (int c = 0; c < 4; c++)
            pb[c] = *(const s16x8*)(BT + (size_t)(n0 + c * 64 + srow) * K + k0 + skoff);
    };

    LOADT(0);
#pragma unroll 1
    for (int k0 = 0; k0 < K; k0 += 32) {
#pragma unroll
        for (int c = 0; c < 2; c++)
            *(s16x8*)&As[(c * 64 + srow) * 40 + skoff] = pa[c];
#pragma unroll
        for (int c = 0; c < 4; c++)
            *(s16x8*)&Bs[(c * 64 + srow) * 40 + skoff] = pb[c];
        __syncthreads();
        if (k0 + 32 < K) LOADT(k0 + 32);   // next tile in flight during MFMA
        s16x8 af[4];
#pragma unroll
        for (int mi = 0; mi < 4; mi++)
            af[mi] = *(s16x8*)&As[(wr * 64 + mi * 16 + (lane & 15)) * 40 + (lane >> 4) * 8];
#pragma unroll
        for (int ni = 0; ni < 8; ni++) {
            s16x8 bfv = *(s16x8*)&Bs[(wc * 128 + ni * 16 + (lane & 15)) * 40 + (lane >> 4) * 8];
#pragma unroll
            for (int mi = 0; mi < 4; mi++)
                acc[mi][ni] = __builtin_amdgcn_mfma_f32_16x16x32_bf16(
                    af[mi], bfv, acc[mi][ni], 0, 0, 0);
        }
        __syncthreads();
    }

    if (EPI == E_SILU) {
#pragma unroll
        for (int mi = 0; mi < 4; mi++)
#pragma unroll
            for (int ni = 0; ni < 8; ni++)
#pragma unroll
                for (int r = 0; r < 4; r++) {
                    int row = m0 + wr * 64 + mi * 16 + (lane >> 4) * 4 + r;
                    int col = n0 + wc * 128 + ni * 16 + (lane & 15);
                    float v = acc[mi][ni][r] + bias[col];
                    float s = v / (1.f + __expf(-v));
                    if (col < EE) outB[(size_t)row * EE + col] = f2b(s);
                    else          outB2[(size_t)row * EE + (col - EE)] = f2b(s);
                }
    } else if (EPI == E_OUT) {
#pragma unroll
        for (int mi = 0; mi < 4; mi++)
#pragma unroll
            for (int ni = 0; ni < 8; ni++)
#pragma unroll
                for (int r = 0; r < 4; r++) {
                    int row = m0 + wr * 64 + mi * 16 + (lane >> 4) * 4 + r;
                    int col = n0 + wc * 128 + ni * 16 + (lane & 15);
                    float v = acc[mi][ni][r] + bias[col] + toF(resid[(size_t)row * 256 + col]);
                    int t = row & 63, n = row >> 6;
                    outF[((size_t)t * NN_ + n) * 256 + col] = v;
                }
    } else {
        // E_BF16T: rows r = t*1024+j -> store transposed [t][col][j].
        short* Ts = (short*)smem;
#pragma unroll 1
        for (int h = 0; h < 2; h++) {
            if (h) __syncthreads();      // protect previous half's reads
            if (wr == h) {
#pragma unroll
                for (int mi = 0; mi < 4; mi++)
#pragma unroll
                    for (int ni = 0; ni < 8; ni++)
#pragma unroll
                        for (int r = 0; r < 4; r++) {
                            int rl = mi * 16 + (lane >> 4) * 4 + r;
                            int cl = wc * 128 + ni * 16 + (lane & 15);
                            union { bf16 b; short s; } u;
                            u.b = f2b(acc[mi][ni][r] + bias[n0 + cl]);
                            Ts[rl * 268 + cl] = u.s;
                        }
            }
            __syncthreads();
            const int col = tid;
            const int rowbase = m0 + h * 64;
            size_t dbase = (((size_t)(rowbase >> 10)) * 256 + (n0 + col)) * 1024 + (rowbase & 1023);
#pragma unroll
            for (int j0 = 0; j0 < 64; j0 += 8) {
                s16x8 v;
#pragma unroll
                for (int i = 0; i < 8; i++) v[i] = Ts[(j0 + i) * 268 + col];
                *(s16x8*)&outB[dbase + j0] = v;
            }
        }
    }
}

// ---------------- adj bit-pack: adj in {0,1} -> 1 bit/elem (268MB -> 8.4MB) --------
__global__ __launch_bounds__(256) void packadj_k(
    const float4* __restrict__ adj4, unsigned int* __restrict__ bits32)
{
    const size_t nwords = (size_t)TT * NN_ * NN_ / 32;   // 2,097,152
    const size_t stride = (size_t)gridDim.x * 256;
    for (size_t w = (size_t)blockIdx.x * 256 + threadIdx.x; w < nwords; w += stride) {
        const float4* __restrict__ p = adj4 + w * 8;
        float4 v[8];
#pragma unroll
        for (int i = 0; i < 8; i++) v[i] = p[i];
        unsigned int m = 0;
#pragma unroll
        for (int i = 0; i < 8; i++) {
            m |= (v[i].x != 0.f ? 1u : 0u) << (4 * i);
            m |= (v[i].y != 0.f ? 2u : 0u) << (4 * i);
            m |= (v[i].z != 0.f ? 4u : 0u) << (4 * i);
            m |= (v[i].w != 0.f ? 8u : 0u) << (4 * i);
        }
        bits32[w] = m;
    }
}

// ---------------- dense MFMA aggregation via bitmask -------------------------------
template <bool GATED>
__global__ __launch_bounds__(256, 2) void aggmm_k(
    const unsigned char* __restrict__ adjbits, const bf16* __restrict__ gatesb,
    const bf16* __restrict__ BTsrc, bf16* __restrict__ out)
{
    __shared__ __align__(16) short As[128 * 40];
    __shared__ __align__(16) short Bs[256 * 40];
    const int tid = threadIdx.x;
    const int wid = tid >> 6, lane = tid & 63;
    const int wr = wid & 1;          // wave rows: wr*64
    const int wc = wid >> 1;         // wave cols: wc*128
    const int bx = blockIdx.x;
    const int t = bx >> 3, n0 = (bx & 7) * 128;
    const int srow = tid >> 2;       // 0..63
    const int skoff = (tid & 3) * 8; // 0,8,16,24

    const unsigned char* __restrict__ abB =
        adjbits + ((size_t)t * 1024 + n0) * 128 + (tid & 3);
    const bf16* __restrict__ gB = GATED ? (gatesb + (size_t)n0 * 1024 + skoff) : nullptr;
    const bf16* __restrict__ bt = GATED ? BTsrc : (BTsrc + (size_t)t * 256 * 1024);
    const size_t orow0 = (size_t)t * 1024 + n0;

    f32x4 acc[4][8] = {};

    unsigned char pm[2];
    s16x8 pg[2];
    s16x8 pb[4];

    auto LOADA = [&](int k0) {
#pragma unroll
        for (int c = 0; c < 2; c++) {
            int r = c * 64 + srow;
            pm[c] = abB[(size_t)r * 128 + (k0 >> 3)];
            if (GATED) pg[c] = *(const s16x8*)(gB + (size_t)r * 1024 + k0);
        }
#pragma unroll
        for (int c = 0; c < 4; c++)
            pb[c] = *(const s16x8*)(bt + (size_t)(c * 64 + srow) * 1024 + k0 + skoff);
    };
    auto STORE = [&]() {
#pragma unroll
        for (int c = 0; c < 2; c++) {
            unsigned m = pm[c];
            s16x8 tmp;
            if (GATED) {
#pragma unroll
                for (int i = 0; i < 8; i++) tmp[i] = ((m >> i) & 1) ? pg[c][i] : (short)0;
            } else {
#pragma unroll
                for (int i = 0; i < 8; i++) tmp[i] = ((m >> i) & 1) ? (short)0x3F80 : (short)0;
            }
            *(s16x8*)&As[(c * 64 + srow) * 40 + skoff] = tmp;
        }
#pragma unroll
        for (int c = 0; c < 4; c++)
            *(s16x8*)&Bs[(c * 64 + srow) * 40 + skoff] = pb[c];
    };

    LOADA(0);
#pragma unroll 1
    for (int k0 = 0; k0 < 1024; k0 += 32) {
        STORE();
        __syncthreads();
        if (k0 + 32 < 1024) LOADA(k0 + 32);   // next tile in flight during MFMA
        s16x8 af[4];
#pragma unroll
        for (int mi = 0; mi < 4; mi++)
            af[mi] = *(s16x8*)&As[(wr * 64 + mi * 16 + (lane & 15)) * 40 + (lane >> 4) * 8];
#pragma unroll
        for (int ni = 0; ni < 8; ni++) {
            s16x8 bfv = *(s16x8*)&Bs[(wc * 128 + ni * 16 + (lane & 15)) * 40 + (lane >> 4) * 8];
#pragma unroll
            for (int mi = 0; mi < 4; mi++)
                acc[mi][ni] = __builtin_amdgcn_mfma_f32_16x16x32_bf16(
                    af[mi], bfv, acc[mi][ni], 0, 0, 0);
        }
        __syncthreads();
    }

#pragma unroll
    for (int mi = 0; mi < 4; mi++)
#pragma unroll
        for (int ni = 0; ni < 8; ni++)
#pragma unroll
            for (int r = 0; r < 4; r++) {
                int rowl = wr * 64 + mi * 16 + (lane >> 4) * 4 + r;
                int col = wc * 128 + ni * 16 + (lane & 15);
                out[(orow0 + rowl) * 256 + col] = f2b(acc[mi][ni][r]);
            }
}

// ---------------- Mamba selective scan: 2 independent n-streams per thread ----------
// Block = (n-pair, e-half). Streams share al[]/wdt[] (same e); two h-states double
// ILP on VALU+trans pipes, hiding each stream's exp2->fma dependency chain in the
// other's issue slots. Per-stream arithmetic identical to the 1-stream version.
__global__ __launch_bounds__(256) void scan_k(
    const bf16* __restrict__ u, const bf16* __restrict__ sg,
    const float* __restrict__ dbc,
    const float* __restrict__ Wdt, const float* __restrict__ bdt,
    const float* __restrict__ Alog, const float* __restrict__ D,
    bf16* __restrict__ yg)
{
    const int n0 = blockIdx.x * 2, e = blockIdx.y * 256 + threadIdx.x;
    float al[16], wdt[16], h0[16], h1[16];
#pragma unroll
    for (int s = 0; s < 16; s++) {
        al[s] = -__expf(Alog[e * 16 + s]) * 1.44269504f;   // * log2(e)
        h0[s] = 0.f; h1[s] = 0.f;
    }
#pragma unroll
    for (int k = 0; k < 16; k++) wdt[k] = Wdt[(size_t)k * EE + e];
    const float bdte = bdt[e], De = D[e];
    const float* __restrict__ r0p = dbc + (size_t)n0 * TT * 48;
    const float* __restrict__ r1p = r0p + TT * 48;
    const size_t base0 = (size_t)n0 * TT * EE + e;
    const size_t base1 = base0 + (size_t)TT * EE;
#pragma unroll 1
    for (int t = 0; t < TT; t++) {
        const float* __restrict__ r0 = r0p + t * 48;
        const float* __restrict__ r1 = r1p + t * 48;
        float a00 = bdte, a01 = 0.f, a10 = bdte, a11 = 0.f;
#pragma unroll
        for (int k = 0; k < 8; k++) {
            a00 = fmaf(r0[k],     wdt[k],     a00);
            a01 = fmaf(r0[k + 8], wdt[k + 8], a01);
            a10 = fmaf(r1[k],     wdt[k],     a10);
            a11 = fmaf(r1[k + 8], wdt[k + 8], a11);
        }
        float acc0 = a00 + a01, acc1 = a10 + a11;
        float delta0 = (acc0 > 20.f)
            ? acc0 : 0.69314718056f * LOG2F(1.f + EXP2F(acc0 * 1.44269504f));
        float delta1 = (acc1 > 20.f)
            ? acc1 : 0.69314718056f * LOG2F(1.f + EXP2F(acc1 * 1.44269504f));
        size_t idx0 = base0 + (size_t)t * EE;
        size_t idx1 = base1 + (size_t)t * EE;
        float uv0 = toF(u[idx0]), uv1 = toF(u[idx1]);
        float du0 = delta0 * uv0, du1 = delta1 * uv1;
        float y00 = 0.f, y01 = 0.f, y10 = 0.f, y11 = 0.f;
#pragma unroll
        for (int s = 0; s < 16; s += 2) {
            float ad00 = EXP2F(delta0 * al[s]);
            float ad01 = EXP2F(delta0 * al[s + 1]);
            float ad10 = EXP2F(delta1 * al[s]);
            float ad11 = EXP2F(delta1 * al[s + 1]);
            h0[s]     = fmaf(ad00, h0[s],     du0 * r0[16 + s]);
            h0[s + 1] = fmaf(ad01, h0[s + 1], du0 * r0[17 + s]);
            h1[s]     = fmaf(ad10, h1[s],     du1 * r1[16 + s]);
            h1[s + 1] = fmaf(ad11, h1[s + 1], du1 * r1[17 + s]);
            y00 = fmaf(r0[32 + s], h0[s],     y00);
            y01 = fmaf(r0[33 + s], h0[s + 1], y01);
            y10 = fmaf(r1[32 + s], h1[s],     y10);
            y11 = fmaf(r1[33 + s], h1[s + 1], y11);
        }
        float y0 = y00 + y01, y1 = y10 + y11;
        yg[idx0] = f2b((y0 + uv0 * De) * toF(sg[idx0]));
        yg[idx1] = f2b((y1 + uv1 * De) * toF(sg[idx1]));
    }
}

// ---------------- fused prep: cast + 4x transT + wdbct in one launch ----------------
__global__ __launch_bounds__(256) void prep_all_k(
    const float* __restrict__ pos,
    const float* __restrict__ g1Wu, const float* __restrict__ g2Wm,
    const float* __restrict__ g2Wu, const float* __restrict__ mWin,
    const float* __restrict__ mWout,
    const float* __restrict__ Wd, const float* __restrict__ WB,
    const float* __restrict__ WC, const float* __restrict__ bd,
    const float* __restrict__ bB, const float* __restrict__ bC,
    bf16* __restrict__ posb, bf16* __restrict__ g1WuT, bf16* __restrict__ g2WmT,
    bf16* __restrict__ g2WuT, bf16* __restrict__ mWinT, bf16* __restrict__ mWoutT,
    bf16* __restrict__ WdBCT, float* __restrict__ biascat)
{
    const int total = 262144 + 131072 + 65536 + 131072 + 262144 + 131072 + 32768 + 48;
    for (int gid = blockIdx.x * 256 + threadIdx.x; gid < total; gid += gridDim.x * 256) {
        int g = gid;
        if (g < 262144) { posb[g] = f2b(pos[g]); continue; }
        g -= 262144;
        if (g < 131072) { int n = g >> 9, k = g & 511; g1WuT[g] = f2b(g1Wu[(size_t)k * 256 + n]); continue; }
        g -= 131072;
        if (g < 65536)  { int n = g >> 8, k = g & 255; g2WmT[g] = f2b(g2Wm[(size_t)k * 256 + n]); continue; }
        g -= 65536;
        if (g < 131072) { int n = g >> 9, k = g & 511; g2WuT[g] = f2b(g2Wu[(size_t)k * 256 + n]); continue; }
        g -= 131072;
        if (g < 262144) { int n = g >> 8, k = g & 255; mWinT[g] = f2b(mWin[(size_t)k * 1024 + n]); continue; }
        g -= 262144;
        if (g < 131072) { int n = g >> 9, k = g & 511; mWoutT[g] = f2b(mWout[(size_t)k * 256 + n]); continue; }
        g -= 131072;
        if (g < 32768) {
            int n = g >> 9, k = g & 511;
            float v = 0.f;
            if (n < 16)      v = Wd[(size_t)k * 16 + n];
            else if (n < 32) v = WB[(size_t)k * 16 + (n - 16)];
            else if (n < 48) v = WC[(size_t)k * 16 + (n - 32)];
            WdBCT[g] = f2b(v);
            continue;
        }
        g -= 32768;
        biascat[g] = (g < 16) ? bd[g] : (g < 32) ? bB[g - 16] : bC[g - 32];
    }
}

__global__ void transmsgs_k(const float* __restrict__ msgs, bf16* __restrict__ msgsT) {
    int gid = blockIdx.x * 256 + threadIdx.x;
    int c = gid >> 10, j = gid & 1023;
    msgsT[gid] = f2b(msgs[(size_t)j * 256 + c]);
}

extern "C" void kernel_launch(void* const* d_in, const int* in_sizes, int n_in,
                              void* d_out, int out_size, void* d_ws, size_t ws_size,
                              hipStream_t stream)
{
    const float* adj   = (const float*)d_in[0];
    const float* pos   = (const float*)d_in[1];
    const float* g1Wm  = (const float*)d_in[2];
    const float* g1bm  = (const float*)d_in[3];
    const float* g1Wq  = (const float*)d_in[4];
    const float* g1Wk  = (const float*)d_in[5];
    const float* g1gb  = (const float*)d_in[6];
    const float* g1Wu  = (const float*)d_in[7];
    const float* g1bu  = (const float*)d_in[8];
    const float* g1lg  = (const float*)d_in[9];
    const float* g1lb  = (const float*)d_in[10];
    const float* g2Wm  = (const float*)d_in[11];
    const float* g2bm  = (const float*)d_in[12];
    const float* g2Wu  = (const float*)d_in[13];
    const float* g2bu  = (const float*)d_in[14];
    const float* g2lg  = (const float*)d_in[15];
    const float* g2lb  = (const float*)d_in[16];
    const float* mlg   = (const float*)d_in[17];
    const float* mlb   = (const float*)d_in[18];
    const float* mWin  = (const float*)d_in[19];
    const float* mbin  = (const float*)d_in[20];
    const float* mWd   = (const float*)d_in[21];
    const float* mbd   = (const float*)d_in[22];
    const float* mWdt  = (const float*)d_in[23];
    const float* mbdt  = (const float*)d_in[24];
    const float* mWB   = (const float*)d_in[25];
    const float* mbB   = (const float*)d_in[26];
    const float* mWC   = (const float*)d_in[27];
    const float* mbC   = (const float*)d_in[28];
    const float* mAlog = (const float*)d_in[29];
    const float* mD    = (const float*)d_in[30];
    const float* mWout = (const float*)d_in[31];
    const float* mbout = (const float*)d_in[32];
    float* out = (float*)d_out;
    char* ws = (char*)d_ws;

    const size_t BIGE = (size_t)TT * NN_ * 256;
    size_t o = 0;
    auto alloc = [&](size_t bytes) { size_t r = o; o += (bytes + 255) & ~(size_t)255; return r; };

    float* msgs  = (float*)(ws + alloc((size_t)NN_ * 256 * 4));
    float* q     = (float*)(ws + alloc((size_t)NN_ * 256 * 4));
    float* kk    = (float*)(ws + alloc((size_t)NN_ * 256 * 4));
    bf16*  gatesb = (bf16*)(ws + alloc((size_t)NN_ * NN_ * 2));
    unsigned long long* adjbits =
        (unsigned long long*)(ws + alloc((size_t)TT * NN_ * NN_ / 8));
    bf16*  Ra    = (bf16*)(ws + alloc(BIGE * 2));                 // agg / xn
    size_t off_x1 = alloc(BIGE * 2);
    bf16*  x1    = (bf16*)(ws + off_x1);
    bf16*  agg2  = (bf16*)(ws + alloc(BIGE * 2));                 // contiguous after x1
    bf16*  x2    = (bf16*)(ws + alloc(BIGE * 2));                 // res, [N,T,H]
    bf16*  yg    = (bf16*)(ws + alloc(BIGE * 2));
    bf16*  sg    = (bf16*)(ws + alloc((size_t)NN_ * TT * EE * 2));
    float* dbc   = (float*)(ws + alloc((size_t)TT * NN_ * 48 * 4));  // [M,48] d1|Bm|Cm
    bf16*  u     = (bf16*)(ws + off_x1);                          // aliases x1+agg2
    // transposed bf16 weights / staging
    bf16* posb   = (bf16*)(ws + alloc((size_t)NN_ * 256 * 2));
    bf16* g1WuT  = (bf16*)(ws + alloc((size_t)256 * 512 * 2));
    bf16* g2WmT  = (bf16*)(ws + alloc((size_t)256 * 256 * 2));
    bf16* g2WuT  = (bf16*)(ws + alloc((size_t)256 * 512 * 2));
    bf16* mWinT  = (bf16*)(ws + alloc((size_t)1024 * 256 * 2));
    bf16* mWoutT = (bf16*)(ws + alloc((size_t)256 * 512 * 2));
    bf16* WdBCT  = (bf16*)(ws + alloc((size_t)64 * 512 * 2));
    float* biascat = (float*)(ws + alloc(64 * 4));
    bf16* msgsT  = (bf16*)(ws + alloc((size_t)256 * 1024 * 2));
    bf16* msgs2T = (bf16*)(ws + alloc(BIGE * 2));

    const unsigned ALLR = 0xFFFFFFFFu;
    const int M = TT * NN_;

    // prep (2 launches instead of 7)
    packadj_k<<<2048, 256, 0, stream>>>((const float4*)adj, (unsigned int*)adjbits);
    prep_all_k<<<1024, 256, 0, stream>>>(
        pos, g1Wu, g2Wm, g2Wu, mWin, mWout, mWd, mWB, mWC, mbd, mbB, mbC,
        posb, g1WuT, g2WmT, g2WuT, mWinT, mWoutT, WdBCT, biascat);

    // S0: msgs = pos @ g1_Wm + bm (f32)
    gemm_k<false, EPI_F32><<<dim3(16, 4), 256, 0, stream>>>(
        pos, g1Wm, msgs, g1bm, nullptr, 1.f, NN_, 256, 256, 256, 256);
    transmsgs_k<<<1024, 256, 0, stream>>>(msgs, msgsT);
    // S1: q AND k in one launch
    gemmqk_k<<<dim3(16, 8), 256, 0, stream>>>(msgs, g1Wq, g1Wk, q, kk);
    // S2: gates = sigmoid(q @ k^T / 16 + gb) -> bf16
    gemm_k<true, EPI_SIG_B16><<<dim3(16, 16), 256, 0, stream>>>(
        q, kk, (float*)gatesb, nullptr, g1gb, 1.f / 16.f, NN_, NN_, 256, 256, 256);
    // S3: agg -> Ra
    aggmm_k<true><<<512, 256, 0, stream>>>(
        (const unsigned char*)adjbits, gatesb, msgsT, Ra);
    // S4(+S5): x1 = LN(relu(cat(posb,Ra) @ Wu1 + bu1))
    mfma_k<64, 256, true, E_LN1><<<dim3(1024, 1), 256, 0, stream>>>(
        posb, Ra, 1023u, g1WuT, g1bu, nullptr, x1, nullptr,
        g1lg, g1lb, nullptr, nullptr, nullptr, M, 512);
    // S6: msgs2 = x1 @ Wm2 + bm2 -> msgs2T ([t][c][j])  (64x128 wave tile)
    mfma2_k<E_BF16T><<<dim3(512, 1), 256, 0, stream>>>(
        x1, g2WmT, g2bm, nullptr, msgs2T, nullptr, nullptr, 256);
    // S7: agg2 = adj @ msgs2
    aggmm_k<false><<<512, 256, 0, stream>>>(
        (const unsigned char*)adjbits, nullptr, msgs2T, agg2);
    // S8(+S9+S10): x2 = LN(relu(cat(x1,agg2)@Wu2+bu2)) [N,T,H], xn = LN2 -> Ra [N,T,H]
    mfma_k<64, 256, true, E_LN2><<<dim3(1024, 1), 256, 0, stream>>>(
        x1, agg2, ALLR, g2WuT, g2bu, nullptr, x2, Ra,
        g2lg, g2lb, mlg, mlb, nullptr, M, 512);
    // S11: u/sg = silu halves of xn @ Win + bin  (64x128 wave tile)
    mfma2_k<E_SILU><<<dim3(512, 4), 256, 0, stream>>>(
        Ra, mWinT, mbin, nullptr, u, sg, nullptr, 256);
    // S12 fused: dbc = u @ [Wd|WB|WC] + biases  ([M,48] interleaved)
    mfma_k<256, 64, false, E_TRI><<<dim3(256, 1), 256, 0, stream>>>(
        u, u, ALLR, WdBCT, biascat, dbc, nullptr, nullptr,
        nullptr, nullptr, nullptr, nullptr, nullptr, M, 512);
    // S13: selective scan -> yg  (block per (n-pair, e-half); 2 streams/thread)
    scan_k<<<dim3(NN_ / 2, 2), 256, 0, stream>>>(u, sg, dbc, mWdt, mbdt, mAlog, mD, yg);
    // S14: out = yg @ Wout + bout + res -> [T,N,H] f32  (64x128 wave tile)
    mfma2_k<E_OUT><<<dim3(512, 1), 256, 0, stream>>>(
        yg, mWoutT, mbout, out, nullptr, nullptr, x2, 512);

    (void)in_sizes; (void)n_in; (void)out_size; (void)ws_size;
}

// Round 8
// 1012.027 us; speedup vs baseline: 1.0533x; 1.0173x over previous
//
#include <hip/hip_runtime.h>
#include <hip/hip_bf16.h>

typedef __hip_bfloat16 bf16;
typedef __attribute__((ext_vector_type(8))) short s16x8;
typedef __attribute__((ext_vector_type(4))) short s16x4;
typedef __attribute__((ext_vector_type(4))) float f32x4;

#define TT 64
#define NN_ 1024
#define EE 512

__device__ __forceinline__ float toF(float v) { return v; }
__device__ __forceinline__ float toF(bf16 v) { return __bfloat162float(v); }
__device__ __forceinline__ bf16 f2b(float v) { return __float2bfloat16(v); }

#if __has_builtin(__builtin_amdgcn_exp2f)
#define EXP2F(x) __builtin_amdgcn_exp2f(x)
#else
#define EXP2F(x) exp2f(x)
#endif
#if __has_builtin(__builtin_amdgcn_logf)
#define LOG2F(x) __builtin_amdgcn_logf(x)
#else
#define LOG2F(x) log2f(x)
#endif

enum { EPI_F32 = 0, EPI_SIG_F32 = 1, EPI_SIG_B16 = 2, EPI_F32T = 3 };
enum { E_LN1 = 0, E_BF16 = 1, E_LN2 = 2, E_SILU = 3, E_OUT = 4, E_TRI = 5, E_BF16T = 6 };

// ---------------- small fp32 tiled GEMM (S0/S2; 1024-row problems) ------------------
// EPI_F32T additionally writes the transposed bf16 copy (fuses the old transmsgs_k).
template <bool TRANSB, int EPI>
__global__ __launch_bounds__(256) void gemm_k(
    const float* __restrict__ A, const float* __restrict__ B,
    float* __restrict__ outF, const float* __restrict__ bias,
    const float* __restrict__ sbeta, float alpha,
    int M, int Nn, int K, int lda, int ldb,
    bf16* __restrict__ outT)
{
    __shared__ float As[16][68];
    __shared__ float Bs[16][68];
    const int tid = threadIdx.x;
    const int tx = tid & 15, ty = tid >> 4;
    const int m0 = blockIdx.x * 64, n0 = blockIdx.y * 64;
    float acc[4][4] = {};

    for (int k0 = 0; k0 < K; k0 += 16) {
        {
            int row = tid >> 2, kk0 = (tid & 3) * 4, grow = m0 + row;
#pragma unroll
            for (int j = 0; j < 4; j++) {
                int kk = kk0 + j, gk = k0 + kk;
                As[kk][row] = (grow < M) ? A[(size_t)grow * lda + gk] : 0.f;
            }
        }
        if (!TRANSB) {
            int kk = tid >> 4, c0 = (tid & 15) * 4;
#pragma unroll
            for (int j = 0; j < 4; j++) {
                int col = c0 + j, gn = n0 + col;
                Bs[kk][col] = (gn < Nn) ? B[(size_t)(k0 + kk) * ldb + gn] : 0.f;
            }
        } else {
            int col = tid >> 2, kk0 = (tid & 3) * 4, gn = n0 + col;
#pragma unroll
            for (int j = 0; j < 4; j++) {
                int kk = kk0 + j;
                Bs[kk][col] = (gn < Nn) ? B[(size_t)gn * ldb + (k0 + kk)] : 0.f;
            }
        }
        __syncthreads();
#pragma unroll
        for (int kk = 0; kk < 16; kk++) {
            float a[4], b[4];
#pragma unroll
            for (int i = 0; i < 4; i++) a[i] = As[kk][ty * 4 + i];
#pragma unroll
            for (int j = 0; j < 4; j++) b[j] = Bs[kk][tx * 4 + j];
#pragma unroll
            for (int i = 0; i < 4; i++)
#pragma unroll
                for (int j = 0; j < 4; j++)
                    acc[i][j] = fmaf(a[i], b[j], acc[i][j]);
        }
        __syncthreads();
    }

    float gb = ((EPI == EPI_SIG_F32 || EPI == EPI_SIG_B16) && sbeta) ? sbeta[0] : 0.f;
#pragma unroll
    for (int i = 0; i < 4; i++) {
        int row = m0 + ty * 4 + i;
        if (row >= M) continue;
#pragma unroll
        for (int j = 0; j < 4; j++) {
            int col = n0 + tx * 4 + j;
            if (col >= Nn) continue;
            float v = acc[i][j];
            if (EPI == EPI_F32 || EPI == EPI_F32T) {
                if (bias) v += bias[col];
                outF[(size_t)row * Nn + col] = v;
                if (EPI == EPI_F32T) outT[(size_t)col * 1024 + row] = f2b(v);
            } else if (EPI == EPI_SIG_F32) {
                v = v * alpha + gb;
                outF[(size_t)row * Nn + col] = 1.f / (1.f + __expf(-v));
            } else {
                v = v * alpha + gb;
                ((bf16*)outF)[(size_t)row * Nn + col] = f2b(1.f / (1.f + __expf(-v)));
            }
        }
    }
}

// ---------------- S1 fused: q AND k in one launch (grid 16x8) -----------------------
__global__ __launch_bounds__(256) void gemmqk_k(
    const float* __restrict__ A, const float* __restrict__ Bq,
    const float* __restrict__ Bk, float* __restrict__ outq, float* __restrict__ outk)
{
    __shared__ float As[16][68];
    __shared__ float Bs[16][68];
    const float* __restrict__ B = (blockIdx.y < 4) ? Bq : Bk;
    float* __restrict__ outF = (blockIdx.y < 4) ? outq : outk;
    const int tid = threadIdx.x;
    const int tx = tid & 15, ty = tid >> 4;
    const int m0 = blockIdx.x * 64, n0 = (blockIdx.y & 3) * 64;
    float acc[4][4] = {};

    for (int k0 = 0; k0 < 256; k0 += 16) {
        {
            int row = tid >> 2, kk0 = (tid & 3) * 4, grow = m0 + row;
#pragma unroll
            for (int j = 0; j < 4; j++) {
                int kk = kk0 + j;
                As[kk][row] = A[(size_t)grow * 256 + k0 + kk];
            }
        }
        {
            int kk = tid >> 4, c0 = (tid & 15) * 4;
#pragma unroll
            for (int j = 0; j < 4; j++) {
                int col = c0 + j;
                Bs[kk][col] = B[(size_t)(k0 + kk) * 256 + n0 + col];
            }
        }
        __syncthreads();
#pragma unroll
        for (int kk = 0; kk < 16; kk++) {
            float a[4], b[4];
#pragma unroll
            for (int i = 0; i < 4; i++) a[i] = As[kk][ty * 4 + i];
#pragma unroll
            for (int j = 0; j < 4; j++) b[j] = Bs[kk][tx * 4 + j];
#pragma unroll
            for (int i = 0; i < 4; i++)
#pragma unroll
                for (int j = 0; j < 4; j++)
                    acc[i][j] = fmaf(a[i], b[j], acc[i][j]);
        }
        __syncthreads();
    }
#pragma unroll
    for (int i = 0; i < 4; i++) {
        int row = m0 + ty * 4 + i;
#pragma unroll
        for (int j = 0; j < 4; j++) {
            int col = n0 + tx * 4 + j;
            outF[(size_t)row * 256 + col] = acc[i][j];
        }
    }
}

// ---------------- MFMA bf16 GEMM, 64x64 wave tile (LN / TRI epilogues) ---------------
// LN reduction: single pass -- var = E[x^2] - mu^2, (s,q) butterfly interleaved.
template <int BM, int BN, bool CAT, int EPI>
__global__ __launch_bounds__(256) void mfma_k(
    const bf16* __restrict__ A1, const bf16* __restrict__ A2, unsigned rowmask,
    const bf16* __restrict__ BT, const float* __restrict__ bias,
    float* __restrict__ outF,
    bf16* __restrict__ outB, bf16* __restrict__ outB2,
    const float* __restrict__ g1, const float* __restrict__ b1,
    const float* __restrict__ g2, const float* __restrict__ b2,
    const bf16* __restrict__ resid,
    int M, int K)
{
    constexpr bool LN = (EPI == E_LN1 || EPI == E_LN2);
    constexpr int STAGE_B = (BM * 32 + BN * 32) * 2;
    constexpr int SB = LN ? (64 * 260 * 4) : STAGE_B;
    __shared__ __align__(16) char smem[SB];
    short* As = (short*)smem;
    short* Bs = As + BM * 32;
    float* Cs = (float*)smem;   // LN epilogue reuses staging LDS

    const int tid = threadIdx.x;
    const int wid = tid >> 6, lane = tid & 63;
    const int wr = (BN == 256) ? 0 : wid;
    const int wc = (BN == 256) ? wid : 0;
    const int m0 = blockIdx.x * BM, n0 = blockIdx.y * BN;
    const int srow = tid >> 2;
    const int skoff = (tid & 3) * 8;

    f32x4 acc[4][4] = {};
    s16x8 pa[BM / 64], pbv[BN / 64];

    auto LOADT = [&](int k0) {
#pragma unroll
        for (int c = 0; c < BM / 64; c++) {
            int r = c * 64 + srow;
            int gr = m0 + r;
            const bf16* p;
            if (CAT) {
                int gk = k0 + skoff;
                p = (gk < 256) ? (A1 + (size_t)(gr & rowmask) * 256 + gk)
                               : (A2 + (size_t)gr * 256 + (gk - 256));
            } else {
                p = A1 + (size_t)gr * K + k0 + skoff;
            }
            pa[c] = *(const s16x8*)p;
        }
#pragma unroll
        for (int c = 0; c < BN / 64; c++) {
            int r = c * 64 + srow;
            pbv[c] = *(const s16x8*)(BT + (size_t)(n0 + r) * K + k0 + skoff);
        }
    };

    LOADT(0);
#pragma unroll 1
    for (int k0 = 0; k0 < K; k0 += 32) {
#pragma unroll
        for (int c = 0; c < BM / 64; c++)
            *(s16x8*)&As[(c * 64 + srow) * 32 + skoff] = pa[c];
#pragma unroll
        for (int c = 0; c < BN / 64; c++)
            *(s16x8*)&Bs[(c * 64 + srow) * 32 + skoff] = pbv[c];
        __syncthreads();
        if (k0 + 32 < K) LOADT(k0 + 32);   // next tile in flight during MFMA
        s16x8 af[4], bf[4];
#pragma unroll
        for (int mi = 0; mi < 4; mi++)
            af[mi] = *(s16x8*)&As[(wr * 64 + mi * 16 + (lane & 15)) * 32 + (lane >> 4) * 8];
#pragma unroll
        for (int ni = 0; ni < 4; ni++)
            bf[ni] = *(s16x8*)&Bs[(wc * 64 + ni * 16 + (lane & 15)) * 32 + (lane >> 4) * 8];
#pragma unroll
        for (int mi = 0; mi < 4; mi++)
#pragma unroll
            for (int ni = 0; ni < 4; ni++)
                acc[mi][ni] = __builtin_amdgcn_mfma_f32_16x16x32_bf16(
                    af[mi], bf[ni], acc[mi][ni], 0, 0, 0);
        __syncthreads();
    }

    if (EPI == E_TRI) {
        // dbc[M,48]: cols 0-15 d1, 16-31 Bm, 32-47 Cm
#pragma unroll
        for (int mi = 0; mi < 4; mi++)
#pragma unroll
            for (int ni = 0; ni < 4; ni++)
#pragma unroll
                for (int r = 0; r < 4; r++) {
                    int row = m0 + wid * 64 + mi * 16 + (lane >> 4) * 4 + r;
                    int col = ni * 16 + (lane & 15);
                    if (col < 48) {
                        float v = acc[mi][ni][r] + bias[col];
                        outF[(size_t)row * 48 + col] = v;
                    }
                }
    } else {
        // E_LN1 / E_LN2: relu -> Cs, then row LN(s). BM=64, BN=256, grid.y=1.
#pragma unroll
        for (int mi = 0; mi < 4; mi++)
#pragma unroll
            for (int ni = 0; ni < 4; ni++)
#pragma unroll
                for (int r = 0; r < 4; r++) {
                    int rl = mi * 16 + (lane >> 4) * 4 + r;
                    int cl = wc * 64 + ni * 16 + (lane & 15);
                    Cs[rl * 260 + cl] = fmaxf(acc[mi][ni][r] + bias[cl], 0.f);
                }
        __syncthreads();
        float g1v[4], b1v[4], g2v[4], b2v[4];
#pragma unroll
        for (int i = 0; i < 4; i++) {
            g1v[i] = g1[lane * 4 + i];
            b1v[i] = b1[lane * 4 + i];
            if (EPI == E_LN2) { g2v[i] = g2[lane * 4 + i]; b2v[i] = b2[lane * 4 + i]; }
        }
#pragma unroll 2
        for (int rr = 0; rr < 16; rr++) {
            int rl = wid * 16 + rr;
            int grow = m0 + rl;
            float x[4];
#pragma unroll
            for (int i = 0; i < 4; i++) x[i] = Cs[rl * 260 + lane * 4 + i];
            float s = (x[0] + x[1]) + (x[2] + x[3]);
            float qq = fmaf(x[0], x[0], fmaf(x[1], x[1], fmaf(x[2], x[2], x[3] * x[3])));
#pragma unroll
            for (int o = 1; o < 64; o <<= 1) {
                s += __shfl_xor(s, o, 64);
                qq += __shfl_xor(qq, o, 64);
            }
            float mu = s * (1.f / 256.f);
            float var = fmaf(-mu, mu, qq * (1.f / 256.f));
            float inv = rsqrtf(fmaxf(var, 0.f) + 1e-5f);
            float y[4];
#pragma unroll
            for (int i = 0; i < 4; i++) y[i] = (x[i] - mu) * inv * g1v[i] + b1v[i];
            if (EPI == E_LN1) {
                __align__(8) bf16 pk[4];
#pragma unroll
                for (int i = 0; i < 4; i++) pk[i] = f2b(y[i]);
                *(s16x4*)&outB[(size_t)grow * 256 + lane * 4] = *(s16x4*)pk;
            } else {
                int trow = (grow & 1023) * 64 + (grow >> 10);   // [N,T] order
                __align__(8) bf16 pk[4];
#pragma unroll
                for (int i = 0; i < 4; i++) pk[i] = f2b(y[i]);
                *(s16x4*)&outB[(size_t)trow * 256 + lane * 4] = *(s16x4*)pk;
                float s2 = (y[0] + y[1]) + (y[2] + y[3]);
                float q2 = fmaf(y[0], y[0], fmaf(y[1], y[1], fmaf(y[2], y[2], y[3] * y[3])));
#pragma unroll
                for (int o = 1; o < 64; o <<= 1) {
                    s2 += __shfl_xor(s2, o, 64);
                    q2 += __shfl_xor(q2, o, 64);
                }
                float mu2 = s2 * (1.f / 256.f);
                float var2 = fmaf(-mu2, mu2, q2 * (1.f / 256.f));
                float inv2 = rsqrtf(fmaxf(var2, 0.f) + 1e-5f);
                __align__(8) bf16 pk2[4];
#pragma unroll
                for (int i = 0; i < 4; i++) pk2[i] = f2b((y[i] - mu2) * inv2 * g2v[i] + b2v[i]);
                *(s16x4*)&outB2[(size_t)trow * 256 + lane * 4] = *(s16x4*)pk2;
            }
        }
    }
}

// ---------------- MFMA bf16 GEMM, 64x128 wave tile (S6/S11/S14) ----------------------
template <int EPI>
__global__ __launch_bounds__(256, 2) void mfma2_k(
    const bf16* __restrict__ A, const bf16* __restrict__ BT,
    const float* __restrict__ bias,
    float* __restrict__ outF, bf16* __restrict__ outB, bf16* __restrict__ outB2,
    const bf16* __restrict__ resid,
    int K)
{
    constexpr int STAGE_B = (128 * 40 + 256 * 40) * 2;          // 30720
    constexpr int TRB = (EPI == E_BF16T) ? (64 * 268 * 2) : 0;  // 34304
    constexpr int SB = STAGE_B > TRB ? STAGE_B : TRB;
    __shared__ __align__(16) char smem[SB];
    short* As = (short*)smem;
    short* Bs = As + 128 * 40;

    const int tid = threadIdx.x;
    const int wid = tid >> 6, lane = tid & 63;
    const int wr = wid & 1;          // wave rows: wr*64
    const int wc = wid >> 1;         // wave cols: wc*128
    const int m0 = blockIdx.x * 128, n0 = blockIdx.y * 256;
    const int srow = tid >> 2;       // 0..63
    const int skoff = (tid & 3) * 8; // 0,8,16,24

    f32x4 acc[4][8] = {};
    s16x8 pa[2], pb[4];

    auto LOADT = [&](int k0) {
#pragma unroll
        for (int c = 0; c < 2; c++)
            pa[c] = *(const s16x8*)(A + (size_t)(m0 + c * 64 + srow) * K + k0 + skoff);
#pragma unroll
        for (int c = 0; c < 4; c++)
            pb[c] = *(const s16x8*)(BT + (size_t)(n0 + c * 64 + srow) * K + k0 + skoff);
    };

    LOADT(0);
#pragma unroll 1
    for (int k0 = 0; k0 < K; k0 += 32) {
#pragma unroll
        for (int c = 0; c < 2; c++)
            *(s16x8*)&As[(c * 64 + srow) * 40 + skoff] = pa[c];
#pragma unroll
        for (int c = 0; c < 4; c++)
            *(s16x8*)&Bs[(c * 64 + srow) * 40 + skoff] = pb[c];
        __syncthreads();
        if (k0 + 32 < K) LOADT(k0 + 32);   // next tile in flight during MFMA
        s16x8 af[4];
#pragma unroll
        for (int mi = 0; mi < 4; mi++)
            af[mi] = *(s16x8*)&As[(wr * 64 + mi * 16 + (lane & 15)) * 40 + (lane >> 4) * 8];
#pragma unroll
        for (int ni = 0; ni < 8; ni++) {
            s16x8 bfv = *(s16x8*)&Bs[(wc * 128 + ni * 16 + (lane & 15)) * 40 + (lane >> 4) * 8];
#pragma unroll
            for (int mi = 0; mi < 4; mi++)
                acc[mi][ni] = __builtin_amdgcn_mfma_f32_16x16x32_bf16(
                    af[mi], bfv, acc[mi][ni], 0, 0, 0);
        }
        __syncthreads();
    }

    if (EPI == E_SILU) {
#pragma unroll
        for (int mi = 0; mi < 4; mi++)
#pragma unroll
            for (int ni = 0; ni < 8; ni++)
#pragma unroll
                for (int r = 0; r < 4; r++) {
                    int row = m0 + wr * 64 + mi * 16 + (lane >> 4) * 4 + r;
                    int col = n0 + wc * 128 + ni * 16 + (lane & 15);
                    float v = acc[mi][ni][r] + bias[col];
                    float s = v / (1.f + __expf(-v));
                    if (col < EE) outB[(size_t)row * EE + col] = f2b(s);
                    else          outB2[(size_t)row * EE + (col - EE)] = f2b(s);
                }
    } else if (EPI == E_OUT) {
#pragma unroll
        for (int mi = 0; mi < 4; mi++)
#pragma unroll
            for (int ni = 0; ni < 8; ni++)
#pragma unroll
                for (int r = 0; r < 4; r++) {
                    int row = m0 + wr * 64 + mi * 16 + (lane >> 4) * 4 + r;
                    int col = n0 + wc * 128 + ni * 16 + (lane & 15);
                    float v = acc[mi][ni][r] + bias[col] + toF(resid[(size_t)row * 256 + col]);
                    int t = row & 63, n = row >> 6;
                    outF[((size_t)t * NN_ + n) * 256 + col] = v;
                }
    } else {
        // E_BF16T: rows r = t*1024+j -> store transposed [t][col][j].
        short* Ts = (short*)smem;
#pragma unroll 1
        for (int h = 0; h < 2; h++) {
            if (h) __syncthreads();      // protect previous half's reads
            if (wr == h) {
#pragma unroll
                for (int mi = 0; mi < 4; mi++)
#pragma unroll
                    for (int ni = 0; ni < 8; ni++)
#pragma unroll
                        for (int r = 0; r < 4; r++) {
                            int rl = mi * 16 + (lane >> 4) * 4 + r;
                            int cl = wc * 128 + ni * 16 + (lane & 15);
                            union { bf16 b; short s; } u;
                            u.b = f2b(acc[mi][ni][r] + bias[n0 + cl]);
                            Ts[rl * 268 + cl] = u.s;
                        }
            }
            __syncthreads();
            const int col = tid;
            const int rowbase = m0 + h * 64;
            size_t dbase = (((size_t)(rowbase >> 10)) * 256 + (n0 + col)) * 1024 + (rowbase & 1023);
#pragma unroll
            for (int j0 = 0; j0 < 64; j0 += 8) {
                s16x8 v;
#pragma unroll
                for (int i = 0; i < 8; i++) v[i] = Ts[(j0 + i) * 268 + col];
                *(s16x8*)&outB[dbase + j0] = v;
            }
        }
    }
}

// ---------------- adj bit-pack: adj in {0,1} -> 1 bit/elem (268MB -> 8.4MB) --------
__global__ __launch_bounds__(256) void packadj_k(
    const float4* __restrict__ adj4, unsigned int* __restrict__ bits32)
{
    const size_t nwords = (size_t)TT * NN_ * NN_ / 32;   // 2,097,152
    const size_t stride = (size_t)gridDim.x * 256;
    for (size_t w = (size_t)blockIdx.x * 256 + threadIdx.x; w < nwords; w += stride) {
        const float4* __restrict__ p = adj4 + w * 8;
        float4 v[8];
#pragma unroll
        for (int i = 0; i < 8; i++) v[i] = p[i];
        unsigned int m = 0;
#pragma unroll
        for (int i = 0; i < 8; i++) {
            m |= (v[i].x != 0.f ? 1u : 0u) << (4 * i);
            m |= (v[i].y != 0.f ? 2u : 0u) << (4 * i);
            m |= (v[i].z != 0.f ? 4u : 0u) << (4 * i);
            m |= (v[i].w != 0.f ? 8u : 0u) << (4 * i);
        }
        bits32[w] = m;
    }
}

// ---------------- dense MFMA aggregation via bitmask -------------------------------
template <bool GATED>
__global__ __launch_bounds__(256, 2) void aggmm_k(
    const unsigned char* __restrict__ adjbits, const bf16* __restrict__ gatesb,
    const bf16* __restrict__ BTsrc, bf16* __restrict__ out)
{
    __shared__ __align__(16) short As[128 * 40];
    __shared__ __align__(16) short Bs[256 * 40];
    const int tid = threadIdx.x;
    const int wid = tid >> 6, lane = tid & 63;
    const int wr = wid & 1;          // wave rows: wr*64
    const int wc = wid >> 1;         // wave cols: wc*128
    const int bx = blockIdx.x;
    const int t = bx >> 3, n0 = (bx & 7) * 128;
    const int srow = tid >> 2;       // 0..63
    const int skoff = (tid & 3) * 8; // 0,8,16,24

    const unsigned char* __restrict__ abB =
        adjbits + ((size_t)t * 1024 + n0) * 128 + (tid & 3);
    const bf16* __restrict__ gB = GATED ? (gatesb + (size_t)n0 * 1024 + skoff) : nullptr;
    const bf16* __restrict__ bt = GATED ? BTsrc : (BTsrc + (size_t)t * 256 * 1024);
    const size_t orow0 = (size_t)t * 1024 + n0;

    f32x4 acc[4][8] = {};

    unsigned char pm[2];
    s16x8 pg[2];
    s16x8 pb[4];

    auto LOADA = [&](int k0) {
#pragma unroll
        for (int c = 0; c < 2; c++) {
            int r = c * 64 + srow;
            pm[c] = abB[(size_t)r * 128 + (k0 >> 3)];
            if (GATED) pg[c] = *(const s16x8*)(gB + (size_t)r * 1024 + k0);
        }
#pragma unroll
        for (int c = 0; c < 4; c++)
            pb[c] = *(const s16x8*)(bt + (size_t)(c * 64 + srow) * 1024 + k0 + skoff);
    };
    auto STORE = [&]() {
#pragma unroll
        for (int c = 0; c < 2; c++) {
            unsigned m = pm[c];
            s16x8 tmp;
            if (GATED) {
#pragma unroll
                for (int i = 0; i < 8; i++) tmp[i] = ((m >> i) & 1) ? pg[c][i] : (short)0;
            } else {
#pragma unroll
                for (int i = 0; i < 8; i++) tmp[i] = ((m >> i) & 1) ? (short)0x3F80 : (short)0;
            }
            *(s16x8*)&As[(c * 64 + srow) * 40 + skoff] = tmp;
        }
#pragma unroll
        for (int c = 0; c < 4; c++)
            *(s16x8*)&Bs[(c * 64 + srow) * 40 + skoff] = pb[c];
    };

    LOADA(0);
#pragma unroll 1
    for (int k0 = 0; k0 < 1024; k0 += 32) {
        STORE();
        __syncthreads();
        if (k0 + 32 < 1024) LOADA(k0 + 32);   // next tile in flight during MFMA
        s16x8 af[4];
#pragma unroll
        for (int mi = 0; mi < 4; mi++)
            af[mi] = *(s16x8*)&As[(wr * 64 + mi * 16 + (lane & 15)) * 40 + (lane >> 4) * 8];
#pragma unroll
        for (int ni = 0; ni < 8; ni++) {
            s16x8 bfv = *(s16x8*)&Bs[(wc * 128 + ni * 16 + (lane & 15)) * 40 + (lane >> 4) * 8];
#pragma unroll
            for (int mi = 0; mi < 4; mi++)
                acc[mi][ni] = __builtin_amdgcn_mfma_f32_16x16x32_bf16(
                    af[mi], bfv, acc[mi][ni], 0, 0, 0);
        }
        __syncthreads();
    }

#pragma unroll
    for (int mi = 0; mi < 4; mi++)
#pragma unroll
        for (int ni = 0; ni < 8; ni++)
#pragma unroll
            for (int r = 0; r < 4; r++) {
                int rowl = wr * 64 + mi * 16 + (lane >> 4) * 4 + r;
                int col = wc * 128 + ni * 16 + (lane & 15);
                out[(orow0 + rowl) * 256 + col] = f2b(acc[mi][ni][r]);
            }
}

// ---------------- Mamba selective scan: 2 independent n-streams per thread ----------
// (round-5 verified version, restored verbatim)
__global__ __launch_bounds__(256) void scan_k(
    const bf16* __restrict__ u, const bf16* __restrict__ sg,
    const float* __restrict__ dbc,
    const float* __restrict__ Wdt, const float* __restrict__ bdt,
    const float* __restrict__ Alog, const float* __restrict__ D,
    bf16* __restrict__ yg)
{
    const int n0 = blockIdx.x * 2, e = blockIdx.y * 256 + threadIdx.x;
    float al[16], wdt[16], h0[16], h1[16];
#pragma unroll
    for (int s = 0; s < 16; s++) {
        al[s] = -__expf(Alog[e * 16 + s]) * 1.44269504f;   // * log2(e)
        h0[s] = 0.f; h1[s] = 0.f;
    }
#pragma unroll
    for (int k = 0; k < 16; k++) wdt[k] = Wdt[(size_t)k * EE + e];
    const float bdte = bdt[e], De = D[e];
    const float* __restrict__ r0p = dbc + (size_t)n0 * TT * 48;
    const float* __restrict__ r1p = r0p + TT * 48;
    const size_t base0 = (size_t)n0 * TT * EE + e;
    const size_t base1 = base0 + (size_t)TT * EE;
#pragma unroll 1
    for (int t = 0; t < TT; t++) {
        const float* __restrict__ r0 = r0p + t * 48;
        const float* __restrict__ r1 = r1p + t * 48;
        float a00 = bdte, a01 = 0.f, a10 = bdte, a11 = 0.f;
#pragma unroll
        for (int k = 0; k < 8; k++) {
            a00 = fmaf(r0[k],     wdt[k],     a00);
            a01 = fmaf(r0[k + 8], wdt[k + 8], a01);
            a10 = fmaf(r1[k],     wdt[k],     a10);
            a11 = fmaf(r1[k + 8], wdt[k + 8], a11);
        }
        float acc0 = a00 + a01, acc1 = a10 + a11;
        float delta0 = (acc0 > 20.f)
            ? acc0 : 0.69314718056f * LOG2F(1.f + EXP2F(acc0 * 1.44269504f));
        float delta1 = (acc1 > 20.f)
            ? acc1 : 0.69314718056f * LOG2F(1.f + EXP2F(acc1 * 1.44269504f));
        size_t idx0 = base0 + (size_t)t * EE;
        size_t idx1 = base1 + (size_t)t * EE;
        float uv0 = toF(u[idx0]), uv1 = toF(u[idx1]);
        float du0 = delta0 * uv0, du1 = delta1 * uv1;
        float y00 = 0.f, y01 = 0.f, y10 = 0.f, y11 = 0.f;
#pragma unroll
        for (int s = 0; s < 16; s += 2) {
            float ad00 = EXP2F(delta0 * al[s]);
            float ad01 = EXP2F(delta0 * al[s + 1]);
            float ad10 = EXP2F(delta1 * al[s]);
            float ad11 = EXP2F(delta1 * al[s + 1]);
            h0[s]     = fmaf(ad00, h0[s],     du0 * r0[16 + s]);
            h0[s + 1] = fmaf(ad01, h0[s + 1], du0 * r0[17 + s]);
            h1[s]     = fmaf(ad10, h1[s],     du1 * r1[16 + s]);
            h1[s + 1] = fmaf(ad11, h1[s + 1], du1 * r1[17 + s]);
            y00 = fmaf(r0[32 + s], h0[s],     y00);
            y01 = fmaf(r0[33 + s], h0[s + 1], y01);
            y10 = fmaf(r1[32 + s], h1[s],     y10);
            y11 = fmaf(r1[33 + s], h1[s + 1], y11);
        }
        float y0 = y00 + y01, y1 = y10 + y11;
        yg[idx0] = f2b((y0 + uv0 * De) * toF(sg[idx0]));
        yg[idx1] = f2b((y1 + uv1 * De) * toF(sg[idx1]));
    }
}

// ---------------- fused prep: cast + 4x transT + wdbct in one launch ----------------
__global__ __launch_bounds__(256) void prep_all_k(
    const float* __restrict__ pos,
    const float* __restrict__ g1Wu, const float* __restrict__ g2Wm,
    const float* __restrict__ g2Wu, const float* __restrict__ mWin,
    const float* __restrict__ mWout,
    const float* __restrict__ Wd, const float* __restrict__ WB,
    const float* __restrict__ WC, const float* __restrict__ bd,
    const float* __restrict__ bB, const float* __restrict__ bC,
    bf16* __restrict__ posb, bf16* __restrict__ g1WuT, bf16* __restrict__ g2WmT,
    bf16* __restrict__ g2WuT, bf16* __restrict__ mWinT, bf16* __restrict__ mWoutT,
    bf16* __restrict__ WdBCT, float* __restrict__ biascat)
{
    const int total = 262144 + 131072 + 65536 + 131072 + 262144 + 131072 + 32768 + 48;
    for (int gid = blockIdx.x * 256 + threadIdx.x; gid < total; gid += gridDim.x * 256) {
        int g = gid;
        if (g < 262144) { posb[g] = f2b(pos[g]); continue; }
        g -= 262144;
        if (g < 131072) { int n = g >> 9, k = g & 511; g1WuT[g] = f2b(g1Wu[(size_t)k * 256 + n]); continue; }
        g -= 131072;
        if (g < 65536)  { int n = g >> 8, k = g & 255; g2WmT[g] = f2b(g2Wm[(size_t)k * 256 + n]); continue; }
        g -= 65536;
        if (g < 131072) { int n = g >> 9, k = g & 511; g2WuT[g] = f2b(g2Wu[(size_t)k * 256 + n]); continue; }
        g -= 131072;
        if (g < 262144) { int n = g >> 8, k = g & 255; mWinT[g] = f2b(mWin[(size_t)k * 1024 + n]); continue; }
        g -= 262144;
        if (g < 131072) { int n = g >> 9, k = g & 511; mWoutT[g] = f2b(mWout[(size_t)k * 256 + n]); continue; }
        g -= 131072;
        if (g < 32768) {
            int n = g >> 9, k = g & 511;
            float v = 0.f;
            if (n < 16)      v = Wd[(size_t)k * 16 + n];
            else if (n < 32) v = WB[(size_t)k * 16 + (n - 16)];
            else if (n < 48) v = WC[(size_t)k * 16 + (n - 32)];
            WdBCT[g] = f2b(v);
            continue;
        }
        g -= 32768;
        biascat[g] = (g < 16) ? bd[g] : (g < 32) ? bB[g - 16] : bC[g - 32];
    }
}

extern "C" void kernel_launch(void* const* d_in, const int* in_sizes, int n_in,
                              void* d_out, int out_size, void* d_ws, size_t ws_size,
                              hipStream_t stream)
{
    const float* adj   = (const float*)d_in[0];
    const float* pos   = (const float*)d_in[1];
    const float* g1Wm  = (const float*)d_in[2];
    const float* g1bm  = (const float*)d_in[3];
    const float* g1Wq  = (const float*)d_in[4];
    const float* g1Wk  = (const float*)d_in[5];
    const float* g1gb  = (const float*)d_in[6];
    const float* g1Wu  = (const float*)d_in[7];
    const float* g1bu  = (const float*)d_in[8];
    const float* g1lg  = (const float*)d_in[9];
    const float* g1lb  = (const float*)d_in[10];
    const float* g2Wm  = (const float*)d_in[11];
    const float* g2bm  = (const float*)d_in[12];
    const float* g2Wu  = (const float*)d_in[13];
    const float* g2bu  = (const float*)d_in[14];
    const float* g2lg  = (const float*)d_in[15];
    const float* g2lb  = (const float*)d_in[16];
    const float* mlg   = (const float*)d_in[17];
    const float* mlb   = (const float*)d_in[18];
    const float* mWin  = (const float*)d_in[19];
    const float* mbin  = (const float*)d_in[20];
    const float* mWd   = (const float*)d_in[21];
    const float* mbd   = (const float*)d_in[22];
    const float* mWdt  = (const float*)d_in[23];
    const float* mbdt  = (const float*)d_in[24];
    const float* mWB   = (const float*)d_in[25];
    const float* mbB   = (const float*)d_in[26];
    const float* mWC   = (const float*)d_in[27];
    const float* mbC   = (const float*)d_in[28];
    const float* mAlog = (const float*)d_in[29];
    const float* mD    = (const float*)d_in[30];
    const float* mWout = (const float*)d_in[31];
    const float* mbout = (const float*)d_in[32];
    float* out = (float*)d_out;
    char* ws = (char*)d_ws;

    const size_t BIGE = (size_t)TT * NN_ * 256;
    size_t o = 0;
    auto alloc = [&](size_t bytes) { size_t r = o; o += (bytes + 255) & ~(size_t)255; return r; };

    float* msgs  = (float*)(ws + alloc((size_t)NN_ * 256 * 4));
    float* q     = (float*)(ws + alloc((size_t)NN_ * 256 * 4));
    float* kk    = (float*)(ws + alloc((size_t)NN_ * 256 * 4));
    bf16*  gatesb = (bf16*)(ws + alloc((size_t)NN_ * NN_ * 2));
    unsigned long long* adjbits =
        (unsigned long long*)(ws + alloc((size_t)TT * NN_ * NN_ / 8));
    bf16*  Ra    = (bf16*)(ws + alloc(BIGE * 2));                 // agg / xn
    size_t off_x1 = alloc(BIGE * 2);
    bf16*  x1    = (bf16*)(ws + off_x1);
    bf16*  agg2  = (bf16*)(ws + alloc(BIGE * 2));                 // contiguous after x1
    bf16*  x2    = (bf16*)(ws + alloc(BIGE * 2));                 // res, [N,T,H]
    bf16*  yg    = (bf16*)(ws + alloc(BIGE * 2));
    bf16*  sg    = (bf16*)(ws + alloc((size_t)NN_ * TT * EE * 2));
    float* dbc   = (float*)(ws + alloc((size_t)TT * NN_ * 48 * 4));  // [M,48] d1|Bm|Cm
    bf16*  u     = (bf16*)(ws + off_x1);                          // aliases x1+agg2
    // transposed bf16 weights / staging
    bf16* posb   = (bf16*)(ws + alloc((size_t)NN_ * 256 * 2));
    bf16* g1WuT  = (bf16*)(ws + alloc((size_t)256 * 512 * 2));
    bf16* g2WmT  = (bf16*)(ws + alloc((size_t)256 * 256 * 2));
    bf16* g2WuT  = (bf16*)(ws + alloc((size_t)256 * 512 * 2));
    bf16* mWinT  = (bf16*)(ws + alloc((size_t)1024 * 256 * 2));
    bf16* mWoutT = (bf16*)(ws + alloc((size_t)256 * 512 * 2));
    bf16* WdBCT  = (bf16*)(ws + alloc((size_t)64 * 512 * 2));
    float* biascat = (float*)(ws + alloc(64 * 4));
    bf16* msgsT  = (bf16*)(ws + alloc((size_t)256 * 1024 * 2));
    bf16* msgs2T = (bf16*)(ws + alloc(BIGE * 2));

    const unsigned ALLR = 0xFFFFFFFFu;
    const int M = TT * NN_;

    // prep (2 launches)
    packadj_k<<<2048, 256, 0, stream>>>((const float4*)adj, (unsigned int*)adjbits);
    prep_all_k<<<1024, 256, 0, stream>>>(
        pos, g1Wu, g2Wm, g2Wu, mWin, mWout, mWd, mWB, mWC, mbd, mbB, mbC,
        posb, g1WuT, g2WmT, g2WuT, mWinT, mWoutT, WdBCT, biascat);

    // S0: msgs = pos @ g1_Wm + bm (f32) + fused msgsT (bf16, transposed)
    gemm_k<false, EPI_F32T><<<dim3(16, 4), 256, 0, stream>>>(
        pos, g1Wm, msgs, g1bm, nullptr, 1.f, NN_, 256, 256, 256, 256, msgsT);
    // S1: q AND k in one launch
    gemmqk_k<<<dim3(16, 8), 256, 0, stream>>>(msgs, g1Wq, g1Wk, q, kk);
    // S2: gates = sigmoid(q @ k^T / 16 + gb) -> bf16
    gemm_k<true, EPI_SIG_B16><<<dim3(16, 16), 256, 0, stream>>>(
        q, kk, (float*)gatesb, nullptr, g1gb, 1.f / 16.f, NN_, NN_, 256, 256, 256, nullptr);
    // S3: agg -> Ra
    aggmm_k<true><<<512, 256, 0, stream>>>(
        (const unsigned char*)adjbits, gatesb, msgsT, Ra);
    // S4(+S5): x1 = LN(relu(cat(posb,Ra) @ Wu1 + bu1))
    mfma_k<64, 256, true, E_LN1><<<dim3(1024, 1), 256, 0, stream>>>(
        posb, Ra, 1023u, g1WuT, g1bu, nullptr, x1, nullptr,
        g1lg, g1lb, nullptr, nullptr, nullptr, M, 512);
    // S6: msgs2 = x1 @ Wm2 + bm2 -> msgs2T ([t][c][j])  (64x128 wave tile)
    mfma2_k<E_BF16T><<<dim3(512, 1), 256, 0, stream>>>(
        x1, g2WmT, g2bm, nullptr, msgs2T, nullptr, nullptr, 256);
    // S7: agg2 = adj @ msgs2
    aggmm_k<false><<<512, 256, 0, stream>>>(
        (const unsigned char*)adjbits, nullptr, msgs2T, agg2);
    // S8(+S9+S10): x2 = LN(relu(cat(x1,agg2)@Wu2+bu2)) [N,T,H], xn = LN2 -> Ra [N,T,H]
    mfma_k<64, 256, true, E_LN2><<<dim3(1024, 1), 256, 0, stream>>>(
        x1, agg2, ALLR, g2WuT, g2bu, nullptr, x2, Ra,
        g2lg, g2lb, mlg, mlb, nullptr, M, 512);
    // S11: u/sg = silu halves of xn @ Win + bin  (64x128 wave tile)
    mfma2_k<E_SILU><<<dim3(512, 4), 256, 0, stream>>>(
        Ra, mWinT, mbin, nullptr, u, sg, nullptr, 256);
    // S12 fused: dbc = u @ [Wd|WB|WC] + biases  ([M,48] interleaved)
    mfma_k<256, 64, false, E_TRI><<<dim3(256, 1), 256, 0, stream>>>(
        u, u, ALLR, WdBCT, biascat, dbc, nullptr, nullptr,
        nullptr, nullptr, nullptr, nullptr, nullptr, M, 512);
    // S13: selective scan -> yg  (block per (n-pair, e-half); 2 streams/thread)
    scan_k<<<dim3(NN_ / 2, 2), 256, 0, stream>>>(u, sg, dbc, mWdt, mbdt, mAlog, mD, yg);
    // S14: out = yg @ Wout + bout + res -> [T,N,H] f32  (64x128 wave tile)
    mfma2_k<E_OUT><<<dim3(512, 1), 256, 0, stream>>>(
        yg, mWoutT, mbout, out, nullptr, nullptr, x2, 512);

    (void)in_sizes; (void)n_in; (void)out_size; (void)ws_size;
}

// Round 10
// 1011.374 us; speedup vs baseline: 1.0540x; 1.0006x over previous
//
#include <hip/hip_runtime.h>
#include <hip/hip_bf16.h>

typedef __hip_bfloat16 bf16;
typedef __attribute__((ext_vector_type(8))) short s16x8;
typedef __attribute__((ext_vector_type(4))) short s16x4;
typedef __attribute__((ext_vector_type(4))) float f32x4;

#define TT 64
#define NN_ 1024
#define EE 512

__device__ __forceinline__ float toF(float v) { return v; }
__device__ __forceinline__ float toF(bf16 v) { return __bfloat162float(v); }
__device__ __forceinline__ bf16 f2b(float v) { return __float2bfloat16(v); }

#if __has_builtin(__builtin_amdgcn_exp2f)
#define EXP2F(x) __builtin_amdgcn_exp2f(x)
#else
#define EXP2F(x) exp2f(x)
#endif
#if __has_builtin(__builtin_amdgcn_logf)
#define LOG2F(x) __builtin_amdgcn_logf(x)
#else
#define LOG2F(x) log2f(x)
#endif

enum { EPI_F32 = 0, EPI_SIG_F32 = 1, EPI_SIG_B16 = 2, EPI_F32T = 3 };
enum { E_LN1 = 0, E_BF16 = 1, E_LN2 = 2, E_SILU = 3, E_OUT = 4, E_TRI = 5, E_BF16T = 6 };

// ---------------- small fp32 tiled GEMM (S0; 1024-row problems) ---------------------
// EPI_F32T additionally writes the transposed bf16 copy (fuses the old transmsgs_k).
template <bool TRANSB, int EPI>
__global__ __launch_bounds__(256) void gemm_k(
    const float* __restrict__ A, const float* __restrict__ B,
    float* __restrict__ outF, const float* __restrict__ bias,
    const float* __restrict__ sbeta, float alpha,
    int M, int Nn, int K, int lda, int ldb,
    bf16* __restrict__ outT)
{
    __shared__ float As[16][68];
    __shared__ float Bs[16][68];
    const int tid = threadIdx.x;
    const int tx = tid & 15, ty = tid >> 4;
    const int m0 = blockIdx.x * 64, n0 = blockIdx.y * 64;
    float acc[4][4] = {};

    for (int k0 = 0; k0 < K; k0 += 16) {
        {
            int row = tid >> 2, kk0 = (tid & 3) * 4, grow = m0 + row;
#pragma unroll
            for (int j = 0; j < 4; j++) {
                int kk = kk0 + j, gk = k0 + kk;
                As[kk][row] = (grow < M) ? A[(size_t)grow * lda + gk] : 0.f;
            }
        }
        if (!TRANSB) {
            int kk = tid >> 4, c0 = (tid & 15) * 4;
#pragma unroll
            for (int j = 0; j < 4; j++) {
                int col = c0 + j, gn = n0 + col;
                Bs[kk][col] = (gn < Nn) ? B[(size_t)(k0 + kk) * ldb + gn] : 0.f;
            }
        } else {
            int col = tid >> 2, kk0 = (tid & 3) * 4, gn = n0 + col;
#pragma unroll
            for (int j = 0; j < 4; j++) {
                int kk = kk0 + j;
                Bs[kk][col] = (gn < Nn) ? B[(size_t)gn * ldb + (k0 + kk)] : 0.f;
            }
        }
        __syncthreads();
#pragma unroll
        for (int kk = 0; kk < 16; kk++) {
            float a[4], b[4];
#pragma unroll
            for (int i = 0; i < 4; i++) a[i] = As[kk][ty * 4 + i];
#pragma unroll
            for (int j = 0; j < 4; j++) b[j] = Bs[kk][tx * 4 + j];
#pragma unroll
            for (int i = 0; i < 4; i++)
#pragma unroll
                for (int j = 0; j < 4; j++)
                    acc[i][j] = fmaf(a[i], b[j], acc[i][j]);
        }
        __syncthreads();
    }

    float gb = ((EPI == EPI_SIG_F32 || EPI == EPI_SIG_B16) && sbeta) ? sbeta[0] : 0.f;
#pragma unroll
    for (int i = 0; i < 4; i++) {
        int row = m0 + ty * 4 + i;
        if (row >= M) continue;
#pragma unroll
        for (int j = 0; j < 4; j++) {
            int col = n0 + tx * 4 + j;
            if (col >= Nn) continue;
            float v = acc[i][j];
            if (EPI == EPI_F32 || EPI == EPI_F32T) {
                if (bias) v += bias[col];
                outF[(size_t)row * Nn + col] = v;
                if (EPI == EPI_F32T) outT[(size_t)col * 1024 + row] = f2b(v);
            } else if (EPI == EPI_SIG_F32) {
                v = v * alpha + gb;
                outF[(size_t)row * Nn + col] = 1.f / (1.f + __expf(-v));
            } else {
                v = v * alpha + gb;
                ((bf16*)outF)[(size_t)row * Nn + col] = f2b(1.f / (1.f + __expf(-v)));
            }
        }
    }
}

// ---------------- S1 fused: q AND k in one launch (grid 16x8) -----------------------
__global__ __launch_bounds__(256) void gemmqk_k(
    const float* __restrict__ A, const float* __restrict__ Bq,
    const float* __restrict__ Bk, float* __restrict__ outq, float* __restrict__ outk)
{
    __shared__ float As[16][68];
    __shared__ float Bs[16][68];
    const float* __restrict__ B = (blockIdx.y < 4) ? Bq : Bk;
    float* __restrict__ outF = (blockIdx.y < 4) ? outq : outk;
    const int tid = threadIdx.x;
    const int tx = tid & 15, ty = tid >> 4;
    const int m0 = blockIdx.x * 64, n0 = (blockIdx.y & 3) * 64;
    float acc[4][4] = {};

    for (int k0 = 0; k0 < 256; k0 += 16) {
        {
            int row = tid >> 2, kk0 = (tid & 3) * 4, grow = m0 + row;
#pragma unroll
            for (int j = 0; j < 4; j++) {
                int kk = kk0 + j;
                As[kk][row] = A[(size_t)grow * 256 + k0 + kk];
            }
        }
        {
            int kk = tid >> 4, c0 = (tid & 15) * 4;
#pragma unroll
            for (int j = 0; j < 4; j++) {
                int col = c0 + j;
                Bs[kk][col] = B[(size_t)(k0 + kk) * 256 + n0 + col];
            }
        }
        __syncthreads();
#pragma unroll
        for (int kk = 0; kk < 16; kk++) {
            float a[4], b[4];
#pragma unroll
            for (int i = 0; i < 4; i++) a[i] = As[kk][ty * 4 + i];
#pragma unroll
            for (int j = 0; j < 4; j++) b[j] = Bs[kk][tx * 4 + j];
#pragma unroll
            for (int i = 0; i < 4; i++)
#pragma unroll
                for (int j = 0; j < 4; j++)
                    acc[i][j] = fmaf(a[i], b[j], acc[i][j]);
        }
        __syncthreads();
    }
#pragma unroll
    for (int i = 0; i < 4; i++) {
        int row = m0 + ty * 4 + i;
#pragma unroll
        for (int j = 0; j < 4; j++) {
            int col = n0 + tx * 4 + j;
            outF[(size_t)row * 256 + col] = acc[i][j];
        }
    }
}

// ---------------- S2: gates = sigmoid(q @ k^T / 16 + gb), 32x32 tiles ---------------
// Bit-exact with the old gemm_k<true,EPI_SIG_B16> path: per-output fp32 fma chain in
// sequential k order, identical epilogue. 1024 blocks (4x the 64x64 grid) so the
// 16-step barrier'd K-loop latency is hidden by occupancy, not suffered serially.
__global__ __launch_bounds__(256) void gemmsig_k(
    const float* __restrict__ Q, const float* __restrict__ Kv,
    const float* __restrict__ sbeta, bf16* __restrict__ gatesb)
{
    __shared__ float As[16][36];
    __shared__ float Bs[16][36];
    const int tid = threadIdx.x;
    const int tx = tid & 15, ty = tid >> 4;
    const int m0 = blockIdx.x * 32, n0 = blockIdx.y * 32;
    float acc[2][2] = {};

    for (int k0 = 0; k0 < 256; k0 += 16) {
        {
            int r = tid >> 3, kk0 = (tid & 7) * 2;
            As[kk0][r]     = Q[(size_t)(m0 + r) * 256 + k0 + kk0];
            As[kk0 + 1][r] = Q[(size_t)(m0 + r) * 256 + k0 + kk0 + 1];
            Bs[kk0][r]     = Kv[(size_t)(n0 + r) * 256 + k0 + kk0];
            Bs[kk0 + 1][r] = Kv[(size_t)(n0 + r) * 256 + k0 + kk0 + 1];
        }
        __syncthreads();
#pragma unroll
        for (int kk = 0; kk < 16; kk++) {
            float a0 = As[kk][ty * 2], a1 = As[kk][ty * 2 + 1];
            float b0 = Bs[kk][tx * 2], b1 = Bs[kk][tx * 2 + 1];
            acc[0][0] = fmaf(a0, b0, acc[0][0]);
            acc[0][1] = fmaf(a0, b1, acc[0][1]);
            acc[1][0] = fmaf(a1, b0, acc[1][0]);
            acc[1][1] = fmaf(a1, b1, acc[1][1]);
        }
        __syncthreads();
    }

    const float gb = sbeta[0];
#pragma unroll
    for (int i = 0; i < 2; i++)
#pragma unroll
        for (int j = 0; j < 2; j++) {
            float v = acc[i][j] * (1.f / 16.f) + gb;
            gatesb[(size_t)(m0 + ty * 2 + i) * 1024 + (n0 + tx * 2 + j)] =
                f2b(1.f / (1.f + __expf(-v)));
        }
}

// ---------------- MFMA bf16 GEMM, 64x64 wave tile (LN / TRI epilogues) ---------------
// LN reduction: single pass -- var = E[x^2] - mu^2, (s,q) butterfly interleaved.
template <int BM, int BN, bool CAT, int EPI>
__global__ __launch_bounds__(256) void mfma_k(
    const bf16* __restrict__ A1, const bf16* __restrict__ A2, unsigned rowmask,
    const bf16* __restrict__ BT, const float* __restrict__ bias,
    float* __restrict__ outF,
    bf16* __restrict__ outB, bf16* __restrict__ outB2,
    const float* __restrict__ g1, const float* __restrict__ b1,
    const float* __restrict__ g2, const float* __restrict__ b2,
    const bf16* __restrict__ resid,
    int M, int K)
{
    constexpr bool LN = (EPI == E_LN1 || EPI == E_LN2);
    constexpr int STAGE_B = (BM * 32 + BN * 32) * 2;
    constexpr int SB = LN ? (64 * 260 * 4) : STAGE_B;
    __shared__ __align__(16) char smem[SB];
    short* As = (short*)smem;
    short* Bs = As + BM * 32;
    float* Cs = (float*)smem;   // LN epilogue reuses staging LDS

    const int tid = threadIdx.x;
    const int wid = tid >> 6, lane = tid & 63;
    const int wr = (BN == 256) ? 0 : wid;
    const int wc = (BN == 256) ? wid : 0;
    const int m0 = blockIdx.x * BM, n0 = blockIdx.y * BN;
    const int srow = tid >> 2;
    const int skoff = (tid & 3) * 8;

    f32x4 acc[4][4] = {};
    s16x8 pa[BM / 64], pbv[BN / 64];

    auto LOADT = [&](int k0) {
#pragma unroll
        for (int c = 0; c < BM / 64; c++) {
            int r = c * 64 + srow;
            int gr = m0 + r;
            const bf16* p;
            if (CAT) {
                int gk = k0 + skoff;
                p = (gk < 256) ? (A1 + (size_t)(gr & rowmask) * 256 + gk)
                               : (A2 + (size_t)gr * 256 + (gk - 256));
            } else {
                p = A1 + (size_t)gr * K + k0 + skoff;
            }
            pa[c] = *(const s16x8*)p;
        }
#pragma unroll
        for (int c = 0; c < BN / 64; c++) {
            int r = c * 64 + srow;
            pbv[c] = *(const s16x8*)(BT + (size_t)(n0 + r) * K + k0 + skoff);
        }
    };

    LOADT(0);
#pragma unroll 1
    for (int k0 = 0; k0 < K; k0 += 32) {
#pragma unroll
        for (int c = 0; c < BM / 64; c++)
            *(s16x8*)&As[(c * 64 + srow) * 32 + skoff] = pa[c];
#pragma unroll
        for (int c = 0; c < BN / 64; c++)
            *(s16x8*)&Bs[(c * 64 + srow) * 32 + skoff] = pbv[c];
        __syncthreads();
        if (k0 + 32 < K) LOADT(k0 + 32);   // next tile in flight during MFMA
        s16x8 af[4], bf[4];
#pragma unroll
        for (int mi = 0; mi < 4; mi++)
            af[mi] = *(s16x8*)&As[(wr * 64 + mi * 16 + (lane & 15)) * 32 + (lane >> 4) * 8];
#pragma unroll
        for (int ni = 0; ni < 4; ni++)
            bf[ni] = *(s16x8*)&Bs[(wc * 64 + ni * 16 + (lane & 15)) * 32 + (lane >> 4) * 8];
#pragma unroll
        for (int mi = 0; mi < 4; mi++)
#pragma unroll
            for (int ni = 0; ni < 4; ni++)
                acc[mi][ni] = __builtin_amdgcn_mfma_f32_16x16x32_bf16(
                    af[mi], bf[ni], acc[mi][ni], 0, 0, 0);
        __syncthreads();
    }

    if (EPI == E_TRI) {
        // dbc[M,48]: cols 0-15 d1, 16-31 Bm, 32-47 Cm
#pragma unroll
        for (int mi = 0; mi < 4; mi++)
#pragma unroll
            for (int ni = 0; ni < 4; ni++)
#pragma unroll
                for (int r = 0; r < 4; r++) {
                    int row = m0 + wid * 64 + mi * 16 + (lane >> 4) * 4 + r;
                    int col = ni * 16 + (lane & 15);
                    if (col < 48) {
                        float v = acc[mi][ni][r] + bias[col];
                        outF[(size_t)row * 48 + col] = v;
                    }
                }
    } else {
        // E_LN1 / E_LN2: relu -> Cs, then row LN(s). BM=64, BN=256, grid.y=1.
#pragma unroll
        for (int mi = 0; mi < 4; mi++)
#pragma unroll
            for (int ni = 0; ni < 4; ni++)
#pragma unroll
                for (int r = 0; r < 4; r++) {
                    int rl = mi * 16 + (lane >> 4) * 4 + r;
                    int cl = wc * 64 + ni * 16 + (lane & 15);
                    Cs[rl * 260 + cl] = fmaxf(acc[mi][ni][r] + bias[cl], 0.f);
                }
        __syncthreads();
        float g1v[4], b1v[4], g2v[4], b2v[4];
#pragma unroll
        for (int i = 0; i < 4; i++) {
            g1v[i] = g1[lane * 4 + i];
            b1v[i] = b1[lane * 4 + i];
            if (EPI == E_LN2) { g2v[i] = g2[lane * 4 + i]; b2v[i] = b2[lane * 4 + i]; }
        }
#pragma unroll 2
        for (int rr = 0; rr < 16; rr++) {
            int rl = wid * 16 + rr;
            int grow = m0 + rl;
            float x[4];
#pragma unroll
            for (int i = 0; i < 4; i++) x[i] = Cs[rl * 260 + lane * 4 + i];
            float s = (x[0] + x[1]) + (x[2] + x[3]);
            float qq = fmaf(x[0], x[0], fmaf(x[1], x[1], fmaf(x[2], x[2], x[3] * x[3])));
#pragma unroll
            for (int o = 1; o < 64; o <<= 1) {
                s += __shfl_xor(s, o, 64);
                qq += __shfl_xor(qq, o, 64);
            }
            float mu = s * (1.f / 256.f);
            float var = fmaf(-mu, mu, qq * (1.f / 256.f));
            float inv = rsqrtf(fmaxf(var, 0.f) + 1e-5f);
            float y[4];
#pragma unroll
            for (int i = 0; i < 4; i++) y[i] = (x[i] - mu) * inv * g1v[i] + b1v[i];
            if (EPI == E_LN1) {
                __align__(8) bf16 pk[4];
#pragma unroll
                for (int i = 0; i < 4; i++) pk[i] = f2b(y[i]);
                *(s16x4*)&outB[(size_t)grow * 256 + lane * 4] = *(s16x4*)pk;
            } else {
                int trow = (grow & 1023) * 64 + (grow >> 10);   // [N,T] order
                __align__(8) bf16 pk[4];
#pragma unroll
                for (int i = 0; i < 4; i++) pk[i] = f2b(y[i]);
                *(s16x4*)&outB[(size_t)trow * 256 + lane * 4] = *(s16x4*)pk;
                float s2 = (y[0] + y[1]) + (y[2] + y[3]);
                float q2 = fmaf(y[0], y[0], fmaf(y[1], y[1], fmaf(y[2], y[2], y[3] * y[3])));
#pragma unroll
                for (int o = 1; o < 64; o <<= 1) {
                    s2 += __shfl_xor(s2, o, 64);
                    q2 += __shfl_xor(q2, o, 64);
                }
                float mu2 = s2 * (1.f / 256.f);
                float var2 = fmaf(-mu2, mu2, q2 * (1.f / 256.f));
                float inv2 = rsqrtf(fmaxf(var2, 0.f) + 1e-5f);
                __align__(8) bf16 pk2[4];
#pragma unroll
                for (int i = 0; i < 4; i++) pk2[i] = f2b((y[i] - mu2) * inv2 * g2v[i] + b2v[i]);
                *(s16x4*)&outB2[(size_t)trow * 256 + lane * 4] = *(s16x4*)pk2;
            }
        }
    }
}

// ---------------- MFMA bf16 GEMM, 64x128 wave tile (S6/S11/S14) ----------------------
template <int EPI>
__global__ __launch_bounds__(256, 2) void mfma2_k(
    const bf16* __restrict__ A, const bf16* __restrict__ BT,
    const float* __restrict__ bias,
    float* __restrict__ outF, bf16* __restrict__ outB, bf16* __restrict__ outB2,
    const bf16* __restrict__ resid,
    int K)
{
    constexpr int STAGE_B = (128 * 40 + 256 * 40) * 2;          // 30720
    constexpr int TRB = (EPI == E_BF16T) ? (64 * 268 * 2) : 0;  // 34304
    constexpr int SB = STAGE_B > TRB ? STAGE_B : TRB;
    __shared__ __align__(16) char smem[SB];
    short* As = (short*)smem;
    short* Bs = As + 128 * 40;

    const int tid = threadIdx.x;
    const int wid = tid >> 6, lane = tid & 63;
    const int wr = wid & 1;          // wave rows: wr*64
    const int wc = wid >> 1;         // wave cols: wc*128
    const int m0 = blockIdx.x * 128, n0 = blockIdx.y * 256;
    const int srow = tid >> 2;       // 0..63
    const int skoff = (tid & 3) * 8; // 0,8,16,24

    f32x4 acc[4][8] = {};
    s16x8 pa[2], pb[4];

    auto LOADT = [&](int k0) {
#pragma unroll
        for (int c = 0; c < 2; c++)
            pa[c] = *(const s16x8*)(A + (size_t)(m0 + c * 64 + srow) * K + k0 + skoff);
#pragma unroll
        for (int c = 0; c < 4; c++)
            pb[c] = *(const s16x8*)(BT + (size_t)(n0 + c * 64 + srow) * K + k0 + skoff);
    };

    LOADT(0);
#pragma unroll 1
    for (int k0 = 0; k0 < K; k0 += 32) {
#pragma unroll
        for (int c = 0; c < 2; c++)
            *(s16x8*)&As[(c * 64 + srow) * 40 + skoff] = pa[c];
#pragma unroll
        for (int c = 0; c < 4; c++)
            *(s16x8*)&Bs[(c * 64 + srow) * 40 + skoff] = pb[c];
        __syncthreads();
        if (k0 + 32 < K) LOADT(k0 + 32);   // next tile in flight during MFMA
        s16x8 af[4];
#pragma unroll
        for (int mi = 0; mi < 4; mi++)
            af[mi] = *(s16x8*)&As[(wr * 64 + mi * 16 + (lane & 15)) * 40 + (lane >> 4) * 8];
#pragma unroll
        for (int ni = 0; ni < 8; ni++) {
            s16x8 bfv = *(s16x8*)&Bs[(wc * 128 + ni * 16 + (lane & 15)) * 40 + (lane >> 4) * 8];
#pragma unroll
            for (int mi = 0; mi < 4; mi++)
                acc[mi][ni] = __builtin_amdgcn_mfma_f32_16x16x32_bf16(
                    af[mi], bfv, acc[mi][ni], 0, 0, 0);
        }
        __syncthreads();
    }

    if (EPI == E_SILU) {
#pragma unroll
        for (int mi = 0; mi < 4; mi++)
#pragma unroll
            for (int ni = 0; ni < 8; ni++)
#pragma unroll
                for (int r = 0; r < 4; r++) {
                    int row = m0 + wr * 64 + mi * 16 + (lane >> 4) * 4 + r;
                    int col = n0 + wc * 128 + ni * 16 + (lane & 15);
                    float v = acc[mi][ni][r] + bias[col];
                    float s = v / (1.f + __expf(-v));
                    if (col < EE) outB[(size_t)row * EE + col] = f2b(s);
                    else          outB2[(size_t)row * EE + (col - EE)] = f2b(s);
                }
    } else if (EPI == E_OUT) {
#pragma unroll
        for (int mi = 0; mi < 4; mi++)
#pragma unroll
            for (int ni = 0; ni < 8; ni++)
#pragma unroll
                for (int r = 0; r < 4; r++) {
                    int row = m0 + wr * 64 + mi * 16 + (lane >> 4) * 4 + r;
                    int col = n0 + wc * 128 + ni * 16 + (lane & 15);
                    float v = acc[mi][ni][r] + bias[col] + toF(resid[(size_t)row * 256 + col]);
                    int t = row & 63, n = row >> 6;
                    outF[((size_t)t * NN_ + n) * 256 + col] = v;
                }
    } else {
        // E_BF16T: rows r = t*1024+j -> store transposed [t][col][j].
        short* Ts = (short*)smem;
#pragma unroll 1
        for (int h = 0; h < 2; h++) {
            if (h) __syncthreads();      // protect previous half's reads
            if (wr == h) {
#pragma unroll
                for (int mi = 0; mi < 4; mi++)
#pragma unroll
                    for (int ni = 0; ni < 8; ni++)
#pragma unroll
                        for (int r = 0; r < 4; r++) {
                            int rl = mi * 16 + (lane >> 4) * 4 + r;
                            int cl = wc * 128 + ni * 16 + (lane & 15);
                            union { bf16 b; short s; } u;
                            u.b = f2b(acc[mi][ni][r] + bias[n0 + cl]);
                            Ts[rl * 268 + cl] = u.s;
                        }
            }
            __syncthreads();
            const int col = tid;
            const int rowbase = m0 + h * 64;
            size_t dbase = (((size_t)(rowbase >> 10)) * 256 + (n0 + col)) * 1024 + (rowbase & 1023);
#pragma unroll
            for (int j0 = 0; j0 < 64; j0 += 8) {
                s16x8 v;
#pragma unroll
                for (int i = 0; i < 8; i++) v[i] = Ts[(j0 + i) * 268 + col];
                *(s16x8*)&outB[dbase + j0] = v;
            }
        }
    }
}

// ---------------- adj bit-pack: adj in {0,1} -> 1 bit/elem (268MB -> 8.4MB) --------
__global__ __launch_bounds__(256) void packadj_k(
    const float4* __restrict__ adj4, unsigned int* __restrict__ bits32)
{
    const size_t nwords = (size_t)TT * NN_ * NN_ / 32;   // 2,097,152
    const size_t stride = (size_t)gridDim.x * 256;
    for (size_t w = (size_t)blockIdx.x * 256 + threadIdx.x; w < nwords; w += stride) {
        const float4* __restrict__ p = adj4 + w * 8;
        float4 v[8];
#pragma unroll
        for (int i = 0; i < 8; i++) v[i] = p[i];
        unsigned int m = 0;
#pragma unroll
        for (int i = 0; i < 8; i++) {
            m |= (v[i].x != 0.f ? 1u : 0u) << (4 * i);
            m |= (v[i].y != 0.f ? 2u : 0u) << (4 * i);
            m |= (v[i].z != 0.f ? 4u : 0u) << (4 * i);
            m |= (v[i].w != 0.f ? 8u : 0u) << (4 * i);
        }
        bits32[w] = m;
    }
}

// ---------------- dense MFMA aggregation via bitmask -------------------------------
template <bool GATED>
__global__ __launch_bounds__(256, 2) void aggmm_k(
    const unsigned char* __restrict__ adjbits, const bf16* __restrict__ gatesb,
    const bf16* __restrict__ BTsrc, bf16* __restrict__ out)
{
    __shared__ __align__(16) short As[128 * 40];
    __shared__ __align__(16) short Bs[256 * 40];
    const int tid = threadIdx.x;
    const int wid = tid >> 6, lane = tid & 63;
    const int wr = wid & 1;          // wave rows: wr*64
    const int wc = wid >> 1;         // wave cols: wc*128
    const int bx = blockIdx.x;
    const int t = bx >> 3, n0 = (bx & 7) * 128;
    const int srow = tid >> 2;       // 0..63
    const int skoff = (tid & 3) * 8; // 0,8,16,24

    const unsigned char* __restrict__ abB =
        adjbits + ((size_t)t * 1024 + n0) * 128 + (tid & 3);
    const bf16* __restrict__ gB = GATED ? (gatesb + (size_t)n0 * 1024 + skoff) : nullptr;
    const bf16* __restrict__ bt = GATED ? BTsrc : (BTsrc + (size_t)t * 256 * 1024);
    const size_t orow0 = (size_t)t * 1024 + n0;

    f32x4 acc[4][8] = {};

    unsigned char pm[2];
    s16x8 pg[2];
    s16x8 pb[4];

    auto LOADA = [&](int k0) {
#pragma unroll
        for (int c = 0; c < 2; c++) {
            int r = c * 64 + srow;
            pm[c] = abB[(size_t)r * 128 + (k0 >> 3)];
            if (GATED) pg[c] = *(const s16x8*)(gB + (size_t)r * 1024 + k0);
        }
#pragma unroll
        for (int c = 0; c < 4; c++)
            pb[c] = *(const s16x8*)(bt + (size_t)(c * 64 + srow) * 1024 + k0 + skoff);
    };
    auto STORE = [&]() {
#pragma unroll
        for (int c = 0; c < 2; c++) {
            unsigned m = pm[c];
            s16x8 tmp;
            if (GATED) {
#pragma unroll
                for (int i = 0; i < 8; i++) tmp[i] = ((m >> i) & 1) ? pg[c][i] : (short)0;
            } else {
#pragma unroll
                for (int i = 0; i < 8; i++) tmp[i] = ((m >> i) & 1) ? (short)0x3F80 : (short)0;
            }
            *(s16x8*)&As[(c * 64 + srow) * 40 + skoff] = tmp;
        }
#pragma unroll
        for (int c = 0; c < 4; c++)
            *(s16x8*)&Bs[(c * 64 + srow) * 40 + skoff] = pb[c];
    };

    LOADA(0);
#pragma unroll 1
    for (int k0 = 0; k0 < 1024; k0 += 32) {
        STORE();
        __syncthreads();
        if (k0 + 32 < 1024) LOADA(k0 + 32);   // next tile in flight during MFMA
        s16x8 af[4];
#pragma unroll
        for (int mi = 0; mi < 4; mi++)
            af[mi] = *(s16x8*)&As[(wr * 64 + mi * 16 + (lane & 15)) * 40 + (lane >> 4) * 8];
#pragma unroll
        for (int ni = 0; ni < 8; ni++) {
            s16x8 bfv = *(s16x8*)&Bs[(wc * 128 + ni * 16 + (lane & 15)) * 40 + (lane >> 4) * 8];
#pragma unroll
            for (int mi = 0; mi < 4; mi++)
                acc[mi][ni] = __builtin_amdgcn_mfma_f32_16x16x32_bf16(
                    af[mi], bfv, acc[mi][ni], 0, 0, 0);
        }
        __syncthreads();
    }

#pragma unroll
    for (int mi = 0; mi < 4; mi++)
#pragma unroll
        for (int ni = 0; ni < 8; ni++)
#pragma unroll
            for (int r = 0; r < 4; r++) {
                int rowl = wr * 64 + mi * 16 + (lane >> 4) * 4 + r;
                int col = wc * 128 + ni * 16 + (lane & 15);
                out[(orow0 + rowl) * 256 + col] = f2b(acc[mi][ni][r]);
            }
}

// ---------------- Mamba selective scan: 2 independent n-streams per thread ----------
__global__ __launch_bounds__(256) void scan_k(
    const bf16* __restrict__ u, const bf16* __restrict__ sg,
    const float* __restrict__ dbc,
    const float* __restrict__ Wdt, const float* __restrict__ bdt,
    const float* __restrict__ Alog, const float* __restrict__ D,
    bf16* __restrict__ yg)
{
    const int n0 = blockIdx.x * 2, e = blockIdx.y * 256 + threadIdx.x;
    float al[16], wdt[16], h0[16], h1[16];
#pragma unroll
    for (int s = 0; s < 16; s++) {
        al[s] = -__expf(Alog[e * 16 + s]) * 1.44269504f;   // * log2(e)
        h0[s] = 0.f; h1[s] = 0.f;
    }
#pragma unroll
    for (int k = 0; k < 16; k++) wdt[k] = Wdt[(size_t)k * EE + e];
    const float bdte = bdt[e], De = D[e];
    const float* __restrict__ r0p = dbc + (size_t)n0 * TT * 48;
    const float* __restrict__ r1p = r0p + TT * 48;
    const size_t base0 = (size_t)n0 * TT * EE + e;
    const size_t base1 = base0 + (size_t)TT * EE;
#pragma unroll 1
    for (int t = 0; t < TT; t++) {
        const float* __restrict__ r0 = r0p + t * 48;
        const float* __restrict__ r1 = r1p + t * 48;
        float a00 = bdte, a01 = 0.f, a10 = bdte, a11 = 0.f;
#pragma unroll
        for (int k = 0; k < 8; k++) {
            a00 = fmaf(r0[k],     wdt[k],     a00);
            a01 = fmaf(r0[k + 8], wdt[k + 8], a01);
            a10 = fmaf(r1[k],     wdt[k],     a10);
            a11 = fmaf(r1[k + 8], wdt[k + 8], a11);
        }
        float acc0 = a00 + a01, acc1 = a10 + a11;
        float delta0 = (acc0 > 20.f)
            ? acc0 : 0.69314718056f * LOG2F(1.f + EXP2F(acc0 * 1.44269504f));
        float delta1 = (acc1 > 20.f)
            ? acc1 : 0.69314718056f * LOG2F(1.f + EXP2F(acc1 * 1.44269504f));
        size_t idx0 = base0 + (size_t)t * EE;
        size_t idx1 = base1 + (size_t)t * EE;
        float uv0 = toF(u[idx0]), uv1 = toF(u[idx1]);
        float du0 = delta0 * uv0, du1 = delta1 * uv1;
        float y00 = 0.f, y01 = 0.f, y10 = 0.f, y11 = 0.f;
#pragma unroll
        for (int s = 0; s < 16; s += 2) {
            float ad00 = EXP2F(delta0 * al[s]);
            float ad01 = EXP2F(delta0 * al[s + 1]);
            float ad10 = EXP2F(delta1 * al[s]);
            float ad11 = EXP2F(delta1 * al[s + 1]);
            h0[s]     = fmaf(ad00, h0[s],     du0 * r0[16 + s]);
            h0[s + 1] = fmaf(ad01, h0[s + 1], du0 * r0[17 + s]);
            h1[s]     = fmaf(ad10, h1[s],     du1 * r1[16 + s]);
            h1[s + 1] = fmaf(ad11, h1[s + 1], du1 * r1[17 + s]);
            y00 = fmaf(r0[32 + s], h0[s],     y00);
            y01 = fmaf(r0[33 + s], h0[s + 1], y01);
            y10 = fmaf(r1[32 + s], h1[s],     y10);
            y11 = fmaf(r1[33 + s], h1[s + 1], y11);
        }
        float y0 = y00 + y01, y1 = y10 + y11;
        yg[idx0] = f2b((y0 + uv0 * De) * toF(sg[idx0]));
        yg[idx1] = f2b((y1 + uv1 * De) * toF(sg[idx1]));
    }
}

// ---------------- fused prep: cast + 4x transT + wdbct in one launch ----------------
__global__ __launch_bounds__(256) void prep_all_k(
    const float* __restrict__ pos,
    const float* __restrict__ g1Wu, const float* __restrict__ g2Wm,
    const float* __restrict__ g2Wu, const float* __restrict__ mWin,
    const float* __restrict__ mWout,
    const float* __restrict__ Wd, const float* __restrict__ WB,
    const float* __restrict__ WC, const float* __restrict__ bd,
    const float* __restrict__ bB, const float* __restrict__ bC,
    bf16* __restrict__ posb, bf16* __restrict__ g1WuT, bf16* __restrict__ g2WmT,
    bf16* __restrict__ g2WuT, bf16* __restrict__ mWinT, bf16* __restrict__ mWoutT,
    bf16* __restrict__ WdBCT, float* __restrict__ biascat)
{
    const int total = 262144 + 131072 + 65536 + 131072 + 262144 + 131072 + 32768 + 48;
    for (int gid = blockIdx.x * 256 + threadIdx.x; gid < total; gid += gridDim.x * 256) {
        int g = gid;
        if (g < 262144) { posb[g] = f2b(pos[g]); continue; }
        g -= 262144;
        if (g < 131072) { int n = g >> 9, k = g & 511; g1WuT[g] = f2b(g1Wu[(size_t)k * 256 + n]); continue; }
        g -= 131072;
        if (g < 65536)  { int n = g >> 8, k = g & 255; g2WmT[g] = f2b(g2Wm[(size_t)k * 256 + n]); continue; }
        g -= 65536;
        if (g < 131072) { int n = g >> 9, k = g & 511; g2WuT[g] = f2b(g2Wu[(size_t)k * 256 + n]); continue; }
        g -= 131072;
        if (g < 262144) { int n = g >> 8, k = g & 255; mWinT[g] = f2b(mWin[(size_t)k * 1024 + n]); continue; }
        g -= 262144;
        if (g < 131072) { int n = g >> 9, k = g & 511; mWoutT[g] = f2b(mWout[(size_t)k * 256 + n]); continue; }
        g -= 131072;
        if (g < 32768) {
            int n = g >> 9, k = g & 511;
            float v = 0.f;
            if (n < 16)      v = Wd[(size_t)k * 16 + n];
            else if (n < 32) v = WB[(size_t)k * 16 + (n - 16)];
            else if (n < 48) v = WC[(size_t)k * 16 + (n - 32)];
            WdBCT[g] = f2b(v);
            continue;
        }
        g -= 32768;
        biascat[g] = (g < 16) ? bd[g] : (g < 32) ? bB[g - 16] : bC[g - 32];
    }
}

extern "C" void kernel_launch(void* const* d_in, const int* in_sizes, int n_in,
                              void* d_out, int out_size, void* d_ws, size_t ws_size,
                              hipStream_t stream)
{
    const float* adj   = (const float*)d_in[0];
    const float* pos   = (const float*)d_in[1];
    const float* g1Wm  = (const float*)d_in[2];
    const float* g1bm  = (const float*)d_in[3];
    const float* g1Wq  = (const float*)d_in[4];
    const float* g1Wk  = (const float*)d_in[5];
    const float* g1gb  = (const float*)d_in[6];
    const float* g1Wu  = (const float*)d_in[7];
    const float* g1bu  = (const float*)d_in[8];
    const float* g1lg  = (const float*)d_in[9];
    const float* g1lb  = (const float*)d_in[10];
    const float* g2Wm  = (const float*)d_in[11];
    const float* g2bm  = (const float*)d_in[12];
    const float* g2Wu  = (const float*)d_in[13];
    const float* g2bu  = (const float*)d_in[14];
    const float* g2lg  = (const float*)d_in[15];
    const float* g2lb  = (const float*)d_in[16];
    const float* mlg   = (const float*)d_in[17];
    const float* mlb   = (const float*)d_in[18];
    const float* mWin  = (const float*)d_in[19];
    const float* mbin  = (const float*)d_in[20];
    const float* mWd   = (const float*)d_in[21];
    const float* mbd   = (const float*)d_in[22];
    const float* mWdt  = (const float*)d_in[23];
    const float* mbdt  = (const float*)d_in[24];
    const float* mWB   = (const float*)d_in[25];
    const float* mbB   = (const float*)d_in[26];
    const float* mWC   = (const float*)d_in[27];
    const float* mbC   = (const float*)d_in[28];
    const float* mAlog = (const float*)d_in[29];
    const float* mD    = (const float*)d_in[30];
    const float* mWout = (const float*)d_in[31];
    const float* mbout = (const float*)d_in[32];
    float* out = (float*)d_out;
    char* ws = (char*)d_ws;

    const size_t BIGE = (size_t)TT * NN_ * 256;
    size_t o = 0;
    auto alloc = [&](size_t bytes) { size_t r = o; o += (bytes + 255) & ~(size_t)255; return r; };

    float* msgs  = (float*)(ws + alloc((size_t)NN_ * 256 * 4));
    float* q     = (float*)(ws + alloc((size_t)NN_ * 256 * 4));
    float* kk    = (float*)(ws + alloc((size_t)NN_ * 256 * 4));
    bf16*  gatesb = (bf16*)(ws + alloc((size_t)NN_ * NN_ * 2));
    unsigned long long* adjbits =
        (unsigned long long*)(ws + alloc((size_t)TT * NN_ * NN_ / 8));
    bf16*  Ra    = (bf16*)(ws + alloc(BIGE * 2));                 // agg / xn
    size_t off_x1 = alloc(BIGE * 2);
    bf16*  x1    = (bf16*)(ws + off_x1);
    bf16*  agg2  = (bf16*)(ws + alloc(BIGE * 2));                 // contiguous after x1
    bf16*  x2    = (bf16*)(ws + alloc(BIGE * 2));                 // res, [N,T,H]
    bf16*  yg    = (bf16*)(ws + alloc(BIGE * 2));
    bf16*  sg    = (bf16*)(ws + alloc((size_t)NN_ * TT * EE * 2));
    float* dbc   = (float*)(ws + alloc((size_t)TT * NN_ * 48 * 4));  // [M,48] d1|Bm|Cm
    bf16*  u     = (bf16*)(ws + off_x1);                          // aliases x1+agg2
    // transposed bf16 weights / staging
    bf16* posb   = (bf16*)(ws + alloc((size_t)NN_ * 256 * 2));
    bf16* g1WuT  = (bf16*)(ws + alloc((size_t)256 * 512 * 2));
    bf16* g2WmT  = (bf16*)(ws + alloc((size_t)256 * 256 * 2));
    bf16* g2WuT  = (bf16*)(ws + alloc((size_t)256 * 512 * 2));
    bf16* mWinT  = (bf16*)(ws + alloc((size_t)1024 * 256 * 2));
    bf16* mWoutT = (bf16*)(ws + alloc((size_t)256 * 512 * 2));
    bf16* WdBCT  = (bf16*)(ws + alloc((size_t)64 * 512 * 2));
    float* biascat = (float*)(ws + alloc(64 * 4));
    bf16* msgsT  = (bf16*)(ws + alloc((size_t)256 * 1024 * 2));
    bf16* msgs2T = (bf16*)(ws + alloc(BIGE * 2));

    const unsigned ALLR = 0xFFFFFFFFu;
    const int M = TT * NN_;

    // prep (2 launches)
    packadj_k<<<2048, 256, 0, stream>>>((const float4*)adj, (unsigned int*)adjbits);
    prep_all_k<<<1024, 256, 0, stream>>>(
        pos, g1Wu, g2Wm, g2Wu, mWin, mWout, mWd, mWB, mWC, mbd, mbB, mbC,
        posb, g1WuT, g2WmT, g2WuT, mWinT, mWoutT, WdBCT, biascat);

    // S0: msgs = pos @ g1_Wm + bm (f32) + fused msgsT (bf16, transposed)
    gemm_k<false, EPI_F32T><<<dim3(16, 4), 256, 0, stream>>>(
        pos, g1Wm, msgs, g1bm, nullptr, 1.f, NN_, 256, 256, 256, 256, msgsT);
    // S1: q AND k in one launch
    gemmqk_k<<<dim3(16, 8), 256, 0, stream>>>(msgs, g1Wq, g1Wk, q, kk);
    // S2: gates = sigmoid(q @ k^T / 16 + gb) -> bf16 (32x32 tiles, 1024 blocks)
    gemmsig_k<<<dim3(32, 32), 256, 0, stream>>>(q, kk, g1gb, gatesb);
    // S3: agg -> Ra
    aggmm_k<true><<<512, 256, 0, stream>>>(
        (const unsigned char*)adjbits, gatesb, msgsT, Ra);
    // S4(+S5): x1 = LN(relu(cat(posb,Ra) @ Wu1 + bu1))
    mfma_k<64, 256, true, E_LN1><<<dim3(1024, 1), 256, 0, stream>>>(
        posb, Ra, 1023u, g1WuT, g1bu, nullptr, x1, nullptr,
        g1lg, g1lb, nullptr, nullptr, nullptr, M, 512);
    // S6: msgs2 = x1 @ Wm2 + bm2 -> msgs2T ([t][c][j])  (64x128 wave tile)
    mfma2_k<E_BF16T><<<dim3(512, 1), 256, 0, stream>>>(
        x1, g2WmT, g2bm, nullptr, msgs2T, nullptr, nullptr, 256);
    // S7: agg2 = adj @ msgs2
    aggmm_k<false><<<512, 256, 0, stream>>>(
        (const unsigned char*)adjbits, nullptr, msgs2T, agg2);
    // S8(+S9+S10): x2 = LN(relu(cat(x1,agg2)@Wu2+bu2)) [N,T,H], xn = LN2 -> Ra [N,T,H]
    mfma_k<64, 256, true, E_LN2><<<dim3(1024, 1), 256, 0, stream>>>(
        x1, agg2, ALLR, g2WuT, g2bu, nullptr, x2, Ra,
        g2lg, g2lb, mlg, mlb, nullptr, M, 512);
    // S11: u/sg = silu halves of xn @ Win + bin  (64x128 wave tile)
    mfma2_k<E_SILU><<<dim3(512, 4), 256, 0, stream>>>(
        Ra, mWinT, mbin, nullptr, u, sg, nullptr, 256);
    // S12 fused: dbc = u @ [Wd|WB|WC] + biases  ([M,48] interleaved)
    mfma_k<256, 64, false, E_TRI><<<dim3(256, 1), 256, 0, stream>>>(
        u, u, ALLR, WdBCT, biascat, dbc, nullptr, nullptr,
        nullptr, nullptr, nullptr, nullptr, nullptr, M, 512);
    // S13: selective scan -> yg  (block per (n-pair, e-half); 2 streams/thread)
    scan_k<<<dim3(NN_ / 2, 2), 256, 0, stream>>>(u, sg, dbc, mWdt, mbdt, mAlog, mD, yg);
    // S14: out = yg @ Wout + bout + res -> [T,N,H] f32  (64x128 wave tile)
    mfma2_k<E_OUT><<<dim3(512, 1), 256, 0, stream>>>(
        yg, mWoutT, mbout, out, nullptr, nullptr, x2, 512);

    (void)in_sizes; (void)n_in; (void)out_size; (void)ws_size;
}

// Round 11
// 987.120 us; speedup vs baseline: 1.0799x; 1.0246x over previous
//
#include <hip/hip_runtime.h>
#include <hip/hip_bf16.h>

typedef __hip_bfloat16 bf16;
typedef __attribute__((ext_vector_type(8))) short s16x8;
typedef __attribute__((ext_vector_type(4))) short s16x4;
typedef __attribute__((ext_vector_type(4))) float f32x4;

#define TT 64
#define NN_ 1024
#define EE 512

__device__ __forceinline__ float toF(float v) { return v; }
__device__ __forceinline__ float toF(bf16 v) { return __bfloat162float(v); }
__device__ __forceinline__ bf16 f2b(float v) { return __float2bfloat16(v); }

#if __has_builtin(__builtin_amdgcn_exp2f)
#define EXP2F(x) __builtin_amdgcn_exp2f(x)
#else
#define EXP2F(x) exp2f(x)
#endif
#if __has_builtin(__builtin_amdgcn_logf)
#define LOG2F(x) __builtin_amdgcn_logf(x)
#else
#define LOG2F(x) log2f(x)
#endif

enum { E_LN1 = 0, E_BF16 = 1, E_LN2 = 2, E_SILU = 3, E_OUT = 4, E_TRI = 5, E_BF16T = 6 };

// ---------------- S0: msgs = pos @ g1Wm + bm (f32) + msgsT (bf16 transposed) --------
// 32x32 tiles, 256 blocks (vs old 64x64 / 64 blocks). Bit-exact: per-output fp32
// fma chain in sequential k order, bias added after, identical to the old gemm_k.
__global__ __launch_bounds__(256) void gemm32a_k(
    const float* __restrict__ A, const float* __restrict__ B,
    const float* __restrict__ bias,
    float* __restrict__ msgs, bf16* __restrict__ msgsT)
{
    __shared__ float As[16][36];
    __shared__ float Bs[16][36];
    const int tid = threadIdx.x;
    const int tx = tid & 15, ty = tid >> 4;
    const int m0 = blockIdx.x * 32, n0 = blockIdx.y * 32;
    float acc[2][2] = {};

    for (int k0 = 0; k0 < 256; k0 += 16) {
        {
            int r = tid >> 3, kk0 = (tid & 7) * 2;
            As[kk0][r]     = A[(size_t)(m0 + r) * 256 + k0 + kk0];
            As[kk0 + 1][r] = A[(size_t)(m0 + r) * 256 + k0 + kk0 + 1];
            Bs[kk0][r]     = B[(size_t)(k0 + kk0) * 256 + n0 + r];
            Bs[kk0 + 1][r] = B[(size_t)(k0 + kk0 + 1) * 256 + n0 + r];
        }
        __syncthreads();
#pragma unroll
        for (int kk = 0; kk < 16; kk++) {
            float a0 = As[kk][ty * 2], a1 = As[kk][ty * 2 + 1];
            float b0 = Bs[kk][tx * 2], b1 = Bs[kk][tx * 2 + 1];
            acc[0][0] = fmaf(a0, b0, acc[0][0]);
            acc[0][1] = fmaf(a0, b1, acc[0][1]);
            acc[1][0] = fmaf(a1, b0, acc[1][0]);
            acc[1][1] = fmaf(a1, b1, acc[1][1]);
        }
        __syncthreads();
    }

#pragma unroll
    for (int i = 0; i < 2; i++)
#pragma unroll
        for (int j = 0; j < 2; j++) {
            int row = m0 + ty * 2 + i, col = n0 + tx * 2 + j;
            float v = acc[i][j] + bias[col];
            msgs[(size_t)row * 256 + col] = v;
            msgsT[(size_t)col * 1024 + row] = f2b(v);
        }
}

// ---------------- S1: q AND k in one launch, 32x32 tiles (512 blocks) ---------------
__global__ __launch_bounds__(256) void gemm32qk_k(
    const float* __restrict__ A, const float* __restrict__ Bq,
    const float* __restrict__ Bk, float* __restrict__ outq, float* __restrict__ outk)
{
    __shared__ float As[16][36];
    __shared__ float Bs[16][36];
    const bool isq = (blockIdx.y < 8);
    const float* __restrict__ B = isq ? Bq : Bk;
    float* __restrict__ outF = isq ? outq : outk;
    const int tid = threadIdx.x;
    const int tx = tid & 15, ty = tid >> 4;
    const int m0 = blockIdx.x * 32, n0 = (blockIdx.y & 7) * 32;
    float acc[2][2] = {};

    for (int k0 = 0; k0 < 256; k0 += 16) {
        {
            int r = tid >> 3, kk0 = (tid & 7) * 2;
            As[kk0][r]     = A[(size_t)(m0 + r) * 256 + k0 + kk0];
            As[kk0 + 1][r] = A[(size_t)(m0 + r) * 256 + k0 + kk0 + 1];
            Bs[kk0][r]     = B[(size_t)(k0 + kk0) * 256 + n0 + r];
            Bs[kk0 + 1][r] = B[(size_t)(k0 + kk0 + 1) * 256 + n0 + r];
        }
        __syncthreads();
#pragma unroll
        for (int kk = 0; kk < 16; kk++) {
            float a0 = As[kk][ty * 2], a1 = As[kk][ty * 2 + 1];
            float b0 = Bs[kk][tx * 2], b1 = Bs[kk][tx * 2 + 1];
            acc[0][0] = fmaf(a0, b0, acc[0][0]);
            acc[0][1] = fmaf(a0, b1, acc[0][1]);
            acc[1][0] = fmaf(a1, b0, acc[1][0]);
            acc[1][1] = fmaf(a1, b1, acc[1][1]);
        }
        __syncthreads();
    }

#pragma unroll
    for (int i = 0; i < 2; i++)
#pragma unroll
        for (int j = 0; j < 2; j++)
            outF[(size_t)(m0 + ty * 2 + i) * 256 + (n0 + tx * 2 + j)] = acc[i][j];
}

// ---------------- S2: gates = sigmoid(q @ k^T / 16 + gb), 32x32 tiles ---------------
__global__ __launch_bounds__(256) void gemmsig_k(
    const float* __restrict__ Q, const float* __restrict__ Kv,
    const float* __restrict__ sbeta, bf16* __restrict__ gatesb)
{
    __shared__ float As[16][36];
    __shared__ float Bs[16][36];
    const int tid = threadIdx.x;
    const int tx = tid & 15, ty = tid >> 4;
    const int m0 = blockIdx.x * 32, n0 = blockIdx.y * 32;
    float acc[2][2] = {};

    for (int k0 = 0; k0 < 256; k0 += 16) {
        {
            int r = tid >> 3, kk0 = (tid & 7) * 2;
            As[kk0][r]     = Q[(size_t)(m0 + r) * 256 + k0 + kk0];
            As[kk0 + 1][r] = Q[(size_t)(m0 + r) * 256 + k0 + kk0 + 1];
            Bs[kk0][r]     = Kv[(size_t)(n0 + r) * 256 + k0 + kk0];
            Bs[kk0 + 1][r] = Kv[(size_t)(n0 + r) * 256 + k0 + kk0 + 1];
        }
        __syncthreads();
#pragma unroll
        for (int kk = 0; kk < 16; kk++) {
            float a0 = As[kk][ty * 2], a1 = As[kk][ty * 2 + 1];
            float b0 = Bs[kk][tx * 2], b1 = Bs[kk][tx * 2 + 1];
            acc[0][0] = fmaf(a0, b0, acc[0][0]);
            acc[0][1] = fmaf(a0, b1, acc[0][1]);
            acc[1][0] = fmaf(a1, b0, acc[1][0]);
            acc[1][1] = fmaf(a1, b1, acc[1][1]);
        }
        __syncthreads();
    }

    const float gb = sbeta[0];
#pragma unroll
    for (int i = 0; i < 2; i++)
#pragma unroll
        for (int j = 0; j < 2; j++) {
            float v = acc[i][j] * (1.f / 16.f) + gb;
            gatesb[(size_t)(m0 + ty * 2 + i) * 1024 + (n0 + tx * 2 + j)] =
                f2b(1.f / (1.f + __expf(-v)));
        }
}

// ---------------- MFMA bf16 GEMM, 64x64 wave tile (LN / TRI epilogues) ---------------
// LN reduction: single pass -- var = E[x^2] - mu^2, (s,q) butterfly interleaved.
template <int BM, int BN, bool CAT, int EPI>
__global__ __launch_bounds__(256) void mfma_k(
    const bf16* __restrict__ A1, const bf16* __restrict__ A2, unsigned rowmask,
    const bf16* __restrict__ BT, const float* __restrict__ bias,
    float* __restrict__ outF,
    bf16* __restrict__ outB, bf16* __restrict__ outB2,
    const float* __restrict__ g1, const float* __restrict__ b1,
    const float* __restrict__ g2, const float* __restrict__ b2,
    const bf16* __restrict__ resid,
    int M, int K)
{
    constexpr bool LN = (EPI == E_LN1 || EPI == E_LN2);
    constexpr int STAGE_B = (BM * 32 + BN * 32) * 2;
    constexpr int SB = LN ? (64 * 260 * 4) : STAGE_B;
    __shared__ __align__(16) char smem[SB];
    short* As = (short*)smem;
    short* Bs = As + BM * 32;
    float* Cs = (float*)smem;   // LN epilogue reuses staging LDS

    const int tid = threadIdx.x;
    const int wid = tid >> 6, lane = tid & 63;
    const int wr = (BN == 256) ? 0 : wid;
    const int wc = (BN == 256) ? wid : 0;
    const int m0 = blockIdx.x * BM, n0 = blockIdx.y * BN;
    const int srow = tid >> 2;
    const int skoff = (tid & 3) * 8;

    f32x4 acc[4][4] = {};
    s16x8 pa[BM / 64], pbv[BN / 64];

    auto LOADT = [&](int k0) {
#pragma unroll
        for (int c = 0; c < BM / 64; c++) {
            int r = c * 64 + srow;
            int gr = m0 + r;
            const bf16* p;
            if (CAT) {
                int gk = k0 + skoff;
                p = (gk < 256) ? (A1 + (size_t)(gr & rowmask) * 256 + gk)
                               : (A2 + (size_t)gr * 256 + (gk - 256));
            } else {
                p = A1 + (size_t)gr * K + k0 + skoff;
            }
            pa[c] = *(const s16x8*)p;
        }
#pragma unroll
        for (int c = 0; c < BN / 64; c++) {
            int r = c * 64 + srow;
            pbv[c] = *(const s16x8*)(BT + (size_t)(n0 + r) * K + k0 + skoff);
        }
    };

    LOADT(0);
#pragma unroll 1
    for (int k0 = 0; k0 < K; k0 += 32) {
#pragma unroll
        for (int c = 0; c < BM / 64; c++)
            *(s16x8*)&As[(c * 64 + srow) * 32 + skoff] = pa[c];
#pragma unroll
        for (int c = 0; c < BN / 64; c++)
            *(s16x8*)&Bs[(c * 64 + srow) * 32 + skoff] = pbv[c];
        __syncthreads();
        if (k0 + 32 < K) LOADT(k0 + 32);   // next tile in flight during MFMA
        s16x8 af[4], bf[4];
#pragma unroll
        for (int mi = 0; mi < 4; mi++)
            af[mi] = *(s16x8*)&As[(wr * 64 + mi * 16 + (lane & 15)) * 32 + (lane >> 4) * 8];
#pragma unroll
        for (int ni = 0; ni < 4; ni++)
            bf[ni] = *(s16x8*)&Bs[(wc * 64 + ni * 16 + (lane & 15)) * 32 + (lane >> 4) * 8];
#pragma unroll
        for (int mi = 0; mi < 4; mi++)
#pragma unroll
            for (int ni = 0; ni < 4; ni++)
                acc[mi][ni] = __builtin_amdgcn_mfma_f32_16x16x32_bf16(
                    af[mi], bf[ni], acc[mi][ni], 0, 0, 0);
        __syncthreads();
    }

    if (EPI == E_TRI) {
        // dbc[M,48]: cols 0-15 d1, 16-31 Bm, 32-47 Cm
#pragma unroll
        for (int mi = 0; mi < 4; mi++)
#pragma unroll
            for (int ni = 0; ni < 4; ni++)
#pragma unroll
                for (int r = 0; r < 4; r++) {
                    int row = m0 + wid * 64 + mi * 16 + (lane >> 4) * 4 + r;
                    int col = ni * 16 + (lane & 15);
                    if (col < 48) {
                        float v = acc[mi][ni][r] + bias[col];
                        outF[(size_t)row * 48 + col] = v;
                    }
                }
    } else {
        // E_LN1 / E_LN2: relu -> Cs, then row LN(s). BM=64, BN=256, grid.y=1.
#pragma unroll
        for (int mi = 0; mi < 4; mi++)
#pragma unroll
            for (int ni = 0; ni < 4; ni++)
#pragma unroll
                for (int r = 0; r < 4; r++) {
                    int rl = mi * 16 + (lane >> 4) * 4 + r;
                    int cl = wc * 64 + ni * 16 + (lane & 15);
                    Cs[rl * 260 + cl] = fmaxf(acc[mi][ni][r] + bias[cl], 0.f);
                }
        __syncthreads();
        float g1v[4], b1v[4], g2v[4], b2v[4];
#pragma unroll
        for (int i = 0; i < 4; i++) {
            g1v[i] = g1[lane * 4 + i];
            b1v[i] = b1[lane * 4 + i];
            if (EPI == E_LN2) { g2v[i] = g2[lane * 4 + i]; b2v[i] = b2[lane * 4 + i]; }
        }
#pragma unroll 2
        for (int rr = 0; rr < 16; rr++) {
            int rl = wid * 16 + rr;
            int grow = m0 + rl;
            float x[4];
#pragma unroll
            for (int i = 0; i < 4; i++) x[i] = Cs[rl * 260 + lane * 4 + i];
            float s = (x[0] + x[1]) + (x[2] + x[3]);
            float qq = fmaf(x[0], x[0], fmaf(x[1], x[1], fmaf(x[2], x[2], x[3] * x[3])));
#pragma unroll
            for (int o = 1; o < 64; o <<= 1) {
                s += __shfl_xor(s, o, 64);
                qq += __shfl_xor(qq, o, 64);
            }
            float mu = s * (1.f / 256.f);
            float var = fmaf(-mu, mu, qq * (1.f / 256.f));
            float inv = rsqrtf(fmaxf(var, 0.f) + 1e-5f);
            float y[4];
#pragma unroll
            for (int i = 0; i < 4; i++) y[i] = (x[i] - mu) * inv * g1v[i] + b1v[i];
            if (EPI == E_LN1) {
                __align__(8) bf16 pk[4];
#pragma unroll
                for (int i = 0; i < 4; i++) pk[i] = f2b(y[i]);
                *(s16x4*)&outB[(size_t)grow * 256 + lane * 4] = *(s16x4*)pk;
            } else {
                int trow = (grow & 1023) * 64 + (grow >> 10);   // [N,T] order
                __align__(8) bf16 pk[4];
#pragma unroll
                for (int i = 0; i < 4; i++) pk[i] = f2b(y[i]);
                *(s16x4*)&outB[(size_t)trow * 256 + lane * 4] = *(s16x4*)pk;
                float s2 = (y[0] + y[1]) + (y[2] + y[3]);
                float q2 = fmaf(y[0], y[0], fmaf(y[1], y[1], fmaf(y[2], y[2], y[3] * y[3])));
#pragma unroll
                for (int o = 1; o < 64; o <<= 1) {
                    s2 += __shfl_xor(s2, o, 64);
                    q2 += __shfl_xor(q2, o, 64);
                }
                float mu2 = s2 * (1.f / 256.f);
                float var2 = fmaf(-mu2, mu2, q2 * (1.f / 256.f));
                float inv2 = rsqrtf(fmaxf(var2, 0.f) + 1e-5f);
                __align__(8) bf16 pk2[4];
#pragma unroll
                for (int i = 0; i < 4; i++) pk2[i] = f2b((y[i] - mu2) * inv2 * g2v[i] + b2v[i]);
                *(s16x4*)&outB2[(size_t)trow * 256 + lane * 4] = *(s16x4*)pk2;
            }
        }
    }
}

// ---------------- MFMA bf16 GEMM, 64x128 wave tile (S6/S11/S14) ----------------------
template <int EPI>
__global__ __launch_bounds__(256, 2) void mfma2_k(
    const bf16* __restrict__ A, const bf16* __restrict__ BT,
    const float* __restrict__ bias,
    float* __restrict__ outF, bf16* __restrict__ outB, bf16* __restrict__ outB2,
    const bf16* __restrict__ resid,
    int K)
{
    constexpr int STAGE_B = (128 * 40 + 256 * 40) * 2;          // 30720
    constexpr int TRB = (EPI == E_BF16T) ? (64 * 268 * 2) : 0;  // 34304
    constexpr int SB = STAGE_B > TRB ? STAGE_B : TRB;
    __shared__ __align__(16) char smem[SB];
    short* As = (short*)smem;
    short* Bs = As + 128 * 40;

    const int tid = threadIdx.x;
    const int wid = tid >> 6, lane = tid & 63;
    const int wr = wid & 1;          // wave rows: wr*64
    const int wc = wid >> 1;         // wave cols: wc*128
    const int m0 = blockIdx.x * 128, n0 = blockIdx.y * 256;
    const int srow = tid >> 2;       // 0..63
    const int skoff = (tid & 3) * 8; // 0,8,16,24

    f32x4 acc[4][8] = {};
    s16x8 pa[2], pb[4];

    auto LOADT = [&](int k0) {
#pragma unroll
        for (int c = 0; c < 2; c++)
            pa[c] = *(const s16x8*)(A + (size_t)(m0 + c * 64 + srow) * K + k0 + skoff);
#pragma unroll
        for (int c = 0; c < 4; c++)
            pb[c] = *(const s16x8*)(BT + (size_t)(n0 + c * 64 + srow) * K + k0 + skoff);
    };

    LOADT(0);
#pragma unroll 1
    for (int k0 = 0; k0 < K; k0 += 32) {
#pragma unroll
        for (int c = 0; c < 2; c++)
            *(s16x8*)&As[(c * 64 + srow) * 40 + skoff] = pa[c];
#pragma unroll
        for (int c = 0; c < 4; c++)
            *(s16x8*)&Bs[(c * 64 + srow) * 40 + skoff] = pb[c];
        __syncthreads();
        if (k0 + 32 < K) LOADT(k0 + 32);   // next tile in flight during MFMA
        s16x8 af[4];
#pragma unroll
        for (int mi = 0; mi < 4; mi++)
            af[mi] = *(s16x8*)&As[(wr * 64 + mi * 16 + (lane & 15)) * 40 + (lane >> 4) * 8];
#pragma unroll
        for (int ni = 0; ni < 8; ni++) {
            s16x8 bfv = *(s16x8*)&Bs[(wc * 128 + ni * 16 + (lane & 15)) * 40 + (lane >> 4) * 8];
#pragma unroll
            for (int mi = 0; mi < 4; mi++)
                acc[mi][ni] = __builtin_amdgcn_mfma_f32_16x16x32_bf16(
                    af[mi], bfv, acc[mi][ni], 0, 0, 0);
        }
        __syncthreads();
    }

    if (EPI == E_SILU) {
#pragma unroll
        for (int mi = 0; mi < 4; mi++)
#pragma unroll
            for (int ni = 0; ni < 8; ni++)
#pragma unroll
                for (int r = 0; r < 4; r++) {
                    int row = m0 + wr * 64 + mi * 16 + (lane >> 4) * 4 + r;
                    int col = n0 + wc * 128 + ni * 16 + (lane & 15);
                    float v = acc[mi][ni][r] + bias[col];
                    float s = v / (1.f + __expf(-v));
                    if (col < EE) outB[(size_t)row * EE + col] = f2b(s);
                    else          outB2[(size_t)row * EE + (col - EE)] = f2b(s);
                }
    } else if (EPI == E_OUT) {
#pragma unroll
        for (int mi = 0; mi < 4; mi++)
#pragma unroll
            for (int ni = 0; ni < 8; ni++)
#pragma unroll
                for (int r = 0; r < 4; r++) {
                    int row = m0 + wr * 64 + mi * 16 + (lane >> 4) * 4 + r;
                    int col = n0 + wc * 128 + ni * 16 + (lane & 15);
                    float v = acc[mi][ni][r] + bias[col] + toF(resid[(size_t)row * 256 + col]);
                    int t = row & 63, n = row >> 6;
                    outF[((size_t)t * NN_ + n) * 256 + col] = v;
                }
    } else {
        // E_BF16T: rows r = t*1024+j -> store transposed [t][col][j].
        short* Ts = (short*)smem;
#pragma unroll 1
        for (int h = 0; h < 2; h++) {
            if (h) __syncthreads();      // protect previous half's reads
            if (wr == h) {
#pragma unroll
                for (int mi = 0; mi < 4; mi++)
#pragma unroll
                    for (int ni = 0; ni < 8; ni++)
#pragma unroll
                        for (int r = 0; r < 4; r++) {
                            int rl = mi * 16 + (lane >> 4) * 4 + r;
                            int cl = wc * 128 + ni * 16 + (lane & 15);
                            union { bf16 b; short s; } u;
                            u.b = f2b(acc[mi][ni][r] + bias[n0 + cl]);
                            Ts[rl * 268 + cl] = u.s;
                        }
            }
            __syncthreads();
            const int col = tid;
            const int rowbase = m0 + h * 64;
            size_t dbase = (((size_t)(rowbase >> 10)) * 256 + (n0 + col)) * 1024 + (rowbase & 1023);
#pragma unroll
            for (int j0 = 0; j0 < 64; j0 += 8) {
                s16x8 v;
#pragma unroll
                for (int i = 0; i < 8; i++) v[i] = Ts[(j0 + i) * 268 + col];
                *(s16x8*)&outB[dbase + j0] = v;
            }
        }
    }
}

// ---------------- adj bit-pack: adj in {0,1} -> 1 bit/elem (268MB -> 8.4MB) --------
__global__ __launch_bounds__(256) void packadj_k(
    const float4* __restrict__ adj4, unsigned int* __restrict__ bits32)
{
    const size_t nwords = (size_t)TT * NN_ * NN_ / 32;   // 2,097,152
    const size_t stride = (size_t)gridDim.x * 256;
    for (size_t w = (size_t)blockIdx.x * 256 + threadIdx.x; w < nwords; w += stride) {
        const float4* __restrict__ p = adj4 + w * 8;
        float4 v[8];
#pragma unroll
        for (int i = 0; i < 8; i++) v[i] = p[i];
        unsigned int m = 0;
#pragma unroll
        for (int i = 0; i < 8; i++) {
            m |= (v[i].x != 0.f ? 1u : 0u) << (4 * i);
            m |= (v[i].y != 0.f ? 2u : 0u) << (4 * i);
            m |= (v[i].z != 0.f ? 4u : 0u) << (4 * i);
            m |= (v[i].w != 0.f ? 8u : 0u) << (4 * i);
        }
        bits32[w] = m;
    }
}

// ---------------- dense MFMA aggregation via bitmask -------------------------------
template <bool GATED>
__global__ __launch_bounds__(256, 2) void aggmm_k(
    const unsigned char* __restrict__ adjbits, const bf16* __restrict__ gatesb,
    const bf16* __restrict__ BTsrc, bf16* __restrict__ out)
{
    __shared__ __align__(16) short As[128 * 40];
    __shared__ __align__(16) short Bs[256 * 40];
    const int tid = threadIdx.x;
    const int wid = tid >> 6, lane = tid & 63;
    const int wr = wid & 1;          // wave rows: wr*64
    const int wc = wid >> 1;         // wave cols: wc*128
    const int bx = blockIdx.x;
    const int t = bx >> 3, n0 = (bx & 7) * 128;
    const int srow = tid >> 2;       // 0..63
    const int skoff = (tid & 3) * 8; // 0,8,16,24

    const unsigned char* __restrict__ abB =
        adjbits + ((size_t)t * 1024 + n0) * 128 + (tid & 3);
    const bf16* __restrict__ gB = GATED ? (gatesb + (size_t)n0 * 1024 + skoff) : nullptr;
    const bf16* __restrict__ bt = GATED ? BTsrc : (BTsrc + (size_t)t * 256 * 1024);
    const size_t orow0 = (size_t)t * 1024 + n0;

    f32x4 acc[4][8] = {};

    unsigned char pm[2];
    s16x8 pg[2];
    s16x8 pb[4];

    auto LOADA = [&](int k0) {
#pragma unroll
        for (int c = 0; c < 2; c++) {
            int r = c * 64 + srow;
            pm[c] = abB[(size_t)r * 128 + (k0 >> 3)];
            if (GATED) pg[c] = *(const s16x8*)(gB + (size_t)r * 1024 + k0);
        }
#pragma unroll
        for (int c = 0; c < 4; c++)
            pb[c] = *(const s16x8*)(bt + (size_t)(c * 64 + srow) * 1024 + k0 + skoff);
    };
    auto STORE = [&]() {
#pragma unroll
        for (int c = 0; c < 2; c++) {
            unsigned m = pm[c];
            s16x8 tmp;
            if (GATED) {
#pragma unroll
                for (int i = 0; i < 8; i++) tmp[i] = ((m >> i) & 1) ? pg[c][i] : (short)0;
            } else {
#pragma unroll
                for (int i = 0; i < 8; i++) tmp[i] = ((m >> i) & 1) ? (short)0x3F80 : (short)0;
            }
            *(s16x8*)&As[(c * 64 + srow) * 40 + skoff] = tmp;
        }
#pragma unroll
        for (int c = 0; c < 4; c++)
            *(s16x8*)&Bs[(c * 64 + srow) * 40 + skoff] = pb[c];
    };

    LOADA(0);
#pragma unroll 1
    for (int k0 = 0; k0 < 1024; k0 += 32) {
        STORE();
        __syncthreads();
        if (k0 + 32 < 1024) LOADA(k0 + 32);   // next tile in flight during MFMA
        s16x8 af[4];
#pragma unroll
        for (int mi = 0; mi < 4; mi++)
            af[mi] = *(s16x8*)&As[(wr * 64 + mi * 16 + (lane & 15)) * 40 + (lane >> 4) * 8];
#pragma unroll
        for (int ni = 0; ni < 8; ni++) {
            s16x8 bfv = *(s16x8*)&Bs[(wc * 128 + ni * 16 + (lane & 15)) * 40 + (lane >> 4) * 8];
#pragma unroll
            for (int mi = 0; mi < 4; mi++)
                acc[mi][ni] = __builtin_amdgcn_mfma_f32_16x16x32_bf16(
                    af[mi], bfv, acc[mi][ni], 0, 0, 0);
        }
        __syncthreads();
    }

#pragma unroll
    for (int mi = 0; mi < 4; mi++)
#pragma unroll
        for (int ni = 0; ni < 8; ni++)
#pragma unroll
            for (int r = 0; r < 4; r++) {
                int rowl = wr * 64 + mi * 16 + (lane >> 4) * 4 + r;
                int col = wc * 128 + ni * 16 + (lane & 15);
                out[(orow0 + rowl) * 256 + col] = f2b(acc[mi][ni][r]);
            }
}

// ---------------- Mamba selective scan: 2 independent n-streams per thread ----------
// t-loop unrolled x2 (scheduling only): t+1's wave-uniform dbc loads + delta
// projection overlap t's recurrence tail. Per-stream arithmetic order unchanged.
__global__ __launch_bounds__(256) void scan_k(
    const bf16* __restrict__ u, const bf16* __restrict__ sg,
    const float* __restrict__ dbc,
    const float* __restrict__ Wdt, const float* __restrict__ bdt,
    const float* __restrict__ Alog, const float* __restrict__ D,
    bf16* __restrict__ yg)
{
    const int n0 = blockIdx.x * 2, e = blockIdx.y * 256 + threadIdx.x;
    float al[16], wdt[16], h0[16], h1[16];
#pragma unroll
    for (int s = 0; s < 16; s++) {
        al[s] = -__expf(Alog[e * 16 + s]) * 1.44269504f;   // * log2(e)
        h0[s] = 0.f; h1[s] = 0.f;
    }
#pragma unroll
    for (int k = 0; k < 16; k++) wdt[k] = Wdt[(size_t)k * EE + e];
    const float bdte = bdt[e], De = D[e];
    const float* __restrict__ r0p = dbc + (size_t)n0 * TT * 48;
    const float* __restrict__ r1p = r0p + TT * 48;
    const size_t base0 = (size_t)n0 * TT * EE + e;
    const size_t base1 = base0 + (size_t)TT * EE;
#pragma unroll 2
    for (int t = 0; t < TT; t++) {
        const float* __restrict__ r0 = r0p + t * 48;
        const float* __restrict__ r1 = r1p + t * 48;
        float a00 = bdte, a01 = 0.f, a10 = bdte, a11 = 0.f;
#pragma unroll
        for (int k = 0; k < 8; k++) {
            a00 = fmaf(r0[k],     wdt[k],     a00);
            a01 = fmaf(r0[k + 8], wdt[k + 8], a01);
            a10 = fmaf(r1[k],     wdt[k],     a10);
            a11 = fmaf(r1[k + 8], wdt[k + 8], a11);
        }
        float acc0 = a00 + a01, acc1 = a10 + a11;
        float delta0 = (acc0 > 20.f)
            ? acc0 : 0.69314718056f * LOG2F(1.f + EXP2F(acc0 * 1.44269504f));
        float delta1 = (acc1 > 20.f)
            ? acc1 : 0.69314718056f * LOG2F(1.f + EXP2F(acc1 * 1.44269504f));
        size_t idx0 = base0 + (size_t)t * EE;
        size_t idx1 = base1 + (size_t)t * EE;
        float uv0 = toF(u[idx0]), uv1 = toF(u[idx1]);
        float du0 = delta0 * uv0, du1 = delta1 * uv1;
        float y00 = 0.f, y01 = 0.f, y10 = 0.f, y11 = 0.f;
#pragma unroll
        for (int s = 0; s < 16; s += 2) {
            float ad00 = EXP2F(delta0 * al[s]);
            float ad01 = EXP2F(delta0 * al[s + 1]);
            float ad10 = EXP2F(delta1 * al[s]);
            float ad11 = EXP2F(delta1 * al[s + 1]);
            h0[s]     = fmaf(ad00, h0[s],     du0 * r0[16 + s]);
            h0[s + 1] = fmaf(ad01, h0[s + 1], du0 * r0[17 + s]);
            h1[s]     = fmaf(ad10, h1[s],     du1 * r1[16 + s]);
            h1[s + 1] = fmaf(ad11, h1[s + 1], du1 * r1[17 + s]);
            y00 = fmaf(r0[32 + s], h0[s],     y00);
            y01 = fmaf(r0[33 + s], h0[s + 1], y01);
            y10 = fmaf(r1[32 + s], h1[s],     y10);
            y11 = fmaf(r1[33 + s], h1[s + 1], y11);
        }
        float y0 = y00 + y01, y1 = y10 + y11;
        yg[idx0] = f2b((y0 + uv0 * De) * toF(sg[idx0]));
        yg[idx1] = f2b((y1 + uv1 * De) * toF(sg[idx1]));
    }
}

// ---------------- fused prep: cast + 4x transT + wdbct in one launch ----------------
__global__ __launch_bounds__(256) void prep_all_k(
    const float* __restrict__ pos,
    const float* __restrict__ g1Wu, const float* __restrict__ g2Wm,
    const float* __restrict__ g2Wu, const float* __restrict__ mWin,
    const float* __restrict__ mWout,
    const float* __restrict__ Wd, const float* __restrict__ WB,
    const float* __restrict__ WC, const float* __restrict__ bd,
    const float* __restrict__ bB, const float* __restrict__ bC,
    bf16* __restrict__ posb, bf16* __restrict__ g1WuT, bf16* __restrict__ g2WmT,
    bf16* __restrict__ g2WuT, bf16* __restrict__ mWinT, bf16* __restrict__ mWoutT,
    bf16* __restrict__ WdBCT, float* __restrict__ biascat)
{
    const int total = 262144 + 131072 + 65536 + 131072 + 262144 + 131072 + 32768 + 48;
    for (int gid = blockIdx.x * 256 + threadIdx.x; gid < total; gid += gridDim.x * 256) {
        int g = gid;
        if (g < 262144) { posb[g] = f2b(pos[g]); continue; }
        g -= 262144;
        if (g < 131072) { int n = g >> 9, k = g & 511; g1WuT[g] = f2b(g1Wu[(size_t)k * 256 + n]); continue; }
        g -= 131072;
        if (g < 65536)  { int n = g >> 8, k = g & 255; g2WmT[g] = f2b(g2Wm[(size_t)k * 256 + n]); continue; }
        g -= 65536;
        if (g < 131072) { int n = g >> 9, k = g & 511; g2WuT[g] = f2b(g2Wu[(size_t)k * 256 + n]); continue; }
        g -= 131072;
        if (g < 262144) { int n = g >> 8, k = g & 255; mWinT[g] = f2b(mWin[(size_t)k * 1024 + n]); continue; }
        g -= 262144;
        if (g < 131072) { int n = g >> 9, k = g & 511; mWoutT[g] = f2b(mWout[(size_t)k * 256 + n]); continue; }
        g -= 131072;
        if (g < 32768) {
            int n = g >> 9, k = g & 511;
            float v = 0.f;
            if (n < 16)      v = Wd[(size_t)k * 16 + n];
            else if (n < 32) v = WB[(size_t)k * 16 + (n - 16)];
            else if (n < 48) v = WC[(size_t)k * 16 + (n - 32)];
            WdBCT[g] = f2b(v);
            continue;
        }
        g -= 32768;
        biascat[g] = (g < 16) ? bd[g] : (g < 32) ? bB[g - 16] : bC[g - 32];
    }
}

extern "C" void kernel_launch(void* const* d_in, const int* in_sizes, int n_in,
                              void* d_out, int out_size, void* d_ws, size_t ws_size,
                              hipStream_t stream)
{
    const float* adj   = (const float*)d_in[0];
    const float* pos   = (const float*)d_in[1];
    const float* g1Wm  = (const float*)d_in[2];
    const float* g1bm  = (const float*)d_in[3];
    const float* g1Wq  = (const float*)d_in[4];
    const float* g1Wk  = (const float*)d_in[5];
    const float* g1gb  = (const float*)d_in[6];
    const float* g1Wu  = (const float*)d_in[7];
    const float* g1bu  = (const float*)d_in[8];
    const float* g1lg  = (const float*)d_in[9];
    const float* g1lb  = (const float*)d_in[10];
    const float* g2Wm  = (const float*)d_in[11];
    const float* g2bm  = (const float*)d_in[12];
    const float* g2Wu  = (const float*)d_in[13];
    const float* g2bu  = (const float*)d_in[14];
    const float* g2lg  = (const float*)d_in[15];
    const float* g2lb  = (const float*)d_in[16];
    const float* mlg   = (const float*)d_in[17];
    const float* mlb   = (const float*)d_in[18];
    const float* mWin  = (const float*)d_in[19];
    const float* mbin  = (const float*)d_in[20];
    const float* mWd   = (const float*)d_in[21];
    const float* mbd   = (const float*)d_in[22];
    const float* mWdt  = (const float*)d_in[23];
    const float* mbdt  = (const float*)d_in[24];
    const float* mWB   = (const float*)d_in[25];
    const float* mbB   = (const float*)d_in[26];
    const float* mWC   = (const float*)d_in[27];
    const float* mbC   = (const float*)d_in[28];
    const float* mAlog = (const float*)d_in[29];
    const float* mD    = (const float*)d_in[30];
    const float* mWout = (const float*)d_in[31];
    const float* mbout = (const float*)d_in[32];
    float* out = (float*)d_out;
    char* ws = (char*)d_ws;

    const size_t BIGE = (size_t)TT * NN_ * 256;
    size_t o = 0;
    auto alloc = [&](size_t bytes) { size_t r = o; o += (bytes + 255) & ~(size_t)255; return r; };

    float* msgs  = (float*)(ws + alloc((size_t)NN_ * 256 * 4));
    float* q     = (float*)(ws + alloc((size_t)NN_ * 256 * 4));
    float* kk    = (float*)(ws + alloc((size_t)NN_ * 256 * 4));
    bf16*  gatesb = (bf16*)(ws + alloc((size_t)NN_ * NN_ * 2));
    unsigned long long* adjbits =
        (unsigned long long*)(ws + alloc((size_t)TT * NN_ * NN_ / 8));
    bf16*  Ra    = (bf16*)(ws + alloc(BIGE * 2));                 // agg / xn
    size_t off_x1 = alloc(BIGE * 2);
    bf16*  x1    = (bf16*)(ws + off_x1);
    bf16*  agg2  = (bf16*)(ws + alloc(BIGE * 2));                 // contiguous after x1
    bf16*  x2    = (bf16*)(ws + alloc(BIGE * 2));                 // res, [N,T,H]
    bf16*  yg    = (bf16*)(ws + alloc(BIGE * 2));
    bf16*  sg    = (bf16*)(ws + alloc((size_t)NN_ * TT * EE * 2));
    float* dbc   = (float*)(ws + alloc((size_t)TT * NN_ * 48 * 4));  // [M,48] d1|Bm|Cm
    bf16*  u     = (bf16*)(ws + off_x1);                          // aliases x1+agg2
    // transposed bf16 weights / staging
    bf16* posb   = (bf16*)(ws + alloc((size_t)NN_ * 256 * 2));
    bf16* g1WuT  = (bf16*)(ws + alloc((size_t)256 * 512 * 2));
    bf16* g2WmT  = (bf16*)(ws + alloc((size_t)256 * 256 * 2));
    bf16* g2WuT  = (bf16*)(ws + alloc((size_t)256 * 512 * 2));
    bf16* mWinT  = (bf16*)(ws + alloc((size_t)1024 * 256 * 2));
    bf16* mWoutT = (bf16*)(ws + alloc((size_t)256 * 512 * 2));
    bf16* WdBCT  = (bf16*)(ws + alloc((size_t)64 * 512 * 2));
    float* biascat = (float*)(ws + alloc(64 * 4));
    bf16* msgsT  = (bf16*)(ws + alloc((size_t)256 * 1024 * 2));
    bf16* msgs2T = (bf16*)(ws + alloc(BIGE * 2));

    const unsigned ALLR = 0xFFFFFFFFu;
    const int M = TT * NN_;

    // prep (2 launches)
    packadj_k<<<2048, 256, 0, stream>>>((const float4*)adj, (unsigned int*)adjbits);
    prep_all_k<<<1024, 256, 0, stream>>>(
        pos, g1Wu, g2Wm, g2Wu, mWin, mWout, mWd, mWB, mWC, mbd, mbB, mbC,
        posb, g1WuT, g2WmT, g2WuT, mWinT, mWoutT, WdBCT, biascat);

    // S0: msgs = pos @ g1_Wm + bm (f32) + fused msgsT (32x32 tiles, 256 blocks)
    gemm32a_k<<<dim3(32, 8), 256, 0, stream>>>(pos, g1Wm, g1bm, msgs, msgsT);
    // S1: q AND k in one launch (32x32 tiles, 512 blocks)
    gemm32qk_k<<<dim3(32, 16), 256, 0, stream>>>(msgs, g1Wq, g1Wk, q, kk);
    // S2: gates = sigmoid(q @ k^T / 16 + gb) -> bf16 (32x32 tiles, 1024 blocks)
    gemmsig_k<<<dim3(32, 32), 256, 0, stream>>>(q, kk, g1gb, gatesb);
    // S3: agg -> Ra
    aggmm_k<true><<<512, 256, 0, stream>>>(
        (const unsigned char*)adjbits, gatesb, msgsT, Ra);
    // S4(+S5): x1 = LN(relu(cat(posb,Ra) @ Wu1 + bu1))
    mfma_k<64, 256, true, E_LN1><<<dim3(1024, 1), 256, 0, stream>>>(
        posb, Ra, 1023u, g1WuT, g1bu, nullptr, x1, nullptr,
        g1lg, g1lb, nullptr, nullptr, nullptr, M, 512);
    // S6: msgs2 = x1 @ Wm2 + bm2 -> msgs2T ([t][c][j])  (64x128 wave tile)
    mfma2_k<E_BF16T><<<dim3(512, 1), 256, 0, stream>>>(
        x1, g2WmT, g2bm, nullptr, msgs2T, nullptr, nullptr, 256);
    // S7: agg2 = adj @ msgs2
    aggmm_k<false><<<512, 256, 0, stream>>>(
        (const unsigned char*)adjbits, nullptr, msgs2T, agg2);
    // S8(+S9+S10): x2 = LN(relu(cat(x1,agg2)@Wu2+bu2)) [N,T,H], xn = LN2 -> Ra [N,T,H]
    mfma_k<64, 256, true, E_LN2><<<dim3(1024, 1), 256, 0, stream>>>(
        x1, agg2, ALLR, g2WuT, g2bu, nullptr, x2, Ra,
        g2lg, g2lb, mlg, mlb, nullptr, M, 512);
    // S11: u/sg = silu halves of xn @ Win + bin  (64x128 wave tile)
    mfma2_k<E_SILU><<<dim3(512, 4), 256, 0, stream>>>(
        Ra, mWinT, mbin, nullptr, u, sg, nullptr, 256);
    // S12 fused: dbc = u @ [Wd|WB|WC] + biases  ([M,48] interleaved)
    mfma_k<256, 64, false, E_TRI><<<dim3(256, 1), 256, 0, stream>>>(
        u, u, ALLR, WdBCT, biascat, dbc, nullptr, nullptr,
        nullptr, nullptr, nullptr, nullptr, nullptr, M, 512);
    // S13: selective scan -> yg  (block per (n-pair, e-half); 2 streams/thread)
    scan_k<<<dim3(NN_ / 2, 2), 256, 0, stream>>>(u, sg, dbc, mWdt, mbdt, mAlog, mD, yg);
    // S14: out = yg @ Wout + bout + res -> [T,N,H] f32  (64x128 wave tile)
    mfma2_k<E_OUT><<<dim3(512, 1), 256, 0, stream>>>(
        yg, mWoutT, mbout, out, nullptr, nullptr, x2, 512);

    (void)in_sizes; (void)n_in; (void)out_size; (void)ws_size;
}